// Round 1
// baseline (897.580 us; speedup 1.0000x reference)
//
#include <hip/hip_runtime.h>
#include <hip/hip_bf16.h>

#define BB 4
#define NN 2048
#define FIN 32
#define TT 16
#define EE 32768
#define CC 64
#define TFo 64

typedef __attribute__((ext_vector_type(8))) short bf16x8;
typedef __attribute__((ext_vector_type(4))) float f32x4;

typedef __attribute__((address_space(1))) const unsigned int as1_uint;
typedef __attribute__((address_space(3))) unsigned int as3_uint;

__device__ __forceinline__ void gload_lds16(const void* g, void* l) {
    __builtin_amdgcn_global_load_lds((as1_uint*)g, (as3_uint*)l, 16, 0, 0);
}

__device__ __forceinline__ unsigned short f2bf(float v) {
    unsigned u = __builtin_bit_cast(unsigned, v);
    unsigned r = (u + 0x7fffu + ((u >> 16) & 1u)) >> 16;
    return (unsigned short)r;
}

// ---------------- Stage A: temporal attention ----------------

// tmp1[b][f][t] = sum_n X[b][n][f][t] * U1[n]   (atomic accumulate, tmp1 pre-zeroed)
__global__ void k_u1reduce(const float* __restrict__ X, const float* __restrict__ U1,
                           float* __restrict__ tmp1) {
    int b = blockIdx.x >> 6;
    int n0 = (blockIdx.x & 63) * 32;
    float a0 = 0.f, a1 = 0.f;
    for (int i = 0; i < 32; ++i) {
        int n = n0 + i;
        float u = U1[n];
        const float* row = X + ((size_t)(b * NN + n)) * 512;
        a0 += u * row[threadIdx.x];
        a1 += u * row[threadIdx.x + 256];
    }
    atomicAdd(&tmp1[b * 512 + threadIdx.x], a0);
    atomicAdd(&tmp1[b * 512 + threadIdx.x + 256], a1);
}

// lhs[b][t][n'] = sum_f tmp1[b][f][t] * U2[f][n']
__global__ void k_mklhs(const float* __restrict__ tmp1, const float* __restrict__ U2,
                        float* __restrict__ lhs) {
    int npr = ((blockIdx.x & 7) << 8) + threadIdx.x;
    int bt = blockIdx.x >> 3;           // b*16 + t
    int b = bt >> 4, t = bt & 15;
    float acc = 0.f;
#pragma unroll
    for (int f = 0; f < 32; ++f) acc += tmp1[b * 512 + f * 16 + t] * U2[f * NN + npr];
    lhs[(size_t)bt * NN + npr] = acc;
}

// rhs[b][n][t] = sum_f U3[f]*X[b][n][f][t]
__global__ void k_mkrhs(const float* __restrict__ X, const float* __restrict__ U3,
                        float* __restrict__ rhs) {
    int idx = blockIdx.x * 256 + threadIdx.x;   // B*N*T
    int t = idx & 15;
    int bn = idx >> 4;
    float acc = 0.f;
#pragma unroll
    for (int f = 0; f < 32; ++f) acc += U3[f] * X[(size_t)bn * 512 + f * 16 + t];
    rhs[idx] = acc;
}

// Pt[b][t][s] += sum over n-chunk lhs[b][t][n]*rhs[b][n][s]   (Pt pre-zeroed)
__global__ void k_ptaccum(const float* __restrict__ lhs, const float* __restrict__ rhs,
                          float* __restrict__ Pt) {
    int b = blockIdx.x >> 3;
    int n0 = (blockIdx.x & 7) * 256;
    int t = threadIdx.x >> 4, s = threadIdx.x & 15;
    const float* lr = lhs + (size_t)b * TT * NN + (size_t)t * NN;
    const float* rr = rhs + (size_t)b * NN * TT;
    float acc = 0.f;
    for (int i = 0; i < 256; ++i) {
        int n = n0 + i;
        acc += lr[n] * rr[n * 16 + s];
    }
    atomicAdd(&Pt[b * 256 + threadIdx.x], acc);
}

// Emat[b][t][s]: sigmoid(+be), Ve-multiply, softmax over t
__global__ void k_temporalatt(const float* __restrict__ Pt, const float* __restrict__ be,
                              const float* __restrict__ Ve, float* __restrict__ Emat) {
    int b = blockIdx.x;
    int t = threadIdx.x >> 4, s = threadIdx.x & 15;
    __shared__ float sg[16][17];
    __shared__ float em[16][17];
    float v = Pt[b * 256 + t * 16 + s] + be[t * 16 + s];
    sg[t][s] = 1.f / (1.f + __expf(-v));
    __syncthreads();
    float e = 0.f;
#pragma unroll
    for (int u = 0; u < 16; ++u) e += Ve[t * 16 + u] * sg[u][s];
    em[t][s] = e;
    __syncthreads();
    float mx = -1e30f;
#pragma unroll
    for (int u = 0; u < 16; ++u) mx = fmaxf(mx, em[u][s]);
    float sum = 0.f;
#pragma unroll
    for (int u = 0; u < 16; ++u) sum += __expf(em[u][s] - mx);
    Emat[b * 256 + t * 16 + s] = __expf(e - mx) / sum;
}

// Xt[b][n][f][s] = sum_t X[b][n][f][t]*Emat[b][t][s]
__global__ void k_applyemat(const float* __restrict__ X, const float* __restrict__ Emat,
                            float* __restrict__ Xt) {
    __shared__ float em[256];
    int b = blockIdx.x >> 8;   // 256 blocks per batch
    em[threadIdx.x] = Emat[b * 256 + threadIdx.x];
    __syncthreads();
    size_t base = ((size_t)blockIdx.x * 256 + threadIdx.x) * 16;
    float x[16], o[16];
    const float4* xp = (const float4*)(X + base);
#pragma unroll
    for (int q = 0; q < 4; ++q) {
        float4 a = xp[q];
        x[q * 4 + 0] = a.x; x[q * 4 + 1] = a.y; x[q * 4 + 2] = a.z; x[q * 4 + 3] = a.w;
    }
#pragma unroll
    for (int s = 0; s < 16; ++s) {
        float acc = 0.f;
#pragma unroll
        for (int t = 0; t < 16; ++t) acc += x[t] * em[t * 16 + s];
        o[s] = acc;
    }
    float4* op = (float4*)(Xt + base);
#pragma unroll
    for (int q = 0; q < 4; ++q) op[q] = make_float4(o[q*4+0], o[q*4+1], o[q*4+2], o[q*4+3]);
}

// ---------------- Stage B: spatial attention small parts ----------------

// lhs_s[b][n][t], rhs_s[b][t][n] from Xt
__global__ void k_spatiallr(const float* __restrict__ Xt, const float* __restrict__ W1,
                            const float* __restrict__ W2, const float* __restrict__ W3,
                            float* __restrict__ lhs_s, float* __restrict__ rhs_s) {
    int b = blockIdx.x >> 7;
    int n0 = (blockIdx.x & 127) * 16;
    __shared__ float xb[16 * 512];
    __shared__ float av[16 * 32];
    const float* src = Xt + ((size_t)(b * NN + n0)) * 512;
    for (int i = 0; i < 32; ++i) xb[threadIdx.x + i * 256] = src[threadIdx.x + i * 256];
    __syncthreads();
#pragma unroll
    for (int ii = 0; ii < 2; ++ii) {
        int idx = threadIdx.x * 2 + ii;   // nl*32+f
        float acc = 0.f;
        const float* xr = &xb[idx * 16];
#pragma unroll
        for (int t = 0; t < 16; ++t) acc += xr[t] * W1[t];
        av[idx] = acc;
    }
    __syncthreads();
    int nl = threadIdx.x >> 4, t = threadIdx.x & 15;
    float r = 0.f;
#pragma unroll
    for (int f = 0; f < 32; ++f) r += W3[f] * xb[nl * 512 + f * 16 + t];
    rhs_s[(size_t)b * TT * NN + (size_t)t * NN + n0 + nl] = r;
    float l = 0.f;
#pragma unroll
    for (int f = 0; f < 32; ++f) l += av[nl * 32 + f] * W2[f * 16 + t];
    lhs_s[((size_t)(b * NN + n0 + nl)) * 16 + t] = l;
}

// Vs fp32 -> bf16
__global__ void k_f2bf(const float* __restrict__ src, unsigned short* __restrict__ dst) {
    int i = blockIdx.x * 256 + threadIdx.x;
    dst[i] = f2bf(src[i]);
}

// sigT[b][k][m] = bf16(sigmoid(dot(lhs_s[b,m,:], rhs_s[b,:,k]) + bs[m,k]))
__global__ void k_makesigT(const float* __restrict__ lhs_s, const float* __restrict__ rhs_s,
                           const float* __restrict__ bs, unsigned short* __restrict__ sigT) {
    int k0 = blockIdx.x * 64, m0 = blockIdx.y * 64, b = blockIdx.z;
    __shared__ float lh[64][17];
    __shared__ float rh[16][64];
    __shared__ float bsl[64][65];
    int tid = threadIdx.x;
#pragma unroll
    for (int i = 0; i < 4; ++i) {
        int idx = tid + i * 256;
        int mi = idx >> 4, t = idx & 15;
        lh[mi][t] = lhs_s[((size_t)(b * NN + m0 + mi)) * 16 + t];
        int tt = idx >> 6, kj = idx & 63;
        rh[tt][kj] = rhs_s[(size_t)b * TT * NN + (size_t)tt * NN + k0 + kj];
    }
#pragma unroll
    for (int i = 0; i < 16; ++i) {
        int idx = tid + i * 256;
        int mi = idx >> 6, kj = idx & 63;
        bsl[mi][kj] = bs[(size_t)(m0 + mi) * NN + k0 + kj];
    }
    __syncthreads();
    int ml = tid & 63;
    int kg = (tid >> 6) * 16;
    unsigned short* out = sigT + (size_t)b * NN * NN;
#pragma unroll 4
    for (int ki = 0; ki < 16; ++ki) {
        int kl = kg + ki;
        float acc = bsl[ml][kl];
#pragma unroll
        for (int t = 0; t < 16; ++t) acc += lh[ml][t] * rh[t][kl];
        float sgv = 1.f / (1.f + __expf(-acc));
        out[(size_t)(k0 + kl) * NN + m0 + ml] = f2bf(sgv);
    }
}

// ---------------- The big GEMM: S[b][n][k] = sum_m Vs[n][m]*sigT[b][k][m] ----------------

__global__ __launch_bounds__(256) void k_gemm_bt(const unsigned short* __restrict__ A,
                                                 const unsigned short* __restrict__ Bt,
                                                 float* __restrict__ C,
                                                 int M, int N, int K) {
    __shared__ __align__(16) unsigned short lds[2][2][128 * 32];
    const int tid = threadIdx.x;
    const int wave = tid >> 6, lane = tid & 63;
    const int bm = blockIdx.y << 7;
    const int bn = blockIdx.x << 7;
    const unsigned short* Bb = Bt + (size_t)blockIdx.z * N * K;
    float* Cb = C + (size_t)blockIdx.z * M * N;
    const int wr = wave >> 1, wc = wave & 1;
    const int srow = lane >> 2, scol = (lane & 3) << 3;

    f32x4 acc[4][4];
#pragma unroll
    for (int i = 0; i < 4; ++i)
#pragma unroll
        for (int j = 0; j < 4; ++j) acc[i][j] = (f32x4){0.f, 0.f, 0.f, 0.f};

    const size_t abase = (size_t)(bm + srow) * K + scol;
    const size_t bbase = (size_t)(bn + srow) * K + scol;

#define STAGE(buf, k0)                                                              \
    {                                                                               \
        _Pragma("unroll")                                                           \
        for (int ii = 0; ii < 2; ++ii) {                                            \
            int rb = ((ii << 2) + wave) << 4;                                       \
            gload_lds16(A + abase + (size_t)rb * K + (k0), &lds[buf][0][rb * 32]);  \
            gload_lds16(Bb + bbase + (size_t)rb * K + (k0), &lds[buf][1][rb * 32]); \
        }                                                                           \
    }

    STAGE(0, 0)
    __syncthreads();
    const int nk = K >> 5;
    const int rl = lane & 15, kg = (lane >> 4) << 3;
    for (int t = 0; t < nk; ++t) {
        int cur = t & 1;
        if (t + 1 < nk) STAGE(cur ^ 1, (t + 1) << 5)
        const unsigned short* la = &lds[cur][0][0];
        const unsigned short* lb = &lds[cur][1][0];
        bf16x8 af[4], bfr[4];
#pragma unroll
        for (int i = 0; i < 4; ++i) af[i] = *(const bf16x8*)(la + ((wr << 6) + (i << 4) + rl) * 32 + kg);
#pragma unroll
        for (int j = 0; j < 4; ++j) bfr[j] = *(const bf16x8*)(lb + ((wc << 6) + (j << 4) + rl) * 32 + kg);
#pragma unroll
        for (int i = 0; i < 4; ++i)
#pragma unroll
            for (int j = 0; j < 4; ++j)
                acc[i][j] = __builtin_amdgcn_mfma_f32_16x16x32_bf16(af[i], bfr[j], acc[i][j], 0, 0, 0);
        __syncthreads();
    }
#undef STAGE
    const int cl = lane & 15, rg = (lane >> 4) << 2;
#pragma unroll
    for (int i = 0; i < 4; ++i)
#pragma unroll
        for (int j = 0; j < 4; ++j) {
            int m0 = bm + (wr << 6) + (i << 4) + rg;
            int n0 = bn + (wc << 6) + (j << 4) + cl;
#pragma unroll
            for (int r = 0; r < 4; ++r) Cb[(size_t)(m0 + r) * N + n0] = acc[i][j][r];
        }
}

// softmax over n (axis=1) of S[b][n][k], in place
__global__ void k_softmaxcol(float* __restrict__ S) {
    int b = blockIdx.x >> 5;
    int k0 = (blockIdx.x & 31) * 64;
    int g = threadIdx.x >> 6;
    int kk = threadIdx.x & 63;
    float* Sb = S + (size_t)b * NN * NN + k0 + kk;
    float m = -1e30f, s = 0.f;
    for (int n = g; n < NN; n += 4) {
        float v = Sb[(size_t)n * NN];
        float nm = fmaxf(m, v);
        s = s * __expf(m - nm) + __expf(v - nm);
        m = nm;
    }
    __shared__ float lm[4][64], lsum[4][64];
    lm[g][kk] = m; lsum[g][kk] = s;
    __syncthreads();
    if (g == 0) {
        float M = lm[0][kk];
#pragma unroll
        for (int i = 1; i < 4; ++i) M = fmaxf(M, lm[i][kk]);
        float T = 0.f;
#pragma unroll
        for (int i = 0; i < 4; ++i) T += lsum[i][kk] * __expf(lm[i][kk] - M);
        lm[0][kk] = M; lsum[0][kk] = 1.f / T;
    }
    __syncthreads();
    float M = lm[0][kk], inv = lsum[0][kk];
    for (int n = g; n < NN; n += 4) {
        float v = Sb[(size_t)n * NN];
        Sb[(size_t)n * NN] = __expf(v - M) * inv;
    }
}

// diagS[b][n] = S[b][n][n]; att[b][e] = norm[e]*S[b][row[e]][col[e]]
__global__ void k_diagatt(const float* __restrict__ S, const int* __restrict__ row,
                          const int* __restrict__ col, const float* __restrict__ norm,
                          float* __restrict__ diagS, float* __restrict__ att) {
    int idx = blockIdx.x * 256 + threadIdx.x;
    if (idx < BB * EE) {
        int b = idx >> 15, e = idx & (EE - 1);
        att[idx] = norm[e] * S[(size_t)b * NN * NN + (size_t)row[e] * NN + col[e]];
    }
    if (idx < BB * NN) {
        int b = idx >> 11, n = idx & (NN - 1);
        diagS[idx] = S[(size_t)b * NN * NN + (size_t)n * NN + n];
    }
}

// ---------------- graph prep ----------------

__global__ void k_deg(const int* __restrict__ row, const int* __restrict__ col,
                      float* __restrict__ deg) {
    int e = blockIdx.x * 256 + threadIdx.x;
    if (e < EE && row[e] != col[e]) atomicAdd(&deg[row[e]], 1.0f);
}

__global__ void k_dinv(const float* __restrict__ deg, float* __restrict__ dinv) {
    int n = blockIdx.x * 256 + threadIdx.x;
    if (n < NN) {
        float d = deg[n];
        dinv[n] = d > 0.f ? rsqrtf(fmaxf(d, 1e-12f)) : 0.f;
    }
}

__global__ void k_norm(const int* __restrict__ row, const int* __restrict__ col,
                       const float* __restrict__ dinv, float* __restrict__ norm,
                       int* __restrict__ cnt) {
    int e = blockIdx.x * 256 + threadIdx.x;
    if (e < EE) {
        int r = row[e], c = col[e];
        float w = (r != c) ? 1.f : 0.f;
        norm[e] = -dinv[r] * w * dinv[c];
        atomicAdd(&cnt[r], 1);
    }
}

// exclusive scan of cnt[2048] -> starts[2049], single block of 256
__global__ void k_scan(const int* __restrict__ cnt, int* __restrict__ starts) {
    __shared__ int part[256];
    int t = threadIdx.x;
    int loc[8];
    int s = 0;
#pragma unroll
    for (int i = 0; i < 8; ++i) {
        int c = cnt[t * 8 + i];
        loc[i] = s;
        s += c;
    }
    part[t] = s;
    __syncthreads();
    for (int o = 1; o < 256; o <<= 1) {
        int v = (t >= o) ? part[t - o] : 0;
        __syncthreads();
        part[t] += v;
        __syncthreads();
    }
    int pbase = (t > 0) ? part[t - 1] : 0;
#pragma unroll
    for (int i = 0; i < 8; ++i) starts[t * 8 + i] = pbase + loc[i];
    if (t == 255) starts[NN] = part[255];
}

__global__ void k_scatter(const int* __restrict__ row, const int* __restrict__ starts,
                          int* __restrict__ cursor, int* __restrict__ eid) {
    int e = blockIdx.x * 256 + threadIdx.x;
    if (e < EE) {
        int r = row[e];
        int slot = atomicAdd(&cursor[r], 1);
        eid[starts[r] + slot] = e;
    }
}

// ---------------- Chebyshev ----------------

__global__ void k_tx0(const float* __restrict__ X, const float* __restrict__ diagS,
                      float* __restrict__ Tx0) {
    size_t idx = (size_t)blockIdx.x * 256 + threadIdx.x;
    Tx0[idx] = X[idx] * diagS[idx >> 9];
}

// out[b][n][:] = (mode ? 2*gather - sub : gather); gather = sum over row-n edges att*x[col]
__global__ void k_prop(const float* __restrict__ x, const float* __restrict__ att,
                       const int* __restrict__ col, const int* __restrict__ starts,
                       const int* __restrict__ eid, const float* __restrict__ sub,
                       float* __restrict__ out, int mode) {
    int bn = blockIdx.x;
    int b = bn >> 11, n = bn & (NN - 1);
    int s0 = starts[n], s1 = starts[n + 1];
    float a0 = 0.f, a1 = 0.f;
    for (int j = s0; j < s1; ++j) {
        int e = eid[j];
        float a = att[(size_t)b * EE + e];
        int c = col[e];
        const float* xr = x + ((size_t)(b * NN + c)) * 512;
        a0 += a * xr[threadIdx.x];
        a1 += a * xr[threadIdx.x + 256];
    }
    size_t o = (size_t)bn * 512;
    if (mode) {
        out[o + threadIdx.x] = 2.f * a0 - sub[o + threadIdx.x];
        out[o + threadIdx.x + 256] = 2.f * a1 - sub[o + threadIdx.x + 256];
    } else {
        out[o + threadIdx.x] = a0;
        out[o + threadIdx.x + 256] = a1;
    }
}

// X_hat[b][n][c][t] = relu(sum_k sum_f Txk[b n f t]*cW[k][f][c] + cb[c])
__global__ void k_cheb(const float* __restrict__ Tx0, const float* __restrict__ Tx1,
                       const float* __restrict__ Tx2, const float* __restrict__ cW,
                       const float* __restrict__ cb, float* __restrict__ Xh) {
    int bn = blockIdx.x;
    __shared__ float xs[3][512];
    const float* src0 = Tx0 + (size_t)bn * 512;
    const float* src1 = Tx1 + (size_t)bn * 512;
    const float* src2 = Tx2 + (size_t)bn * 512;
    xs[0][threadIdx.x] = src0[threadIdx.x]; xs[0][threadIdx.x + 256] = src0[threadIdx.x + 256];
    xs[1][threadIdx.x] = src1[threadIdx.x]; xs[1][threadIdx.x + 256] = src1[threadIdx.x + 256];
    xs[2][threadIdx.x] = src2[threadIdx.x]; xs[2][threadIdx.x + 256] = src2[threadIdx.x + 256];
    __syncthreads();
#pragma unroll
    for (int p = 0; p < 4; ++p) {
        int idx = threadIdx.x + p * 256;   // c*16+t
        int c = idx >> 4, t = idx & 15;
        float v = cb[c];
#pragma unroll
        for (int k = 0; k < 3; ++k)
#pragma unroll
            for (int f = 0; f < 32; ++f)
                v += xs[k][f * 16 + t] * cW[k * 2048 + f * 64 + c];
        Xh[(size_t)bn * 1024 + idx] = fmaxf(v, 0.f);
    }
}

// ---------------- final: temporal conv + residual + LN ----------------

__global__ void k_final(const float* __restrict__ Xh, const float* __restrict__ X,
                        const float* __restrict__ Wt, const float* __restrict__ bt,
                        const float* __restrict__ Wr, const float* __restrict__ br,
                        const float* __restrict__ gamma, const float* __restrict__ beta,
                        float* __restrict__ out) {
    int bn = blockIdx.x;
    __shared__ float xh[64][18];
    __shared__ float xr[512];
    __shared__ float hbuf[16][65];
    __shared__ float mu_s[16], rs_s[16];
    int tid = threadIdx.x;
    if (tid < 128) {
        int c = tid >> 1;
        xh[c][(tid & 1) * 17] = 0.f;
    }
#pragma unroll
    for (int p = 0; p < 4; ++p) {
        int idx = tid + p * 256;
        int c = idx >> 4, t = idx & 15;
        xh[c][t + 1] = Xh[(size_t)bn * 1024 + idx];
    }
    xr[tid] = X[(size_t)bn * 512 + tid];
    xr[tid + 256] = X[(size_t)bn * 512 + tid + 256];
    __syncthreads();
    float hv[4];
#pragma unroll
    for (int p = 0; p < 4; ++p) {
        int idx = tid + p * 256;
        int o = idx >> 4, t = idx & 15;
        float acc = bt[o];
#pragma unroll 8
        for (int c = 0; c < 64; ++c) {
            const float* w = &Wt[(o * 64 + c) * 3];
            acc += xh[c][t] * w[0] + xh[c][t + 1] * w[1] + xh[c][t + 2] * w[2];
        }
        float acr = br[o];
#pragma unroll
        for (int f = 0; f < 32; ++f) acr += xr[f * 16 + t] * Wr[o * 32 + f];
        float h = fmaxf(acc + acr, 0.f);
        hv[p] = h;
        hbuf[t][o] = h;
    }
    __syncthreads();
    {
        int t = tid >> 4, j = tid & 15;
        float s1 = 0.f, s2 = 0.f;
#pragma unroll
        for (int q = 0; q < 4; ++q) {
            float h = hbuf[t][j + q * 16];
            s1 += h;
            s2 += h * h;
        }
#pragma unroll
        for (int m = 8; m >= 1; m >>= 1) {
            s1 += __shfl_xor(s1, m);
            s2 += __shfl_xor(s2, m);
        }
        if (j == 0) {
            float mu = s1 * (1.f / 64.f);
            float var = s2 * (1.f / 64.f) - mu * mu;
            mu_s[t] = mu;
            rs_s[t] = rsqrtf(var + 1e-5f);
        }
    }
    __syncthreads();
#pragma unroll
    for (int p = 0; p < 4; ++p) {
        int idx = tid + p * 256;
        int o = idx >> 4, t = idx & 15;
        out[(size_t)bn * 1024 + idx] = (hv[p] - mu_s[t]) * rs_s[t] * gamma[o] + beta[o];
    }
}

// ---------------- host ----------------

extern "C" void kernel_launch(void* const* d_in, const int* in_sizes, int n_in,
                              void* d_out, int out_size, void* d_ws, size_t ws_size,
                              hipStream_t stream) {
    (void)in_sizes; (void)n_in; (void)out_size; (void)ws_size;
    const float* X = (const float*)d_in[0];
    const int* ei = (const int*)d_in[1];
    const int* row = ei;
    const int* col = ei + EE;
    const float* U1 = (const float*)d_in[2];
    const float* U2 = (const float*)d_in[3];
    const float* U3 = (const float*)d_in[4];
    const float* be = (const float*)d_in[5];
    const float* Ve = (const float*)d_in[6];
    const float* W1 = (const float*)d_in[7];
    const float* W2 = (const float*)d_in[8];
    const float* W3 = (const float*)d_in[9];
    const float* bs = (const float*)d_in[10];
    const float* Vs = (const float*)d_in[11];
    const float* cW = (const float*)d_in[12];
    const float* cb = (const float*)d_in[13];
    const float* Wt = (const float*)d_in[14];
    const float* bt = (const float*)d_in[15];
    const float* Wr = (const float*)d_in[16];
    const float* br = (const float*)d_in[17];
    const float* gamma = (const float*)d_in[18];
    const float* beta = (const float*)d_in[19];
    float* out = (float*)d_out;

    char* w = (char*)d_ws;
    // zero-init region (one memset)
    constexpr size_t OFF_TMP1 = 0;            // 8192
    constexpr size_t OFF_PT = 8192;           // 4096
    constexpr size_t OFF_DEG = 12288;         // 8192
    constexpr size_t OFF_CNT = 20480;         // 8192
    constexpr size_t OFF_CURSOR = 28672;      // 8192
    constexpr size_t ZEND = 36864;
    constexpr size_t OFF_EMAT = ZEND;                     // 4096
    constexpr size_t OFF_LHS = OFF_EMAT + 4096;           // 512K
    constexpr size_t OFF_RHS = OFF_LHS + 524288;          // 512K
    constexpr size_t OFF_LHSS = OFF_RHS + 524288;         // 512K
    constexpr size_t OFF_RHSS = OFF_LHSS + 524288;        // 512K
    constexpr size_t OFF_DIAG = OFF_RHSS + 524288;        // 32K
    constexpr size_t OFF_ATT = OFF_DIAG + 32768;          // 512K
    constexpr size_t OFF_DINV = OFF_ATT + 524288;         // 8K
    constexpr size_t OFF_NORM = OFF_DINV + 8192;          // 128K
    constexpr size_t OFF_STARTS = OFF_NORM + 131072;      // 8448
    constexpr size_t OFF_EID = OFF_STARTS + 8448;         // 128K
    constexpr size_t OFF_VSBF = OFF_EID + 131072;         // 8MB
    constexpr size_t OFF_XT = OFF_VSBF + 8388608;         // 16MB (reused: Tx0)
    constexpr size_t OFF_SIGT = OFF_XT + 16777216;        // 32MB (reused: X_hat)
    constexpr size_t OFF_S = OFF_SIGT + 33554432;         // 64MB (reused: Tx1, Tx2)

    float* tmp1 = (float*)(w + OFF_TMP1);
    float* Pt = (float*)(w + OFF_PT);
    float* deg = (float*)(w + OFF_DEG);
    int* cnt = (int*)(w + OFF_CNT);
    int* cursor = (int*)(w + OFF_CURSOR);
    float* Emat = (float*)(w + OFF_EMAT);
    float* lhs = (float*)(w + OFF_LHS);
    float* rhs = (float*)(w + OFF_RHS);
    float* lhs_s = (float*)(w + OFF_LHSS);
    float* rhs_s = (float*)(w + OFF_RHSS);
    float* diagS = (float*)(w + OFF_DIAG);
    float* att = (float*)(w + OFF_ATT);
    float* dinv = (float*)(w + OFF_DINV);
    float* normv = (float*)(w + OFF_NORM);
    int* starts = (int*)(w + OFF_STARTS);
    int* eid = (int*)(w + OFF_EID);
    unsigned short* Vsbf = (unsigned short*)(w + OFF_VSBF);
    float* Xt = (float*)(w + OFF_XT);
    float* Tx0 = Xt;                           // reuse after spatial_lr
    unsigned short* sigT = (unsigned short*)(w + OFF_SIGT);
    float* Xh = (float*)(w + OFF_SIGT);        // reuse after GEMM
    float* S = (float*)(w + OFF_S);
    float* Tx1 = S;                            // reuse after diag/att extracted
    float* Tx2 = (float*)(w + OFF_S + 16777216);

    hipMemsetAsync(w, 0, ZEND, stream);

    // temporal attention
    k_u1reduce<<<BB * 64, 256, 0, stream>>>(X, U1, tmp1);
    k_mkrhs<<<BB * NN * TT / 256, 256, 0, stream>>>(X, U3, rhs);
    k_mklhs<<<BB * TT * 8, 256, 0, stream>>>(tmp1, U2, lhs);
    k_ptaccum<<<BB * 8, 256, 0, stream>>>(lhs, rhs, Pt);
    k_temporalatt<<<BB, 256, 0, stream>>>(Pt, be, Ve, Emat);
    k_applyemat<<<BB * NN * FIN / 256, 256, 0, stream>>>(X, Emat, Xt);

    // spatial attention
    k_spatiallr<<<BB * (NN / 16), 256, 0, stream>>>(Xt, W1, W2, W3, lhs_s, rhs_s);
    k_f2bf<<<NN * NN / 256, 256, 0, stream>>>(Vs, Vsbf);
    k_makesigT<<<dim3(NN / 64, NN / 64, BB), 256, 0, stream>>>(lhs_s, rhs_s, bs, sigT);
    k_gemm_bt<<<dim3(NN / 128, NN / 128, BB), 256, 0, stream>>>(Vsbf, sigT, S, NN, NN, NN);
    k_softmaxcol<<<BB * (NN / 64), 256, 0, stream>>>(S);

    // graph prep (independent of S except diag/att)
    k_deg<<<EE / 256, 256, 0, stream>>>(row, col, deg);
    k_dinv<<<NN / 256, 256, 0, stream>>>(deg, dinv);
    k_norm<<<EE / 256, 256, 0, stream>>>(row, col, dinv, normv, cnt);
    k_scan<<<1, 256, 0, stream>>>(cnt, starts);
    k_scatter<<<EE / 256, 256, 0, stream>>>(row, starts, cursor, eid);
    k_diagatt<<<BB * EE / 256, 256, 0, stream>>>(S, row, col, normv, diagS, att);

    // chebyshev
    k_tx0<<<BB * NN * 512 / 256, 256, 0, stream>>>(X, diagS, Tx0);
    k_prop<<<BB * NN, 256, 0, stream>>>(Tx0, att, col, starts, eid, nullptr, Tx1, 0);
    k_prop<<<BB * NN, 256, 0, stream>>>(Tx1, att, col, starts, eid, Tx0, Tx2, 1);
    k_cheb<<<BB * NN, 256, 0, stream>>>(Tx0, Tx1, Tx2, cW, cb, Xh);

    // final
    k_final<<<BB * NN, 256, 0, stream>>>(Xh, X, Wt, bt, Wr, br, gamma, beta, out);
}

// Round 2
// 593.379 us; speedup vs baseline: 1.5127x; 1.5127x over previous
//
#include <hip/hip_runtime.h>
#include <hip/hip_bf16.h>

#define BB 4
#define NN 2048
#define FIN 32
#define TT 16
#define EE 32768
#define CC 64
#define TFo 64
#define NSPLIT 16

typedef __attribute__((ext_vector_type(8))) short bf16x8;
typedef __attribute__((ext_vector_type(4))) float f32x4;

typedef __attribute__((address_space(1))) const unsigned int as1_uint;
typedef __attribute__((address_space(3))) unsigned int as3_uint;

__device__ __forceinline__ void gload_lds16(const void* g, void* l) {
    __builtin_amdgcn_global_load_lds((as1_uint*)g, (as3_uint*)l, 16, 0, 0);
}

__device__ __forceinline__ unsigned short f2bf(float v) {
    unsigned u = __builtin_bit_cast(unsigned, v);
    unsigned r = (u + 0x7fffu + ((u >> 16) & 1u)) >> 16;
    return (unsigned short)r;
}

// ---------------- Stage A: temporal attention ----------------

// tmp1[b][f][t] = sum_n X[b][n][f][t] * U1[n]   (atomic accumulate, tmp1 pre-zeroed)
__global__ void k_u1reduce(const float* __restrict__ X, const float* __restrict__ U1,
                           float* __restrict__ tmp1) {
    int b = blockIdx.x >> 6;
    int n0 = (blockIdx.x & 63) * 32;
    float a0 = 0.f, a1 = 0.f;
    for (int i = 0; i < 32; ++i) {
        int n = n0 + i;
        float u = U1[n];
        const float* row = X + ((size_t)(b * NN + n)) * 512;
        a0 += u * row[threadIdx.x];
        a1 += u * row[threadIdx.x + 256];
    }
    atomicAdd(&tmp1[b * 512 + threadIdx.x], a0);
    atomicAdd(&tmp1[b * 512 + threadIdx.x + 256], a1);
}

// lhs[b][t][n'] = sum_f tmp1[b][f][t] * U2[f][n']
__global__ void k_mklhs(const float* __restrict__ tmp1, const float* __restrict__ U2,
                        float* __restrict__ lhs) {
    int npr = ((blockIdx.x & 7) << 8) + threadIdx.x;
    int bt = blockIdx.x >> 3;           // b*16 + t
    int b = bt >> 4, t = bt & 15;
    float acc = 0.f;
#pragma unroll
    for (int f = 0; f < 32; ++f) acc += tmp1[b * 512 + f * 16 + t] * U2[f * NN + npr];
    lhs[(size_t)bt * NN + npr] = acc;
}

// rhs[b][n][t] = sum_f U3[f]*X[b][n][f][t]
__global__ void k_mkrhs(const float* __restrict__ X, const float* __restrict__ U3,
                        float* __restrict__ rhs) {
    int idx = blockIdx.x * 256 + threadIdx.x;   // B*N*T
    int t = idx & 15;
    int bn = idx >> 4;
    float acc = 0.f;
#pragma unroll
    for (int f = 0; f < 32; ++f) acc += U3[f] * X[(size_t)bn * 512 + f * 16 + t];
    rhs[idx] = acc;
}

// Pt[b][t][s] += sum over n-chunk lhs[b][t][n]*rhs[b][n][s]   (Pt pre-zeroed)
__global__ void k_ptaccum(const float* __restrict__ lhs, const float* __restrict__ rhs,
                          float* __restrict__ Pt) {
    int b = blockIdx.x >> 3;
    int n0 = (blockIdx.x & 7) * 256;
    int t = threadIdx.x >> 4, s = threadIdx.x & 15;
    const float* lr = lhs + (size_t)b * TT * NN + (size_t)t * NN;
    const float* rr = rhs + (size_t)b * NN * TT;
    float acc = 0.f;
    for (int i = 0; i < 256; ++i) {
        int n = n0 + i;
        acc += lr[n] * rr[n * 16 + s];
    }
    atomicAdd(&Pt[b * 256 + threadIdx.x], acc);
}

// Emat[b][t][s]: sigmoid(+be), Ve-multiply, softmax over t
__global__ void k_temporalatt(const float* __restrict__ Pt, const float* __restrict__ be,
                              const float* __restrict__ Ve, float* __restrict__ Emat) {
    int b = blockIdx.x;
    int t = threadIdx.x >> 4, s = threadIdx.x & 15;
    __shared__ float sg[16][17];
    __shared__ float em[16][17];
    float v = Pt[b * 256 + t * 16 + s] + be[t * 16 + s];
    sg[t][s] = 1.f / (1.f + __expf(-v));
    __syncthreads();
    float e = 0.f;
#pragma unroll
    for (int u = 0; u < 16; ++u) e += Ve[t * 16 + u] * sg[u][s];
    em[t][s] = e;
    __syncthreads();
    float mx = -1e30f;
#pragma unroll
    for (int u = 0; u < 16; ++u) mx = fmaxf(mx, em[u][s]);
    float sum = 0.f;
#pragma unroll
    for (int u = 0; u < 16; ++u) sum += __expf(em[u][s] - mx);
    Emat[b * 256 + t * 16 + s] = __expf(e - mx) / sum;
}

// Xt[b][n][f][s] = sum_t X[b][n][f][t]*Emat[b][t][s]
__global__ void k_applyemat(const float* __restrict__ X, const float* __restrict__ Emat,
                            float* __restrict__ Xt) {
    __shared__ float em[256];
    int b = blockIdx.x >> 8;   // 256 blocks per batch
    em[threadIdx.x] = Emat[b * 256 + threadIdx.x];
    __syncthreads();
    size_t base = ((size_t)blockIdx.x * 256 + threadIdx.x) * 16;
    float x[16], o[16];
    const float4* xp = (const float4*)(X + base);
#pragma unroll
    for (int q = 0; q < 4; ++q) {
        float4 a = xp[q];
        x[q * 4 + 0] = a.x; x[q * 4 + 1] = a.y; x[q * 4 + 2] = a.z; x[q * 4 + 3] = a.w;
    }
#pragma unroll
    for (int s = 0; s < 16; ++s) {
        float acc = 0.f;
#pragma unroll
        for (int t = 0; t < 16; ++t) acc += x[t] * em[t * 16 + s];
        o[s] = acc;
    }
    float4* op = (float4*)(Xt + base);
#pragma unroll
    for (int q = 0; q < 4; ++q) op[q] = make_float4(o[q*4+0], o[q*4+1], o[q*4+2], o[q*4+3]);
}

// ---------------- Stage B: spatial attention small parts ----------------

// lhs_s[b][n][t], rhs_s[b][t][n] from Xt
__global__ void k_spatiallr(const float* __restrict__ Xt, const float* __restrict__ W1,
                            const float* __restrict__ W2, const float* __restrict__ W3,
                            float* __restrict__ lhs_s, float* __restrict__ rhs_s) {
    int b = blockIdx.x >> 7;
    int n0 = (blockIdx.x & 127) * 16;
    __shared__ float xb[16 * 512];
    __shared__ float av[16 * 32];
    const float* src = Xt + ((size_t)(b * NN + n0)) * 512;
    for (int i = 0; i < 32; ++i) xb[threadIdx.x + i * 256] = src[threadIdx.x + i * 256];
    __syncthreads();
#pragma unroll
    for (int ii = 0; ii < 2; ++ii) {
        int idx = threadIdx.x * 2 + ii;   // nl*32+f
        float acc = 0.f;
        const float* xr = &xb[idx * 16];
#pragma unroll
        for (int t = 0; t < 16; ++t) acc += xr[t] * W1[t];
        av[idx] = acc;
    }
    __syncthreads();
    int nl = threadIdx.x >> 4, t = threadIdx.x & 15;
    float r = 0.f;
#pragma unroll
    for (int f = 0; f < 32; ++f) r += W3[f] * xb[nl * 512 + f * 16 + t];
    rhs_s[(size_t)b * TT * NN + (size_t)t * NN + n0 + nl] = r;
    float l = 0.f;
#pragma unroll
    for (int f = 0; f < 32; ++f) l += av[nl * 32 + f] * W2[f * 16 + t];
    lhs_s[((size_t)(b * NN + n0 + nl)) * 16 + t] = l;
}

// Vs fp32 -> bf16
__global__ void k_f2bf(const float* __restrict__ src, unsigned short* __restrict__ dst) {
    int i = blockIdx.x * 256 + threadIdx.x;
    dst[i] = f2bf(src[i]);
}

// sigT[b][k][m] = bf16(sigmoid(dot(lhs_s[b,m,:], rhs_s[b,:,k]) + bs[m,k]))
__global__ void k_makesigT(const float* __restrict__ lhs_s, const float* __restrict__ rhs_s,
                           const float* __restrict__ bs, unsigned short* __restrict__ sigT) {
    int k0 = blockIdx.x * 64, m0 = blockIdx.y * 64, b = blockIdx.z;
    __shared__ float lh[64][17];
    __shared__ float rh[16][64];
    __shared__ float bsl[64][65];
    int tid = threadIdx.x;
#pragma unroll
    for (int i = 0; i < 4; ++i) {
        int idx = tid + i * 256;
        int mi = idx >> 4, t = idx & 15;
        lh[mi][t] = lhs_s[((size_t)(b * NN + m0 + mi)) * 16 + t];
        int tt = idx >> 6, kj = idx & 63;
        rh[tt][kj] = rhs_s[(size_t)b * TT * NN + (size_t)tt * NN + k0 + kj];
    }
#pragma unroll
    for (int i = 0; i < 16; ++i) {
        int idx = tid + i * 256;
        int mi = idx >> 6, kj = idx & 63;
        bsl[mi][kj] = bs[(size_t)(m0 + mi) * NN + k0 + kj];
    }
    __syncthreads();
    int ml = tid & 63;
    int kg = (tid >> 6) * 16;
    unsigned short* out = sigT + (size_t)b * NN * NN;
#pragma unroll 4
    for (int ki = 0; ki < 16; ++ki) {
        int kl = kg + ki;
        float acc = bsl[ml][kl];
#pragma unroll
        for (int t = 0; t < 16; ++t) acc += lh[ml][t] * rh[t][kl];
        float sgv = 1.f / (1.f + __expf(-acc));
        out[(size_t)(k0 + kl) * NN + m0 + ml] = f2bf(sgv);
    }
}

// ---------------- The big GEMM: S[b][n][k] = sum_m Vs[n][m]*sigT[b][k][m] ----------------

__global__ __launch_bounds__(256) void k_gemm_bt(const unsigned short* __restrict__ A,
                                                 const unsigned short* __restrict__ Bt,
                                                 float* __restrict__ C,
                                                 int M, int N, int K) {
    __shared__ __align__(16) unsigned short lds[2][2][128 * 32];
    const int tid = threadIdx.x;
    const int wave = tid >> 6, lane = tid & 63;
    const int bm = blockIdx.y << 7;
    const int bn = blockIdx.x << 7;
    const unsigned short* Bb = Bt + (size_t)blockIdx.z * N * K;
    float* Cb = C + (size_t)blockIdx.z * M * N;
    const int wr = wave >> 1, wc = wave & 1;
    const int srow = lane >> 2, scol = (lane & 3) << 3;

    f32x4 acc[4][4];
#pragma unroll
    for (int i = 0; i < 4; ++i)
#pragma unroll
        for (int j = 0; j < 4; ++j) acc[i][j] = (f32x4){0.f, 0.f, 0.f, 0.f};

    const size_t abase = (size_t)(bm + srow) * K + scol;
    const size_t bbase = (size_t)(bn + srow) * K + scol;

#define STAGE(buf, k0)                                                              \
    {                                                                               \
        _Pragma("unroll")                                                           \
        for (int ii = 0; ii < 2; ++ii) {                                            \
            int rb = ((ii << 2) + wave) << 4;                                       \
            gload_lds16(A + abase + (size_t)rb * K + (k0), &lds[buf][0][rb * 32]);  \
            gload_lds16(Bb + bbase + (size_t)rb * K + (k0), &lds[buf][1][rb * 32]); \
        }                                                                           \
    }

    STAGE(0, 0)
    __syncthreads();
    const int nk = K >> 5;
    const int rl = lane & 15, kg = (lane >> 4) << 3;
    for (int t = 0; t < nk; ++t) {
        int cur = t & 1;
        if (t + 1 < nk) STAGE(cur ^ 1, (t + 1) << 5)
        const unsigned short* la = &lds[cur][0][0];
        const unsigned short* lb = &lds[cur][1][0];
        bf16x8 af[4], bfr[4];
#pragma unroll
        for (int i = 0; i < 4; ++i) af[i] = *(const bf16x8*)(la + ((wr << 6) + (i << 4) + rl) * 32 + kg);
#pragma unroll
        for (int j = 0; j < 4; ++j) bfr[j] = *(const bf16x8*)(lb + ((wc << 6) + (j << 4) + rl) * 32 + kg);
#pragma unroll
        for (int i = 0; i < 4; ++i)
#pragma unroll
            for (int j = 0; j < 4; ++j)
                acc[i][j] = __builtin_amdgcn_mfma_f32_16x16x32_bf16(af[i], bfr[j], acc[i][j], 0, 0, 0);
        __syncthreads();
    }
#undef STAGE
    const int cl = lane & 15, rg = (lane >> 4) << 2;
#pragma unroll
    for (int i = 0; i < 4; ++i)
#pragma unroll
        for (int j = 0; j < 4; ++j) {
            int m0 = bm + (wr << 6) + (i << 4) + rg;
            int n0 = bn + (wc << 6) + (j << 4) + cl;
#pragma unroll
            for (int r = 0; r < 4; ++r) Cb[(size_t)(m0 + r) * N + n0] = acc[i][j][r];
        }
}

// ---------------- column softmax statistics (only stats are needed!) ----------------
// pass 1: partial (max,sum) per (b, nsplit, k) — reads raw S once
__global__ void k_colreduce1(const float* __restrict__ S, float* __restrict__ pm,
                             float* __restrict__ ps) {
    int b = blockIdx.z;
    int k0 = blockIdx.x << 8;          // 8 chunks of 256 k
    int nbase = blockIdx.y << 7;       // NSPLIT=16 splits of 128 rows
    int ktl = threadIdx.x & 63;        // float4 column within chunk
    int g = threadIdx.x >> 6;          // 4 row-groups
    const float* base = S + (size_t)b * NN * NN + k0 + (ktl << 2);
    float m0 = -1e30f, m1 = -1e30f, m2 = -1e30f, m3 = -1e30f;
    float s0 = 0.f, s1 = 0.f, s2 = 0.f, s3 = 0.f;
    for (int i = g; i < 128; i += 4) {
        float4 v = *(const float4*)(base + (size_t)(nbase + i) * NN);
        float nm;
        nm = fmaxf(m0, v.x); s0 = s0 * __expf(m0 - nm) + __expf(v.x - nm); m0 = nm;
        nm = fmaxf(m1, v.y); s1 = s1 * __expf(m1 - nm) + __expf(v.y - nm); m1 = nm;
        nm = fmaxf(m2, v.z); s2 = s2 * __expf(m2 - nm) + __expf(v.z - nm); m2 = nm;
        nm = fmaxf(m3, v.w); s3 = s3 * __expf(m3 - nm) + __expf(v.w - nm); m3 = nm;
    }
    __shared__ float sm[4][64][4], ss[4][64][4];
    sm[g][ktl][0] = m0; sm[g][ktl][1] = m1; sm[g][ktl][2] = m2; sm[g][ktl][3] = m3;
    ss[g][ktl][0] = s0; ss[g][ktl][1] = s1; ss[g][ktl][2] = s2; ss[g][ktl][3] = s3;
    __syncthreads();
    int kc = threadIdx.x;              // 0..255 output column within chunk
    float M = sm[0][kc >> 2][kc & 3], Ssum = ss[0][kc >> 2][kc & 3];
#pragma unroll
    for (int gi = 1; gi < 4; ++gi) {
        float mm = sm[gi][kc >> 2][kc & 3], sv = ss[gi][kc >> 2][kc & 3];
        float nm = fmaxf(M, mm);
        Ssum = Ssum * __expf(M - nm) + sv * __expf(mm - nm);
        M = nm;
    }
    size_t o = ((size_t)(b * NSPLIT + blockIdx.y) * NN) + k0 + kc;
    pm[o] = M; ps[o] = Ssum;
}

// pass 2: combine NSPLIT partials -> Mf[b][k], Inv[b][k]
__global__ void k_colreduce2(const float* __restrict__ pm, const float* __restrict__ ps,
                             float* __restrict__ Mf, float* __restrict__ Inv) {
    int idx = blockIdx.x * 256 + threadIdx.x;   // b*NN + k
    int b = idx >> 11, k = idx & (NN - 1);
    float M = -1e30f, Ssum = 0.f;
#pragma unroll
    for (int i = 0; i < NSPLIT; ++i) {
        size_t o = ((size_t)(b * NSPLIT + i) * NN) + k;
        float mm = pm[o], sv = ps[o];
        float nm = fmaxf(M, mm);
        Ssum = Ssum * __expf(M - nm) + sv * __expf(mm - nm);
        M = nm;
    }
    Mf[idx] = M;
    Inv[idx] = 1.f / Ssum;
}

// diagS[b][n] = softmax(S)[b][n][n]; att[b][e] = norm[e]*softmax(S)[b][row[e]][col[e]]
// computed on the fly from raw S + column stats
__global__ void k_diagatt(const float* __restrict__ S, const int* __restrict__ row,
                          const int* __restrict__ col, const float* __restrict__ norm,
                          const float* __restrict__ Mf, const float* __restrict__ Inv,
                          float* __restrict__ diagS, float* __restrict__ att) {
    int idx = blockIdx.x * 256 + threadIdx.x;
    if (idx < BB * EE) {
        int b = idx >> 15, e = idx & (EE - 1);
        int c = col[e];
        float v = S[(size_t)b * NN * NN + (size_t)row[e] * NN + c];
        att[idx] = norm[e] * __expf(v - Mf[b * NN + c]) * Inv[b * NN + c];
    }
    if (idx < BB * NN) {
        float v = S[(size_t)(idx >> 11) * NN * NN + (size_t)(idx & (NN - 1)) * NN + (idx & (NN - 1))];
        diagS[idx] = __expf(v - Mf[idx]) * Inv[idx];
    }
}

// ---------------- graph prep ----------------

__global__ void k_deg(const int* __restrict__ row, const int* __restrict__ col,
                      float* __restrict__ deg) {
    int e = blockIdx.x * 256 + threadIdx.x;
    if (e < EE && row[e] != col[e]) atomicAdd(&deg[row[e]], 1.0f);
}

__global__ void k_dinv(const float* __restrict__ deg, float* __restrict__ dinv) {
    int n = blockIdx.x * 256 + threadIdx.x;
    if (n < NN) {
        float d = deg[n];
        dinv[n] = d > 0.f ? rsqrtf(fmaxf(d, 1e-12f)) : 0.f;
    }
}

__global__ void k_norm(const int* __restrict__ row, const int* __restrict__ col,
                       const float* __restrict__ dinv, float* __restrict__ norm,
                       int* __restrict__ cnt) {
    int e = blockIdx.x * 256 + threadIdx.x;
    if (e < EE) {
        int r = row[e], c = col[e];
        float w = (r != c) ? 1.f : 0.f;
        norm[e] = -dinv[r] * w * dinv[c];
        atomicAdd(&cnt[r], 1);
    }
}

// exclusive scan of cnt[2048] -> starts[2049], single block of 256
__global__ void k_scan(const int* __restrict__ cnt, int* __restrict__ starts) {
    __shared__ int part[256];
    int t = threadIdx.x;
    int loc[8];
    int s = 0;
#pragma unroll
    for (int i = 0; i < 8; ++i) {
        int c = cnt[t * 8 + i];
        loc[i] = s;
        s += c;
    }
    part[t] = s;
    __syncthreads();
    for (int o = 1; o < 256; o <<= 1) {
        int v = (t >= o) ? part[t - o] : 0;
        __syncthreads();
        part[t] += v;
        __syncthreads();
    }
    int pbase = (t > 0) ? part[t - 1] : 0;
#pragma unroll
    for (int i = 0; i < 8; ++i) starts[t * 8 + i] = pbase + loc[i];
    if (t == 255) starts[NN] = part[255];
}

__global__ void k_scatter(const int* __restrict__ row, const int* __restrict__ starts,
                          int* __restrict__ cursor, int* __restrict__ eid) {
    int e = blockIdx.x * 256 + threadIdx.x;
    if (e < EE) {
        int r = row[e];
        int slot = atomicAdd(&cursor[r], 1);
        eid[starts[r] + slot] = e;
    }
}

// ---------------- Chebyshev ----------------

__global__ void k_tx0(const float* __restrict__ X, const float* __restrict__ diagS,
                      float* __restrict__ Tx0) {
    size_t idx = (size_t)blockIdx.x * 256 + threadIdx.x;
    Tx0[idx] = X[idx] * diagS[idx >> 9];
}

// out[b][n][:] = (mode ? 2*gather - sub : gather); gather = sum over row-n edges att*x[col]
__global__ void k_prop(const float* __restrict__ x, const float* __restrict__ att,
                       const int* __restrict__ col, const int* __restrict__ starts,
                       const int* __restrict__ eid, const float* __restrict__ sub,
                       float* __restrict__ out, int mode) {
    int bn = blockIdx.x;
    int b = bn >> 11, n = bn & (NN - 1);
    int s0 = starts[n], s1 = starts[n + 1];
    float a0 = 0.f, a1 = 0.f;
    for (int j = s0; j < s1; ++j) {
        int e = eid[j];
        float a = att[(size_t)b * EE + e];
        int c = col[e];
        const float* xr = x + ((size_t)(b * NN + c)) * 512;
        a0 += a * xr[threadIdx.x];
        a1 += a * xr[threadIdx.x + 256];
    }
    size_t o = (size_t)bn * 512;
    if (mode) {
        out[o + threadIdx.x] = 2.f * a0 - sub[o + threadIdx.x];
        out[o + threadIdx.x + 256] = 2.f * a1 - sub[o + threadIdx.x + 256];
    } else {
        out[o + threadIdx.x] = a0;
        out[o + threadIdx.x + 256] = a1;
    }
}

// X_hat[b][n][c][t] = relu(sum_k sum_f Txk[b n f t]*cW[k][f][c] + cb[c])
__global__ void k_cheb(const float* __restrict__ Tx0, const float* __restrict__ Tx1,
                       const float* __restrict__ Tx2, const float* __restrict__ cW,
                       const float* __restrict__ cb, float* __restrict__ Xh) {
    int bn = blockIdx.x;
    __shared__ float xs[3][512];
    const float* src0 = Tx0 + (size_t)bn * 512;
    const float* src1 = Tx1 + (size_t)bn * 512;
    const float* src2 = Tx2 + (size_t)bn * 512;
    xs[0][threadIdx.x] = src0[threadIdx.x]; xs[0][threadIdx.x + 256] = src0[threadIdx.x + 256];
    xs[1][threadIdx.x] = src1[threadIdx.x]; xs[1][threadIdx.x + 256] = src1[threadIdx.x + 256];
    xs[2][threadIdx.x] = src2[threadIdx.x]; xs[2][threadIdx.x + 256] = src2[threadIdx.x + 256];
    __syncthreads();
#pragma unroll
    for (int p = 0; p < 4; ++p) {
        int idx = threadIdx.x + p * 256;   // c*16+t
        int c = idx >> 4, t = idx & 15;
        float v = cb[c];
#pragma unroll
        for (int k = 0; k < 3; ++k)
#pragma unroll
            for (int f = 0; f < 32; ++f)
                v += xs[k][f * 16 + t] * cW[k * 2048 + f * 64 + c];
        Xh[(size_t)bn * 1024 + idx] = fmaxf(v, 0.f);
    }
}

// ---------------- final: temporal conv + residual + LN ----------------

__global__ void k_final(const float* __restrict__ Xh, const float* __restrict__ X,
                        const float* __restrict__ Wt, const float* __restrict__ bt,
                        const float* __restrict__ Wr, const float* __restrict__ br,
                        const float* __restrict__ gamma, const float* __restrict__ beta,
                        float* __restrict__ out) {
    int bn = blockIdx.x;
    __shared__ float xh[64][18];
    __shared__ float xr[512];
    __shared__ float hbuf[16][65];
    __shared__ float mu_s[16], rs_s[16];
    int tid = threadIdx.x;
    if (tid < 128) {
        int c = tid >> 1;
        xh[c][(tid & 1) * 17] = 0.f;
    }
#pragma unroll
    for (int p = 0; p < 4; ++p) {
        int idx = tid + p * 256;
        int c = idx >> 4, t = idx & 15;
        xh[c][t + 1] = Xh[(size_t)bn * 1024 + idx];
    }
    xr[tid] = X[(size_t)bn * 512 + tid];
    xr[tid + 256] = X[(size_t)bn * 512 + tid + 256];
    __syncthreads();
    float hv[4];
#pragma unroll
    for (int p = 0; p < 4; ++p) {
        int idx = tid + p * 256;
        int o = idx >> 4, t = idx & 15;
        float acc = bt[o];
#pragma unroll 8
        for (int c = 0; c < 64; ++c) {
            const float* w = &Wt[(o * 64 + c) * 3];
            acc += xh[c][t] * w[0] + xh[c][t + 1] * w[1] + xh[c][t + 2] * w[2];
        }
        float acr = br[o];
#pragma unroll
        for (int f = 0; f < 32; ++f) acr += xr[f * 16 + t] * Wr[o * 32 + f];
        float h = fmaxf(acc + acr, 0.f);
        hv[p] = h;
        hbuf[t][o] = h;
    }
    __syncthreads();
    {
        int t = tid >> 4, j = tid & 15;
        float s1 = 0.f, s2 = 0.f;
#pragma unroll
        for (int q = 0; q < 4; ++q) {
            float h = hbuf[t][j + q * 16];
            s1 += h;
            s2 += h * h;
        }
#pragma unroll
        for (int m = 8; m >= 1; m >>= 1) {
            s1 += __shfl_xor(s1, m);
            s2 += __shfl_xor(s2, m);
        }
        if (j == 0) {
            float mu = s1 * (1.f / 64.f);
            float var = s2 * (1.f / 64.f) - mu * mu;
            mu_s[t] = mu;
            rs_s[t] = rsqrtf(var + 1e-5f);
        }
    }
    __syncthreads();
#pragma unroll
    for (int p = 0; p < 4; ++p) {
        int idx = tid + p * 256;
        int o = idx >> 4, t = idx & 15;
        out[(size_t)bn * 1024 + idx] = (hv[p] - mu_s[t]) * rs_s[t] * gamma[o] + beta[o];
    }
}

// ---------------- host ----------------

extern "C" void kernel_launch(void* const* d_in, const int* in_sizes, int n_in,
                              void* d_out, int out_size, void* d_ws, size_t ws_size,
                              hipStream_t stream) {
    (void)in_sizes; (void)n_in; (void)out_size; (void)ws_size;
    const float* X = (const float*)d_in[0];
    const int* ei = (const int*)d_in[1];
    const int* row = ei;
    const int* col = ei + EE;
    const float* U1 = (const float*)d_in[2];
    const float* U2 = (const float*)d_in[3];
    const float* U3 = (const float*)d_in[4];
    const float* be = (const float*)d_in[5];
    const float* Ve = (const float*)d_in[6];
    const float* W1 = (const float*)d_in[7];
    const float* W2 = (const float*)d_in[8];
    const float* W3 = (const float*)d_in[9];
    const float* bs = (const float*)d_in[10];
    const float* Vs = (const float*)d_in[11];
    const float* cW = (const float*)d_in[12];
    const float* cb = (const float*)d_in[13];
    const float* Wt = (const float*)d_in[14];
    const float* bt = (const float*)d_in[15];
    const float* Wr = (const float*)d_in[16];
    const float* br = (const float*)d_in[17];
    const float* gamma = (const float*)d_in[18];
    const float* beta = (const float*)d_in[19];
    float* out = (float*)d_out;

    char* w = (char*)d_ws;
    // zero-init region (one memset)
    constexpr size_t OFF_TMP1 = 0;            // 8192
    constexpr size_t OFF_PT = 8192;           // 4096
    constexpr size_t OFF_DEG = 12288;         // 8192
    constexpr size_t OFF_CNT = 20480;         // 8192
    constexpr size_t OFF_CURSOR = 28672;      // 8192
    constexpr size_t ZEND = 36864;
    constexpr size_t OFF_EMAT = ZEND;                     // 4096
    constexpr size_t OFF_LHS = OFF_EMAT + 4096;           // 512K
    constexpr size_t OFF_RHS = OFF_LHS + 524288;          // 512K
    constexpr size_t OFF_LHSS = OFF_RHS + 524288;         // 512K
    constexpr size_t OFF_RHSS = OFF_LHSS + 524288;        // 512K
    constexpr size_t OFF_DIAG = OFF_RHSS + 524288;        // 32K
    constexpr size_t OFF_ATT = OFF_DIAG + 32768;          // 512K
    constexpr size_t OFF_DINV = OFF_ATT + 524288;         // 8K
    constexpr size_t OFF_NORM = OFF_DINV + 8192;          // 128K
    constexpr size_t OFF_STARTS = OFF_NORM + 131072;      // 8448
    constexpr size_t OFF_EID = OFF_STARTS + 8448;         // 128K
    constexpr size_t OFF_VSBF = OFF_EID + 131072;         // 8MB (reused: pm/ps/Mf/Inv)
    constexpr size_t OFF_XT = OFF_VSBF + 8388608;         // 16MB (reused: Tx0)
    constexpr size_t OFF_SIGT = OFF_XT + 16777216;        // 32MB (reused: X_hat)
    constexpr size_t OFF_S = OFF_SIGT + 33554432;         // 64MB (reused: Tx1, Tx2)

    float* tmp1 = (float*)(w + OFF_TMP1);
    float* Pt = (float*)(w + OFF_PT);
    float* deg = (float*)(w + OFF_DEG);
    int* cnt = (int*)(w + OFF_CNT);
    int* cursor = (int*)(w + OFF_CURSOR);
    float* Emat = (float*)(w + OFF_EMAT);
    float* lhs = (float*)(w + OFF_LHS);
    float* rhs = (float*)(w + OFF_RHS);
    float* lhs_s = (float*)(w + OFF_LHSS);
    float* rhs_s = (float*)(w + OFF_RHSS);
    float* diagS = (float*)(w + OFF_DIAG);
    float* att = (float*)(w + OFF_ATT);
    float* dinv = (float*)(w + OFF_DINV);
    float* normv = (float*)(w + OFF_NORM);
    int* starts = (int*)(w + OFF_STARTS);
    int* eid = (int*)(w + OFF_EID);
    unsigned short* Vsbf = (unsigned short*)(w + OFF_VSBF);
    // after k_gemm_bt, the Vsbf region is dead -> reuse for softmax stats
    float* pm = (float*)(w + OFF_VSBF);                   // 512K (B*NSPLIT*NN)
    float* ps = (float*)(w + OFF_VSBF + 524288);          // 512K
    float* Mf = (float*)(w + OFF_VSBF + 1048576);         // 32K
    float* Inv = (float*)(w + OFF_VSBF + 1048576 + 32768);// 32K
    float* Xt = (float*)(w + OFF_XT);
    float* Tx0 = Xt;                           // reuse after spatial_lr
    unsigned short* sigT = (unsigned short*)(w + OFF_SIGT);
    float* Xh = (float*)(w + OFF_SIGT);        // reuse after GEMM
    float* S = (float*)(w + OFF_S);
    float* Tx1 = S;                            // reuse after diag/att extracted
    float* Tx2 = (float*)(w + OFF_S + 16777216);

    hipMemsetAsync(w, 0, ZEND, stream);

    // temporal attention
    k_u1reduce<<<BB * 64, 256, 0, stream>>>(X, U1, tmp1);
    k_mkrhs<<<BB * NN * TT / 256, 256, 0, stream>>>(X, U3, rhs);
    k_mklhs<<<BB * TT * 8, 256, 0, stream>>>(tmp1, U2, lhs);
    k_ptaccum<<<BB * 8, 256, 0, stream>>>(lhs, rhs, Pt);
    k_temporalatt<<<BB, 256, 0, stream>>>(Pt, be, Ve, Emat);
    k_applyemat<<<BB * NN * FIN / 256, 256, 0, stream>>>(X, Emat, Xt);

    // spatial attention
    k_spatiallr<<<BB * (NN / 16), 256, 0, stream>>>(Xt, W1, W2, W3, lhs_s, rhs_s);
    k_f2bf<<<NN * NN / 256, 256, 0, stream>>>(Vs, Vsbf);
    k_makesigT<<<dim3(NN / 64, NN / 64, BB), 256, 0, stream>>>(lhs_s, rhs_s, bs, sigT);
    k_gemm_bt<<<dim3(NN / 128, NN / 128, BB), 256, 0, stream>>>(Vsbf, sigT, S, NN, NN, NN);

    // softmax statistics only (full normalized S never materialized)
    k_colreduce1<<<dim3(8, NSPLIT, BB), 256, 0, stream>>>(S, pm, ps);
    k_colreduce2<<<BB * NN / 256, 256, 0, stream>>>(pm, ps, Mf, Inv);

    // graph prep (independent of S)
    k_deg<<<EE / 256, 256, 0, stream>>>(row, col, deg);
    k_dinv<<<NN / 256, 256, 0, stream>>>(deg, dinv);
    k_norm<<<EE / 256, 256, 0, stream>>>(row, col, dinv, normv, cnt);
    k_scan<<<1, 256, 0, stream>>>(cnt, starts);
    k_scatter<<<EE / 256, 256, 0, stream>>>(row, starts, cursor, eid);
    k_diagatt<<<BB * EE / 256, 256, 0, stream>>>(S, row, col, normv, Mf, Inv, diagS, att);

    // chebyshev
    k_tx0<<<BB * NN * 512 / 256, 256, 0, stream>>>(X, diagS, Tx0);
    k_prop<<<BB * NN, 256, 0, stream>>>(Tx0, att, col, starts, eid, nullptr, Tx1, 0);
    k_prop<<<BB * NN, 256, 0, stream>>>(Tx1, att, col, starts, eid, Tx0, Tx2, 1);
    k_cheb<<<BB * NN, 256, 0, stream>>>(Tx0, Tx1, Tx2, cW, cb, Xh);

    // final
    k_final<<<BB * NN, 256, 0, stream>>>(Xh, X, Wt, bt, Wr, br, gamma, beta, out);
}

// Round 3
// 466.593 us; speedup vs baseline: 1.9237x; 1.2717x over previous
//
#include <hip/hip_runtime.h>
#include <hip/hip_bf16.h>

#define BB 4
#define NN 2048
#define FIN 32
#define TT 16
#define EE 32768
#define CC 64
#define TFo 64
#define NSPLIT 16

typedef __attribute__((ext_vector_type(8))) short bf16x8;
typedef __attribute__((ext_vector_type(4))) float f32x4;

typedef __attribute__((address_space(1))) const unsigned int as1_uint;
typedef __attribute__((address_space(3))) unsigned int as3_uint;

__device__ __forceinline__ void gload_lds16(const void* g, void* l) {
    __builtin_amdgcn_global_load_lds((as1_uint*)g, (as3_uint*)l, 16, 0, 0);
}

__device__ __forceinline__ unsigned short f2bf(float v) {
    unsigned u = __builtin_bit_cast(unsigned, v);
    unsigned r = (u + 0x7fffu + ((u >> 16) & 1u)) >> 16;
    return (unsigned short)r;
}

// ---------------- Stage A: temporal attention ----------------

// tmp1[b][f][t] = sum_n X[b][n][f][t] * U1[n]   (atomic accumulate, tmp1 pre-zeroed)
__global__ void k_u1reduce(const float* __restrict__ X, const float* __restrict__ U1,
                           float* __restrict__ tmp1) {
    int b = blockIdx.x >> 6;
    int n0 = (blockIdx.x & 63) * 32;
    float a0 = 0.f, a1 = 0.f;
    for (int i = 0; i < 32; ++i) {
        int n = n0 + i;
        float u = U1[n];
        const float* row = X + ((size_t)(b * NN + n)) * 512;
        a0 += u * row[threadIdx.x];
        a1 += u * row[threadIdx.x + 256];
    }
    atomicAdd(&tmp1[b * 512 + threadIdx.x], a0);
    atomicAdd(&tmp1[b * 512 + threadIdx.x + 256], a1);
}

// lhs[b][t][n'] = sum_f tmp1[b][f][t] * U2[f][n']
__global__ void k_mklhs(const float* __restrict__ tmp1, const float* __restrict__ U2,
                        float* __restrict__ lhs) {
    int npr = ((blockIdx.x & 7) << 8) + threadIdx.x;
    int bt = blockIdx.x >> 3;           // b*16 + t
    int b = bt >> 4, t = bt & 15;
    float acc = 0.f;
#pragma unroll
    for (int f = 0; f < 32; ++f) acc += tmp1[b * 512 + f * 16 + t] * U2[f * NN + npr];
    lhs[(size_t)bt * NN + npr] = acc;
}

// rhs[b][n][t] = sum_f U3[f]*X[b][n][f][t]
__global__ void k_mkrhs(const float* __restrict__ X, const float* __restrict__ U3,
                        float* __restrict__ rhs) {
    int idx = blockIdx.x * 256 + threadIdx.x;   // B*N*T
    int t = idx & 15;
    int bn = idx >> 4;
    float acc = 0.f;
#pragma unroll
    for (int f = 0; f < 32; ++f) acc += U3[f] * X[(size_t)bn * 512 + f * 16 + t];
    rhs[idx] = acc;
}

// Pt[b][t][s] += sum over n-chunk lhs[b][t][n]*rhs[b][n][s]   (Pt pre-zeroed)
__global__ void k_ptaccum(const float* __restrict__ lhs, const float* __restrict__ rhs,
                          float* __restrict__ Pt) {
    int b = blockIdx.x >> 3;
    int n0 = (blockIdx.x & 7) * 256;
    int t = threadIdx.x >> 4, s = threadIdx.x & 15;
    const float* lr = lhs + (size_t)b * TT * NN + (size_t)t * NN;
    const float* rr = rhs + (size_t)b * NN * TT;
    float acc = 0.f;
    for (int i = 0; i < 256; ++i) {
        int n = n0 + i;
        acc += lr[n] * rr[n * 16 + s];
    }
    atomicAdd(&Pt[b * 256 + threadIdx.x], acc);
}

// Emat[b][t][s]: sigmoid(+be), Ve-multiply, softmax over t
__global__ void k_temporalatt(const float* __restrict__ Pt, const float* __restrict__ be,
                              const float* __restrict__ Ve, float* __restrict__ Emat) {
    int b = blockIdx.x;
    int t = threadIdx.x >> 4, s = threadIdx.x & 15;
    __shared__ float sg[16][17];
    __shared__ float em[16][17];
    float v = Pt[b * 256 + t * 16 + s] + be[t * 16 + s];
    sg[t][s] = 1.f / (1.f + __expf(-v));
    __syncthreads();
    float e = 0.f;
#pragma unroll
    for (int u = 0; u < 16; ++u) e += Ve[t * 16 + u] * sg[u][s];
    em[t][s] = e;
    __syncthreads();
    float mx = -1e30f;
#pragma unroll
    for (int u = 0; u < 16; ++u) mx = fmaxf(mx, em[u][s]);
    float sum = 0.f;
#pragma unroll
    for (int u = 0; u < 16; ++u) sum += __expf(em[u][s] - mx);
    Emat[b * 256 + t * 16 + s] = __expf(e - mx) / sum;
}

// Xt[b][n][f][s] = sum_t X[b][n][f][t]*Emat[b][t][s]
__global__ void k_applyemat(const float* __restrict__ X, const float* __restrict__ Emat,
                            float* __restrict__ Xt) {
    __shared__ float em[256];
    int b = blockIdx.x >> 8;   // 256 blocks per batch
    em[threadIdx.x] = Emat[b * 256 + threadIdx.x];
    __syncthreads();
    size_t base = ((size_t)blockIdx.x * 256 + threadIdx.x) * 16;
    float x[16], o[16];
    const float4* xp = (const float4*)(X + base);
#pragma unroll
    for (int q = 0; q < 4; ++q) {
        float4 a = xp[q];
        x[q * 4 + 0] = a.x; x[q * 4 + 1] = a.y; x[q * 4 + 2] = a.z; x[q * 4 + 3] = a.w;
    }
#pragma unroll
    for (int s = 0; s < 16; ++s) {
        float acc = 0.f;
#pragma unroll
        for (int t = 0; t < 16; ++t) acc += x[t] * em[t * 16 + s];
        o[s] = acc;
    }
    float4* op = (float4*)(Xt + base);
#pragma unroll
    for (int q = 0; q < 4; ++q) op[q] = make_float4(o[q*4+0], o[q*4+1], o[q*4+2], o[q*4+3]);
}

// ---------------- Stage B: spatial attention small parts ----------------

// lhs_s[b][n][t], rhs_s[b][t][n] from Xt
__global__ void k_spatiallr(const float* __restrict__ Xt, const float* __restrict__ W1,
                            const float* __restrict__ W2, const float* __restrict__ W3,
                            float* __restrict__ lhs_s, float* __restrict__ rhs_s) {
    int b = blockIdx.x >> 7;
    int n0 = (blockIdx.x & 127) * 16;
    __shared__ float xb[16 * 512];
    __shared__ float av[16 * 32];
    const float* src = Xt + ((size_t)(b * NN + n0)) * 512;
    for (int i = 0; i < 32; ++i) xb[threadIdx.x + i * 256] = src[threadIdx.x + i * 256];
    __syncthreads();
#pragma unroll
    for (int ii = 0; ii < 2; ++ii) {
        int idx = threadIdx.x * 2 + ii;   // nl*32+f
        float acc = 0.f;
        const float* xr = &xb[idx * 16];
#pragma unroll
        for (int t = 0; t < 16; ++t) acc += xr[t] * W1[t];
        av[idx] = acc;
    }
    __syncthreads();
    int nl = threadIdx.x >> 4, t = threadIdx.x & 15;
    float r = 0.f;
#pragma unroll
    for (int f = 0; f < 32; ++f) r += W3[f] * xb[nl * 512 + f * 16 + t];
    rhs_s[(size_t)b * TT * NN + (size_t)t * NN + n0 + nl] = r;
    float l = 0.f;
#pragma unroll
    for (int f = 0; f < 32; ++f) l += av[nl * 32 + f] * W2[f * 16 + t];
    lhs_s[((size_t)(b * NN + n0 + nl)) * 16 + t] = l;
}

// Vs fp32 -> bf16
__global__ void k_f2bf(const float* __restrict__ src, unsigned short* __restrict__ dst) {
    int i = blockIdx.x * 256 + threadIdx.x;
    dst[i] = f2bf(src[i]);
}

// weight transposes for k_final: WtT[(c*3+tap)*64+o] = Wt[(o*64+c)*3+tap]; WrT[f*64+o] = Wr[o*32+f]
__global__ void k_wtprep(const float* __restrict__ Wt, const float* __restrict__ Wr,
                         float* __restrict__ WtT, float* __restrict__ WrT) {
    int i = blockIdx.x * 256 + threadIdx.x;
    if (i < 64 * 64 * 3) {
        int o = i & 63;
        int ct = i >> 6;
        int c = ct / 3, tap = ct - c * 3;
        WtT[i] = Wt[(o * 64 + c) * 3 + tap];
    }
    if (i < 32 * 64) {
        int o = i & 63, f = i >> 6;
        WrT[i] = Wr[o * 32 + f];
    }
}

// sigT[b][k][m] = bf16(sigmoid(dot(lhs_s[b,m,:], rhs_s[b,:,k]) + bs[m,k]))
__global__ void k_makesigT(const float* __restrict__ lhs_s, const float* __restrict__ rhs_s,
                           const float* __restrict__ bs, unsigned short* __restrict__ sigT) {
    int k0 = blockIdx.x * 64, m0 = blockIdx.y * 64, b = blockIdx.z;
    __shared__ float lh[64][17];
    __shared__ float rh[16][64];
    __shared__ float bsl[64][65];
    int tid = threadIdx.x;
#pragma unroll
    for (int i = 0; i < 4; ++i) {
        int idx = tid + i * 256;
        int mi = idx >> 4, t = idx & 15;
        lh[mi][t] = lhs_s[((size_t)(b * NN + m0 + mi)) * 16 + t];
        int tt = idx >> 6, kj = idx & 63;
        rh[tt][kj] = rhs_s[(size_t)b * TT * NN + (size_t)tt * NN + k0 + kj];
    }
#pragma unroll
    for (int i = 0; i < 16; ++i) {
        int idx = tid + i * 256;
        int mi = idx >> 6, kj = idx & 63;
        bsl[mi][kj] = bs[(size_t)(m0 + mi) * NN + k0 + kj];
    }
    __syncthreads();
    int ml = tid & 63;
    int kg = (tid >> 6) * 16;
    unsigned short* out = sigT + (size_t)b * NN * NN;
#pragma unroll 4
    for (int ki = 0; ki < 16; ++ki) {
        int kl = kg + ki;
        float acc = bsl[ml][kl];
#pragma unroll
        for (int t = 0; t < 16; ++t) acc += lh[ml][t] * rh[t][kl];
        float sgv = 1.f / (1.f + __expf(-acc));
        out[(size_t)(k0 + kl) * NN + m0 + ml] = f2bf(sgv);
    }
}

// ---------------- The big GEMM: S[b][n][k] = sum_m Vs[n][m]*sigT[b][k][m] ----------------

__global__ __launch_bounds__(256) void k_gemm_bt(const unsigned short* __restrict__ A,
                                                 const unsigned short* __restrict__ Bt,
                                                 float* __restrict__ C,
                                                 int M, int N, int K) {
    __shared__ __align__(16) unsigned short lds[2][2][128 * 32];
    const int tid = threadIdx.x;
    const int wave = tid >> 6, lane = tid & 63;
    const int bm = blockIdx.y << 7;
    const int bn = blockIdx.x << 7;
    const unsigned short* Bb = Bt + (size_t)blockIdx.z * N * K;
    float* Cb = C + (size_t)blockIdx.z * M * N;
    const int wr = wave >> 1, wc = wave & 1;
    const int srow = lane >> 2, scol = (lane & 3) << 3;

    f32x4 acc[4][4];
#pragma unroll
    for (int i = 0; i < 4; ++i)
#pragma unroll
        for (int j = 0; j < 4; ++j) acc[i][j] = (f32x4){0.f, 0.f, 0.f, 0.f};

    const size_t abase = (size_t)(bm + srow) * K + scol;
    const size_t bbase = (size_t)(bn + srow) * K + scol;

#define STAGE(buf, k0)                                                              \
    {                                                                               \
        _Pragma("unroll")                                                           \
        for (int ii = 0; ii < 2; ++ii) {                                            \
            int rb = ((ii << 2) + wave) << 4;                                       \
            gload_lds16(A + abase + (size_t)rb * K + (k0), &lds[buf][0][rb * 32]);  \
            gload_lds16(Bb + bbase + (size_t)rb * K + (k0), &lds[buf][1][rb * 32]); \
        }                                                                           \
    }

    STAGE(0, 0)
    __syncthreads();
    const int nk = K >> 5;
    const int rl = lane & 15, kg = (lane >> 4) << 3;
    for (int t = 0; t < nk; ++t) {
        int cur = t & 1;
        if (t + 1 < nk) STAGE(cur ^ 1, (t + 1) << 5)
        const unsigned short* la = &lds[cur][0][0];
        const unsigned short* lb = &lds[cur][1][0];
        bf16x8 af[4], bfr[4];
#pragma unroll
        for (int i = 0; i < 4; ++i) af[i] = *(const bf16x8*)(la + ((wr << 6) + (i << 4) + rl) * 32 + kg);
#pragma unroll
        for (int j = 0; j < 4; ++j) bfr[j] = *(const bf16x8*)(lb + ((wc << 6) + (j << 4) + rl) * 32 + kg);
#pragma unroll
        for (int i = 0; i < 4; ++i)
#pragma unroll
            for (int j = 0; j < 4; ++j)
                acc[i][j] = __builtin_amdgcn_mfma_f32_16x16x32_bf16(af[i], bfr[j], acc[i][j], 0, 0, 0);
        __syncthreads();
    }
#undef STAGE
    const int cl = lane & 15, rg = (lane >> 4) << 2;
#pragma unroll
    for (int i = 0; i < 4; ++i)
#pragma unroll
        for (int j = 0; j < 4; ++j) {
            int m0 = bm + (wr << 6) + (i << 4) + rg;
            int n0 = bn + (wc << 6) + (j << 4) + cl;
#pragma unroll
            for (int r = 0; r < 4; ++r) Cb[(size_t)(m0 + r) * N + n0] = acc[i][j][r];
        }
}

// ---------------- column softmax statistics (only stats are needed!) ----------------
__global__ void k_colreduce1(const float* __restrict__ S, float* __restrict__ pm,
                             float* __restrict__ ps) {
    int b = blockIdx.z;
    int k0 = blockIdx.x << 8;
    int nbase = blockIdx.y << 7;
    int ktl = threadIdx.x & 63;
    int g = threadIdx.x >> 6;
    const float* base = S + (size_t)b * NN * NN + k0 + (ktl << 2);
    float m0 = -1e30f, m1 = -1e30f, m2 = -1e30f, m3 = -1e30f;
    float s0 = 0.f, s1 = 0.f, s2 = 0.f, s3 = 0.f;
    for (int i = g; i < 128; i += 4) {
        float4 v = *(const float4*)(base + (size_t)(nbase + i) * NN);
        float nm;
        nm = fmaxf(m0, v.x); s0 = s0 * __expf(m0 - nm) + __expf(v.x - nm); m0 = nm;
        nm = fmaxf(m1, v.y); s1 = s1 * __expf(m1 - nm) + __expf(v.y - nm); m1 = nm;
        nm = fmaxf(m2, v.z); s2 = s2 * __expf(m2 - nm) + __expf(v.z - nm); m2 = nm;
        nm = fmaxf(m3, v.w); s3 = s3 * __expf(m3 - nm) + __expf(v.w - nm); m3 = nm;
    }
    __shared__ float sm[4][64][4], ss[4][64][4];
    sm[g][ktl][0] = m0; sm[g][ktl][1] = m1; sm[g][ktl][2] = m2; sm[g][ktl][3] = m3;
    ss[g][ktl][0] = s0; ss[g][ktl][1] = s1; ss[g][ktl][2] = s2; ss[g][ktl][3] = s3;
    __syncthreads();
    int kc = threadIdx.x;
    float M = sm[0][kc >> 2][kc & 3], Ssum = ss[0][kc >> 2][kc & 3];
#pragma unroll
    for (int gi = 1; gi < 4; ++gi) {
        float mm = sm[gi][kc >> 2][kc & 3], sv = ss[gi][kc >> 2][kc & 3];
        float nm = fmaxf(M, mm);
        Ssum = Ssum * __expf(M - nm) + sv * __expf(mm - nm);
        M = nm;
    }
    size_t o = ((size_t)(b * NSPLIT + blockIdx.y) * NN) + k0 + kc;
    pm[o] = M; ps[o] = Ssum;
}

__global__ void k_colreduce2(const float* __restrict__ pm, const float* __restrict__ ps,
                             float* __restrict__ Mf, float* __restrict__ Inv) {
    int idx = blockIdx.x * 256 + threadIdx.x;
    float M = -1e30f, Ssum = 0.f;
#pragma unroll
    for (int i = 0; i < NSPLIT; ++i) {
        size_t o = ((size_t)((idx >> 11) * NSPLIT + i) * NN) + (idx & (NN - 1));
        float mm = pm[o], sv = ps[o];
        float nm = fmaxf(M, mm);
        Ssum = Ssum * __expf(M - nm) + sv * __expf(mm - nm);
        M = nm;
    }
    Mf[idx] = M;
    Inv[idx] = 1.f / Ssum;
}

__global__ void k_diagatt(const float* __restrict__ S, const int* __restrict__ row,
                          const int* __restrict__ col, const float* __restrict__ norm,
                          const float* __restrict__ Mf, const float* __restrict__ Inv,
                          float* __restrict__ diagS, float* __restrict__ att) {
    int idx = blockIdx.x * 256 + threadIdx.x;
    if (idx < BB * EE) {
        int b = idx >> 15, e = idx & (EE - 1);
        int c = col[e];
        float v = S[(size_t)b * NN * NN + (size_t)row[e] * NN + c];
        att[idx] = norm[e] * __expf(v - Mf[b * NN + c]) * Inv[b * NN + c];
    }
    if (idx < BB * NN) {
        float v = S[(size_t)(idx >> 11) * NN * NN + (size_t)(idx & (NN - 1)) * NN + (idx & (NN - 1))];
        diagS[idx] = __expf(v - Mf[idx]) * Inv[idx];
    }
}

// ---------------- graph prep ----------------

__global__ void k_deg(const int* __restrict__ row, const int* __restrict__ col,
                      float* __restrict__ deg) {
    int e = blockIdx.x * 256 + threadIdx.x;
    if (e < EE && row[e] != col[e]) atomicAdd(&deg[row[e]], 1.0f);
}

__global__ void k_dinv(const float* __restrict__ deg, float* __restrict__ dinv) {
    int n = blockIdx.x * 256 + threadIdx.x;
    if (n < NN) {
        float d = deg[n];
        dinv[n] = d > 0.f ? rsqrtf(fmaxf(d, 1e-12f)) : 0.f;
    }
}

__global__ void k_norm(const int* __restrict__ row, const int* __restrict__ col,
                       const float* __restrict__ dinv, float* __restrict__ norm,
                       int* __restrict__ cnt) {
    int e = blockIdx.x * 256 + threadIdx.x;
    if (e < EE) {
        int r = row[e], c = col[e];
        float w = (r != c) ? 1.f : 0.f;
        norm[e] = -dinv[r] * w * dinv[c];
        atomicAdd(&cnt[r], 1);
    }
}

__global__ void k_scan(const int* __restrict__ cnt, int* __restrict__ starts) {
    __shared__ int part[256];
    int t = threadIdx.x;
    int loc[8];
    int s = 0;
#pragma unroll
    for (int i = 0; i < 8; ++i) {
        int c = cnt[t * 8 + i];
        loc[i] = s;
        s += c;
    }
    part[t] = s;
    __syncthreads();
    for (int o = 1; o < 256; o <<= 1) {
        int v = (t >= o) ? part[t - o] : 0;
        __syncthreads();
        part[t] += v;
        __syncthreads();
    }
    int pbase = (t > 0) ? part[t - 1] : 0;
#pragma unroll
    for (int i = 0; i < 8; ++i) starts[t * 8 + i] = pbase + loc[i];
    if (t == 255) starts[NN] = part[255];
}

__global__ void k_scatter(const int* __restrict__ row, const int* __restrict__ starts,
                          int* __restrict__ cursor, int* __restrict__ eid) {
    int e = blockIdx.x * 256 + threadIdx.x;
    if (e < EE) {
        int r = row[e];
        int slot = atomicAdd(&cursor[r], 1);
        eid[starts[r] + slot] = e;
    }
}

// ---------------- Chebyshev ----------------

__global__ void k_tx0(const float* __restrict__ X, const float* __restrict__ diagS,
                      float* __restrict__ Tx0) {
    size_t idx = (size_t)blockIdx.x * 256 + threadIdx.x;
    Tx0[idx] = X[idx] * diagS[idx >> 9];
}

__global__ void k_prop(const float* __restrict__ x, const float* __restrict__ att,
                       const int* __restrict__ col, const int* __restrict__ starts,
                       const int* __restrict__ eid, const float* __restrict__ sub,
                       float* __restrict__ out, int mode) {
    int bn = blockIdx.x;
    int b = bn >> 11, n = bn & (NN - 1);
    int s0 = starts[n], s1 = starts[n + 1];
    float a0 = 0.f, a1 = 0.f;
    for (int j = s0; j < s1; ++j) {
        int e = eid[j];
        float a = att[(size_t)b * EE + e];
        int c = col[e];
        const float* xr = x + ((size_t)(b * NN + c)) * 512;
        a0 += a * xr[threadIdx.x];
        a1 += a * xr[threadIdx.x + 256];
    }
    size_t o = (size_t)bn * 512;
    if (mode) {
        out[o + threadIdx.x] = 2.f * a0 - sub[o + threadIdx.x];
        out[o + threadIdx.x + 256] = 2.f * a1 - sub[o + threadIdx.x + 256];
    } else {
        out[o + threadIdx.x] = a0;
        out[o + threadIdx.x + 256] = a1;
    }
}

__global__ void k_cheb(const float* __restrict__ Tx0, const float* __restrict__ Tx1,
                       const float* __restrict__ Tx2, const float* __restrict__ cW,
                       const float* __restrict__ cb, float* __restrict__ Xh) {
    int bn = blockIdx.x;
    __shared__ float xs[3][512];
    const float* src0 = Tx0 + (size_t)bn * 512;
    const float* src1 = Tx1 + (size_t)bn * 512;
    const float* src2 = Tx2 + (size_t)bn * 512;
    xs[0][threadIdx.x] = src0[threadIdx.x]; xs[0][threadIdx.x + 256] = src0[threadIdx.x + 256];
    xs[1][threadIdx.x] = src1[threadIdx.x]; xs[1][threadIdx.x + 256] = src1[threadIdx.x + 256];
    xs[2][threadIdx.x] = src2[threadIdx.x]; xs[2][threadIdx.x + 256] = src2[threadIdx.x + 256];
    __syncthreads();
#pragma unroll
    for (int p = 0; p < 4; ++p) {
        int idx = threadIdx.x + p * 256;   // c*16+t
        int c = idx >> 4, t = idx & 15;
        float v = cb[c];
#pragma unroll
        for (int k = 0; k < 3; ++k)
#pragma unroll
            for (int f = 0; f < 32; ++f)
                v += xs[k][f * 16 + t] * cW[k * 2048 + f * 64 + c];
        Xh[(size_t)bn * 1024 + idx] = fmaxf(v, 0.f);
    }
}

// ---------------- final: temporal conv + residual + LN ----------------
// one wave per node; lane = output channel o; weights pre-transposed for coalescing
__global__ __launch_bounds__(256) void k_final(const float* __restrict__ Xh,
                                               const float* __restrict__ X,
                                               const float* __restrict__ WtT,
                                               const float* __restrict__ bt,
                                               const float* __restrict__ WrT,
                                               const float* __restrict__ br,
                                               const float* __restrict__ gamma,
                                               const float* __restrict__ beta,
                                               float* __restrict__ out) {
    int j = threadIdx.x >> 6;          // node within block (also wave id)
    int o = threadIdx.x & 63;          // output channel = lane
    int bn = (blockIdx.x << 2) + j;
    __shared__ float xh[4][64][16];    // 16 KB
    __shared__ float xr[4][32][16];    // 8 KB

    // stage node data (each wave stages its own node, coalesced float4)
    {
        const float4* src = (const float4*)(Xh + (size_t)bn * 1024);
        float4* dst = (float4*)&xh[j][0][0];
#pragma unroll
        for (int i = 0; i < 4; ++i) dst[o + (i << 6)] = src[o + (i << 6)];
        const float4* src2 = (const float4*)(X + (size_t)bn * 512);
        float4* dst2 = (float4*)&xr[j][0][0];
#pragma unroll
        for (int i = 0; i < 2; ++i) dst2[o + (i << 6)] = src2[o + (i << 6)];
    }
    __syncthreads();

    float h[16];
    float hinit = bt[o] + br[o];
#pragma unroll
    for (int t = 0; t < 16; ++t) h[t] = hinit;

    // temporal conv: h[t] += sum_c xh[c][t-1..t+1] . WtT[c][0..2][o]
#pragma unroll 2
    for (int c = 0; c < 64; ++c) {
        float w0 = WtT[(c * 3 + 0) * 64 + o];
        float w1 = WtT[(c * 3 + 1) * 64 + o];
        float w2 = WtT[(c * 3 + 2) * 64 + o];
        const float4* xrow = (const float4*)&xh[j][c][0];
        float4 a = xrow[0], b4 = xrow[1], c4 = xrow[2], d4 = xrow[3];
        float xv[16] = {a.x, a.y, a.z, a.w, b4.x, b4.y, b4.z, b4.w,
                        c4.x, c4.y, c4.z, c4.w, d4.x, d4.y, d4.z, d4.w};
#pragma unroll
        for (int t = 0; t < 16; ++t) {
            float xm = (t == 0) ? 0.f : xv[t - 1];
            float xp = (t == 15) ? 0.f : xv[t + 1];
            h[t] += xm * w0 + xv[t] * w1 + xp * w2;
        }
    }

    // residual 1x1 conv: h[t] += sum_f xr[f][t] * WrT[f][o]
#pragma unroll 4
    for (int f = 0; f < 32; ++f) {
        float wr = WrT[(f << 6) + o];
        const float4* xrw = (const float4*)&xr[j][f][0];
        float4 a = xrw[0], b4 = xrw[1], c4 = xrw[2], d4 = xrw[3];
        h[0] += a.x * wr;  h[1] += a.y * wr;  h[2] += a.z * wr;  h[3] += a.w * wr;
        h[4] += b4.x * wr; h[5] += b4.y * wr; h[6] += b4.z * wr; h[7] += b4.w * wr;
        h[8] += c4.x * wr; h[9] += c4.y * wr; h[10] += c4.z * wr; h[11] += c4.w * wr;
        h[12] += d4.x * wr; h[13] += d4.y * wr; h[14] += d4.z * wr; h[15] += d4.w * wr;
    }

    // relu + LayerNorm over the 64 channels (= the 64 lanes of this wave)
#pragma unroll
    for (int t = 0; t < 16; ++t) h[t] = fmaxf(h[t], 0.f);
#pragma unroll
    for (int t = 0; t < 16; ++t) {
        float s1 = h[t], s2 = h[t] * h[t];
#pragma unroll
        for (int m = 32; m >= 1; m >>= 1) {
            s1 += __shfl_xor(s1, m);
            s2 += __shfl_xor(s2, m);
        }
        float mu = s1 * (1.f / 64.f);
        float var = s2 * (1.f / 64.f) - mu * mu;
        h[t] = (h[t] - mu) * rsqrtf(var + 1e-5f);
    }
    float g = gamma[o], bb = beta[o];
    float4* op = (float4*)(out + (size_t)bn * 1024 + (o << 4));
#pragma unroll
    for (int q = 0; q < 4; ++q)
        op[q] = make_float4(h[q * 4 + 0] * g + bb, h[q * 4 + 1] * g + bb,
                            h[q * 4 + 2] * g + bb, h[q * 4 + 3] * g + bb);
}

// ---------------- host ----------------

extern "C" void kernel_launch(void* const* d_in, const int* in_sizes, int n_in,
                              void* d_out, int out_size, void* d_ws, size_t ws_size,
                              hipStream_t stream) {
    (void)in_sizes; (void)n_in; (void)out_size; (void)ws_size;
    const float* X = (const float*)d_in[0];
    const int* ei = (const int*)d_in[1];
    const int* row = ei;
    const int* col = ei + EE;
    const float* U1 = (const float*)d_in[2];
    const float* U2 = (const float*)d_in[3];
    const float* U3 = (const float*)d_in[4];
    const float* be = (const float*)d_in[5];
    const float* Ve = (const float*)d_in[6];
    const float* W1 = (const float*)d_in[7];
    const float* W2 = (const float*)d_in[8];
    const float* W3 = (const float*)d_in[9];
    const float* bs = (const float*)d_in[10];
    const float* Vs = (const float*)d_in[11];
    const float* cW = (const float*)d_in[12];
    const float* cb = (const float*)d_in[13];
    const float* Wt = (const float*)d_in[14];
    const float* bt = (const float*)d_in[15];
    const float* Wr = (const float*)d_in[16];
    const float* br = (const float*)d_in[17];
    const float* gamma = (const float*)d_in[18];
    const float* beta = (const float*)d_in[19];
    float* out = (float*)d_out;

    char* w = (char*)d_ws;
    constexpr size_t OFF_TMP1 = 0;            // 8192
    constexpr size_t OFF_PT = 8192;           // 4096
    constexpr size_t OFF_DEG = 12288;         // 8192
    constexpr size_t OFF_CNT = 20480;         // 8192
    constexpr size_t OFF_CURSOR = 28672;      // 8192
    constexpr size_t ZEND = 36864;
    constexpr size_t OFF_EMAT = ZEND;                     // 4096
    constexpr size_t OFF_LHS = OFF_EMAT + 4096;           // 512K
    constexpr size_t OFF_RHS = OFF_LHS + 524288;          // 512K
    constexpr size_t OFF_LHSS = OFF_RHS + 524288;         // 512K
    constexpr size_t OFF_RHSS = OFF_LHSS + 524288;        // 512K
    constexpr size_t OFF_DIAG = OFF_RHSS + 524288;        // 32K
    constexpr size_t OFF_ATT = OFF_DIAG + 32768;          // 512K
    constexpr size_t OFF_DINV = OFF_ATT + 524288;         // 8K
    constexpr size_t OFF_NORM = OFF_DINV + 8192;          // 128K
    constexpr size_t OFF_STARTS = OFF_NORM + 131072;      // 8448
    constexpr size_t OFF_EID = OFF_STARTS + 8448;         // 128K
    constexpr size_t OFF_WTT = OFF_EID + 131072;          // 48K
    constexpr size_t OFF_WRT = OFF_WTT + 49152;           // 8K
    constexpr size_t OFF_VSBF = OFF_WRT + 8192;           // 8MB (reused: pm/ps/Mf/Inv)
    constexpr size_t OFF_XT = OFF_VSBF + 8388608;         // 16MB (reused: Tx0)
    constexpr size_t OFF_SIGT = OFF_XT + 16777216;        // 32MB (reused: X_hat)
    constexpr size_t OFF_S = OFF_SIGT + 33554432;         // 64MB+ (reused: Tx1, Tx2)

    float* tmp1 = (float*)(w + OFF_TMP1);
    float* Pt = (float*)(w + OFF_PT);
    float* deg = (float*)(w + OFF_DEG);
    int* cnt = (int*)(w + OFF_CNT);
    int* cursor = (int*)(w + OFF_CURSOR);
    float* Emat = (float*)(w + OFF_EMAT);
    float* lhs = (float*)(w + OFF_LHS);
    float* rhs = (float*)(w + OFF_RHS);
    float* lhs_s = (float*)(w + OFF_LHSS);
    float* rhs_s = (float*)(w + OFF_RHSS);
    float* diagS = (float*)(w + OFF_DIAG);
    float* att = (float*)(w + OFF_ATT);
    float* dinv = (float*)(w + OFF_DINV);
    float* normv = (float*)(w + OFF_NORM);
    int* starts = (int*)(w + OFF_STARTS);
    int* eid = (int*)(w + OFF_EID);
    float* WtT = (float*)(w + OFF_WTT);
    float* WrT = (float*)(w + OFF_WRT);
    unsigned short* Vsbf = (unsigned short*)(w + OFF_VSBF);
    float* pm = (float*)(w + OFF_VSBF);                   // reuse after gemm
    float* ps = (float*)(w + OFF_VSBF + 524288);
    float* Mf = (float*)(w + OFF_VSBF + 1048576);
    float* Inv = (float*)(w + OFF_VSBF + 1048576 + 32768);
    float* Xt = (float*)(w + OFF_XT);
    float* Tx0 = Xt;
    unsigned short* sigT = (unsigned short*)(w + OFF_SIGT);
    float* Xh = (float*)(w + OFF_SIGT);
    float* S = (float*)(w + OFF_S);
    float* Tx1 = S;
    float* Tx2 = (float*)(w + OFF_S + 16777216);

    hipMemsetAsync(w, 0, ZEND, stream);

    // temporal attention
    k_u1reduce<<<BB * 64, 256, 0, stream>>>(X, U1, tmp1);
    k_mkrhs<<<BB * NN * TT / 256, 256, 0, stream>>>(X, U3, rhs);
    k_mklhs<<<BB * TT * 8, 256, 0, stream>>>(tmp1, U2, lhs);
    k_ptaccum<<<BB * 8, 256, 0, stream>>>(lhs, rhs, Pt);
    k_temporalatt<<<BB, 256, 0, stream>>>(Pt, be, Ve, Emat);
    k_applyemat<<<BB * NN * FIN / 256, 256, 0, stream>>>(X, Emat, Xt);

    // spatial attention
    k_spatiallr<<<BB * (NN / 16), 256, 0, stream>>>(Xt, W1, W2, W3, lhs_s, rhs_s);
    k_f2bf<<<NN * NN / 256, 256, 0, stream>>>(Vs, Vsbf);
    k_wtprep<<<48, 256, 0, stream>>>(Wt, Wr, WtT, WrT);
    k_makesigT<<<dim3(NN / 64, NN / 64, BB), 256, 0, stream>>>(lhs_s, rhs_s, bs, sigT);
    k_gemm_bt<<<dim3(NN / 128, NN / 128, BB), 256, 0, stream>>>(Vsbf, sigT, S, NN, NN, NN);

    // softmax statistics only (full normalized S never materialized)
    k_colreduce1<<<dim3(8, NSPLIT, BB), 256, 0, stream>>>(S, pm, ps);
    k_colreduce2<<<BB * NN / 256, 256, 0, stream>>>(pm, ps, Mf, Inv);

    // graph prep
    k_deg<<<EE / 256, 256, 0, stream>>>(row, col, deg);
    k_dinv<<<NN / 256, 256, 0, stream>>>(deg, dinv);
    k_norm<<<EE / 256, 256, 0, stream>>>(row, col, dinv, normv, cnt);
    k_scan<<<1, 256, 0, stream>>>(cnt, starts);
    k_scatter<<<EE / 256, 256, 0, stream>>>(row, starts, cursor, eid);
    k_diagatt<<<BB * EE / 256, 256, 0, stream>>>(S, row, col, normv, Mf, Inv, diagS, att);

    // chebyshev
    k_tx0<<<BB * NN * 512 / 256, 256, 0, stream>>>(X, diagS, Tx0);
    k_prop<<<BB * NN, 256, 0, stream>>>(Tx0, att, col, starts, eid, nullptr, Tx1, 0);
    k_prop<<<BB * NN, 256, 0, stream>>>(Tx1, att, col, starts, eid, Tx0, Tx2, 1);
    k_cheb<<<BB * NN, 256, 0, stream>>>(Tx0, Tx1, Tx2, cW, cb, Xh);

    // final
    k_final<<<BB * NN / 4, 256, 0, stream>>>(Xh, X, WtT, bt, WrT, br, gamma, beta, out);
}

// Round 4
// 410.378 us; speedup vs baseline: 2.1872x; 1.1370x over previous
//
#include <hip/hip_runtime.h>
#include <hip/hip_bf16.h>

#define BB 4
#define NN 2048
#define FIN 32
#define TT 16
#define EE 32768
#define CC 64
#define TFo 64
#define NSPLIT 16

typedef __attribute__((ext_vector_type(8))) short bf16x8;
typedef __attribute__((ext_vector_type(4))) float f32x4;

typedef __attribute__((address_space(1))) const unsigned int as1_uint;
typedef __attribute__((address_space(3))) unsigned int as3_uint;

__device__ __forceinline__ void gload_lds16(const void* g, void* l) {
    __builtin_amdgcn_global_load_lds((as1_uint*)g, (as3_uint*)l, 16, 0, 0);
}

__device__ __forceinline__ unsigned short f2bf(float v) {
    unsigned u = __builtin_bit_cast(unsigned, v);
    unsigned r = (u + 0x7fffu + ((u >> 16) & 1u)) >> 16;
    return (unsigned short)r;
}

// ---------------- Stage A: temporal attention ----------------

// tmp1[b][f][t] = sum_n X[b][n][f][t] * U1[n]   (atomic accumulate, tmp1 pre-zeroed)
__global__ void k_u1reduce(const float* __restrict__ X, const float* __restrict__ U1,
                           float* __restrict__ tmp1) {
    int b = blockIdx.x >> 6;
    int n0 = (blockIdx.x & 63) * 32;
    float a0 = 0.f, a1 = 0.f;
    for (int i = 0; i < 32; ++i) {
        int n = n0 + i;
        float u = U1[n];
        const float* row = X + ((size_t)(b * NN + n)) * 512;
        a0 += u * row[threadIdx.x];
        a1 += u * row[threadIdx.x + 256];
    }
    atomicAdd(&tmp1[b * 512 + threadIdx.x], a0);
    atomicAdd(&tmp1[b * 512 + threadIdx.x + 256], a1);
}

// lhs[b][t][n'] = sum_f tmp1[b][f][t] * U2[f][n']
__global__ void k_mklhs(const float* __restrict__ tmp1, const float* __restrict__ U2,
                        float* __restrict__ lhs) {
    int npr = ((blockIdx.x & 7) << 8) + threadIdx.x;
    int bt = blockIdx.x >> 3;           // b*16 + t
    int b = bt >> 4, t = bt & 15;
    float acc = 0.f;
#pragma unroll
    for (int f = 0; f < 32; ++f) acc += tmp1[b * 512 + f * 16 + t] * U2[f * NN + npr];
    lhs[(size_t)bt * NN + npr] = acc;
}

// rhs[b][n][t] = sum_f U3[f]*X[b][n][f][t]
__global__ void k_mkrhs(const float* __restrict__ X, const float* __restrict__ U3,
                        float* __restrict__ rhs) {
    int idx = blockIdx.x * 256 + threadIdx.x;   // B*N*T
    int t = idx & 15;
    int bn = idx >> 4;
    float acc = 0.f;
#pragma unroll
    for (int f = 0; f < 32; ++f) acc += U3[f] * X[(size_t)bn * 512 + f * 16 + t];
    rhs[idx] = acc;
}

// Pt[b][t][s] += sum over n-chunk lhs[b][t][n]*rhs[b][n][s]   (Pt pre-zeroed)
__global__ void k_ptaccum(const float* __restrict__ lhs, const float* __restrict__ rhs,
                          float* __restrict__ Pt) {
    int b = blockIdx.x >> 3;
    int n0 = (blockIdx.x & 7) * 256;
    int t = threadIdx.x >> 4, s = threadIdx.x & 15;
    const float* lr = lhs + (size_t)b * TT * NN + (size_t)t * NN;
    const float* rr = rhs + (size_t)b * NN * TT;
    float acc = 0.f;
    for (int i = 0; i < 256; ++i) {
        int n = n0 + i;
        acc += lr[n] * rr[n * 16 + s];
    }
    atomicAdd(&Pt[b * 256 + threadIdx.x], acc);
}

// Emat[b][t][s]: sigmoid(+be), Ve-multiply, softmax over t
__global__ void k_temporalatt(const float* __restrict__ Pt, const float* __restrict__ be,
                              const float* __restrict__ Ve, float* __restrict__ Emat) {
    int b = blockIdx.x;
    int t = threadIdx.x >> 4, s = threadIdx.x & 15;
    __shared__ float sg[16][17];
    __shared__ float em[16][17];
    float v = Pt[b * 256 + t * 16 + s] + be[t * 16 + s];
    sg[t][s] = 1.f / (1.f + __expf(-v));
    __syncthreads();
    float e = 0.f;
#pragma unroll
    for (int u = 0; u < 16; ++u) e += Ve[t * 16 + u] * sg[u][s];
    em[t][s] = e;
    __syncthreads();
    float mx = -1e30f;
#pragma unroll
    for (int u = 0; u < 16; ++u) mx = fmaxf(mx, em[u][s]);
    float sum = 0.f;
#pragma unroll
    for (int u = 0; u < 16; ++u) sum += __expf(em[u][s] - mx);
    Emat[b * 256 + t * 16 + s] = __expf(e - mx) / sum;
}

// Xt[b][n][f][s] = sum_t X[b][n][f][t]*Emat[b][t][s]
__global__ void k_applyemat(const float* __restrict__ X, const float* __restrict__ Emat,
                            float* __restrict__ Xt) {
    __shared__ float em[256];
    int b = blockIdx.x >> 8;   // 256 blocks per batch
    em[threadIdx.x] = Emat[b * 256 + threadIdx.x];
    __syncthreads();
    size_t base = ((size_t)blockIdx.x * 256 + threadIdx.x) * 16;
    float x[16], o[16];
    const float4* xp = (const float4*)(X + base);
#pragma unroll
    for (int q = 0; q < 4; ++q) {
        float4 a = xp[q];
        x[q * 4 + 0] = a.x; x[q * 4 + 1] = a.y; x[q * 4 + 2] = a.z; x[q * 4 + 3] = a.w;
    }
#pragma unroll
    for (int s = 0; s < 16; ++s) {
        float acc = 0.f;
#pragma unroll
        for (int t = 0; t < 16; ++t) acc += x[t] * em[t * 16 + s];
        o[s] = acc;
    }
    float4* op = (float4*)(Xt + base);
#pragma unroll
    for (int q = 0; q < 4; ++q) op[q] = make_float4(o[q*4+0], o[q*4+1], o[q*4+2], o[q*4+3]);
}

// ---------------- Stage B: spatial attention small parts ----------------

// lhs_s[b][n][t], rhs_s[b][t][n] from Xt
__global__ void k_spatiallr(const float* __restrict__ Xt, const float* __restrict__ W1,
                            const float* __restrict__ W2, const float* __restrict__ W3,
                            float* __restrict__ lhs_s, float* __restrict__ rhs_s) {
    int b = blockIdx.x >> 7;
    int n0 = (blockIdx.x & 127) * 16;
    __shared__ float xb[16 * 512];
    __shared__ float av[16 * 32];
    const float* src = Xt + ((size_t)(b * NN + n0)) * 512;
    for (int i = 0; i < 32; ++i) xb[threadIdx.x + i * 256] = src[threadIdx.x + i * 256];
    __syncthreads();
#pragma unroll
    for (int ii = 0; ii < 2; ++ii) {
        int idx = threadIdx.x * 2 + ii;   // nl*32+f
        float acc = 0.f;
        const float* xr = &xb[idx * 16];
#pragma unroll
        for (int t = 0; t < 16; ++t) acc += xr[t] * W1[t];
        av[idx] = acc;
    }
    __syncthreads();
    int nl = threadIdx.x >> 4, t = threadIdx.x & 15;
    float r = 0.f;
#pragma unroll
    for (int f = 0; f < 32; ++f) r += W3[f] * xb[nl * 512 + f * 16 + t];
    rhs_s[(size_t)b * TT * NN + (size_t)t * NN + n0 + nl] = r;
    float l = 0.f;
#pragma unroll
    for (int f = 0; f < 32; ++f) l += av[nl * 32 + f] * W2[f * 16 + t];
    lhs_s[((size_t)(b * NN + n0 + nl)) * 16 + t] = l;
}

// Vs fp32 -> bf16
__global__ void k_f2bf(const float* __restrict__ src, unsigned short* __restrict__ dst) {
    int i = blockIdx.x * 256 + threadIdx.x;
    dst[i] = f2bf(src[i]);
}

// weight transposes for k_final: WtT[(c*3+tap)*64+o] = Wt[(o*64+c)*3+tap]; WrT[f*64+o] = Wr[o*32+f]
__global__ void k_wtprep(const float* __restrict__ Wt, const float* __restrict__ Wr,
                         float* __restrict__ WtT, float* __restrict__ WrT) {
    int i = blockIdx.x * 256 + threadIdx.x;
    if (i < 64 * 64 * 3) {
        int o = i & 63;
        int ct = i >> 6;
        int c = ct / 3, tap = ct - c * 3;
        WtT[i] = Wt[(o * 64 + c) * 3 + tap];
    }
    if (i < 32 * 64) {
        int o = i & 63, f = i >> 6;
        WrT[i] = Wr[o * 32 + f];
    }
}

// sigT[b][k][m] = bf16(sigmoid(dot(lhs_s[b,m,:], rhs_s[b,:,k]) + bs[m,k]))
__global__ void k_makesigT(const float* __restrict__ lhs_s, const float* __restrict__ rhs_s,
                           const float* __restrict__ bs, unsigned short* __restrict__ sigT) {
    int k0 = blockIdx.x * 64, m0 = blockIdx.y * 64, b = blockIdx.z;
    __shared__ float lh[64][17];
    __shared__ float rh[16][64];
    __shared__ float bsl[64][65];
    int tid = threadIdx.x;
#pragma unroll
    for (int i = 0; i < 4; ++i) {
        int idx = tid + i * 256;
        int mi = idx >> 4, t = idx & 15;
        lh[mi][t] = lhs_s[((size_t)(b * NN + m0 + mi)) * 16 + t];
        int tt = idx >> 6, kj = idx & 63;
        rh[tt][kj] = rhs_s[(size_t)b * TT * NN + (size_t)tt * NN + k0 + kj];
    }
#pragma unroll
    for (int i = 0; i < 16; ++i) {
        int idx = tid + i * 256;
        int mi = idx >> 6, kj = idx & 63;
        bsl[mi][kj] = bs[(size_t)(m0 + mi) * NN + k0 + kj];
    }
    __syncthreads();
    int ml = tid & 63;
    int kg = (tid >> 6) * 16;
    unsigned short* out = sigT + (size_t)b * NN * NN;
#pragma unroll 4
    for (int ki = 0; ki < 16; ++ki) {
        int kl = kg + ki;
        float acc = bsl[ml][kl];
#pragma unroll
        for (int t = 0; t < 16; ++t) acc += lh[ml][t] * rh[t][kl];
        float sgv = 1.f / (1.f + __expf(-acc));
        out[(size_t)(k0 + kl) * NN + m0 + ml] = f2bf(sgv);
    }
}

// ---------------- The big GEMM: S[b][n][k] = sum_m Vs[n][m]*sigT[b][k][m] ----------------

__global__ __launch_bounds__(256) void k_gemm_bt(const unsigned short* __restrict__ A,
                                                 const unsigned short* __restrict__ Bt,
                                                 float* __restrict__ C,
                                                 int M, int N, int K) {
    __shared__ __align__(16) unsigned short lds[2][2][128 * 32];
    const int tid = threadIdx.x;
    const int wave = tid >> 6, lane = tid & 63;
    const int bm = blockIdx.y << 7;
    const int bn = blockIdx.x << 7;
    const unsigned short* Bb = Bt + (size_t)blockIdx.z * N * K;
    float* Cb = C + (size_t)blockIdx.z * M * N;
    const int wr = wave >> 1, wc = wave & 1;
    const int srow = lane >> 2, scol = (lane & 3) << 3;

    f32x4 acc[4][4];
#pragma unroll
    for (int i = 0; i < 4; ++i)
#pragma unroll
        for (int j = 0; j < 4; ++j) acc[i][j] = (f32x4){0.f, 0.f, 0.f, 0.f};

    const size_t abase = (size_t)(bm + srow) * K + scol;
    const size_t bbase = (size_t)(bn + srow) * K + scol;

#define STAGE(buf, k0)                                                              \
    {                                                                               \
        _Pragma("unroll")                                                           \
        for (int ii = 0; ii < 2; ++ii) {                                            \
            int rb = ((ii << 2) + wave) << 4;                                       \
            gload_lds16(A + abase + (size_t)rb * K + (k0), &lds[buf][0][rb * 32]);  \
            gload_lds16(Bb + bbase + (size_t)rb * K + (k0), &lds[buf][1][rb * 32]); \
        }                                                                           \
    }

    STAGE(0, 0)
    __syncthreads();
    const int nk = K >> 5;
    const int rl = lane & 15, kg = (lane >> 4) << 3;
    for (int t = 0; t < nk; ++t) {
        int cur = t & 1;
        if (t + 1 < nk) STAGE(cur ^ 1, (t + 1) << 5)
        const unsigned short* la = &lds[cur][0][0];
        const unsigned short* lb = &lds[cur][1][0];
        bf16x8 af[4], bfr[4];
#pragma unroll
        for (int i = 0; i < 4; ++i) af[i] = *(const bf16x8*)(la + ((wr << 6) + (i << 4) + rl) * 32 + kg);
#pragma unroll
        for (int j = 0; j < 4; ++j) bfr[j] = *(const bf16x8*)(lb + ((wc << 6) + (j << 4) + rl) * 32 + kg);
#pragma unroll
        for (int i = 0; i < 4; ++i)
#pragma unroll
            for (int j = 0; j < 4; ++j)
                acc[i][j] = __builtin_amdgcn_mfma_f32_16x16x32_bf16(af[i], bfr[j], acc[i][j], 0, 0, 0);
        __syncthreads();
    }
#undef STAGE
    const int cl = lane & 15, rg = (lane >> 4) << 2;
#pragma unroll
    for (int i = 0; i < 4; ++i)
#pragma unroll
        for (int j = 0; j < 4; ++j) {
            int m0 = bm + (wr << 6) + (i << 4) + rg;
            int n0 = bn + (wc << 6) + (j << 4) + cl;
#pragma unroll
            for (int r = 0; r < 4; ++r) Cb[(size_t)(m0 + r) * N + n0] = acc[i][j][r];
        }
}

// ---------------- column softmax statistics (only stats are needed!) ----------------
__global__ void k_colreduce1(const float* __restrict__ S, float* __restrict__ pm,
                             float* __restrict__ ps) {
    int b = blockIdx.z;
    int k0 = blockIdx.x << 8;
    int nbase = blockIdx.y << 7;
    int ktl = threadIdx.x & 63;
    int g = threadIdx.x >> 6;
    const float* base = S + (size_t)b * NN * NN + k0 + (ktl << 2);
    float m0 = -1e30f, m1 = -1e30f, m2 = -1e30f, m3 = -1e30f;
    float s0 = 0.f, s1 = 0.f, s2 = 0.f, s3 = 0.f;
    for (int i = g; i < 128; i += 4) {
        float4 v = *(const float4*)(base + (size_t)(nbase + i) * NN);
        float nm;
        nm = fmaxf(m0, v.x); s0 = s0 * __expf(m0 - nm) + __expf(v.x - nm); m0 = nm;
        nm = fmaxf(m1, v.y); s1 = s1 * __expf(m1 - nm) + __expf(v.y - nm); m1 = nm;
        nm = fmaxf(m2, v.z); s2 = s2 * __expf(m2 - nm) + __expf(v.z - nm); m2 = nm;
        nm = fmaxf(m3, v.w); s3 = s3 * __expf(m3 - nm) + __expf(v.w - nm); m3 = nm;
    }
    __shared__ float sm[4][64][4], ss[4][64][4];
    sm[g][ktl][0] = m0; sm[g][ktl][1] = m1; sm[g][ktl][2] = m2; sm[g][ktl][3] = m3;
    ss[g][ktl][0] = s0; ss[g][ktl][1] = s1; ss[g][ktl][2] = s2; ss[g][ktl][3] = s3;
    __syncthreads();
    int kc = threadIdx.x;
    float M = sm[0][kc >> 2][kc & 3], Ssum = ss[0][kc >> 2][kc & 3];
#pragma unroll
    for (int gi = 1; gi < 4; ++gi) {
        float mm = sm[gi][kc >> 2][kc & 3], sv = ss[gi][kc >> 2][kc & 3];
        float nm = fmaxf(M, mm);
        Ssum = Ssum * __expf(M - nm) + sv * __expf(mm - nm);
        M = nm;
    }
    size_t o = ((size_t)(b * NSPLIT + blockIdx.y) * NN) + k0 + kc;
    pm[o] = M; ps[o] = Ssum;
}

__global__ void k_colreduce2(const float* __restrict__ pm, const float* __restrict__ ps,
                             float* __restrict__ Mf, float* __restrict__ Inv) {
    int idx = blockIdx.x * 256 + threadIdx.x;
    float M = -1e30f, Ssum = 0.f;
#pragma unroll
    for (int i = 0; i < NSPLIT; ++i) {
        size_t o = ((size_t)((idx >> 11) * NSPLIT + i) * NN) + (idx & (NN - 1));
        float mm = pm[o], sv = ps[o];
        float nm = fmaxf(M, mm);
        Ssum = Ssum * __expf(M - nm) + sv * __expf(mm - nm);
        M = nm;
    }
    Mf[idx] = M;
    Inv[idx] = 1.f / Ssum;
}

__global__ void k_diagatt(const float* __restrict__ S, const int* __restrict__ row,
                          const int* __restrict__ col, const float* __restrict__ norm,
                          const float* __restrict__ Mf, const float* __restrict__ Inv,
                          float* __restrict__ diagS, float* __restrict__ att) {
    int idx = blockIdx.x * 256 + threadIdx.x;
    if (idx < BB * EE) {
        int b = idx >> 15, e = idx & (EE - 1);
        int c = col[e];
        float v = S[(size_t)b * NN * NN + (size_t)row[e] * NN + c];
        att[idx] = norm[e] * __expf(v - Mf[b * NN + c]) * Inv[b * NN + c];
    }
    if (idx < BB * NN) {
        float v = S[(size_t)(idx >> 11) * NN * NN + (size_t)(idx & (NN - 1)) * NN + (idx & (NN - 1))];
        diagS[idx] = __expf(v - Mf[idx]) * Inv[idx];
    }
}

// ---------------- graph prep ----------------

__global__ void k_deg(const int* __restrict__ row, const int* __restrict__ col,
                      float* __restrict__ deg) {
    int e = blockIdx.x * 256 + threadIdx.x;
    if (e < EE && row[e] != col[e]) atomicAdd(&deg[row[e]], 1.0f);
}

__global__ void k_dinv(const float* __restrict__ deg, float* __restrict__ dinv) {
    int n = blockIdx.x * 256 + threadIdx.x;
    if (n < NN) {
        float d = deg[n];
        dinv[n] = d > 0.f ? rsqrtf(fmaxf(d, 1e-12f)) : 0.f;
    }
}

__global__ void k_norm(const int* __restrict__ row, const int* __restrict__ col,
                       const float* __restrict__ dinv, float* __restrict__ norm,
                       int* __restrict__ cnt) {
    int e = blockIdx.x * 256 + threadIdx.x;
    if (e < EE) {
        int r = row[e], c = col[e];
        float w = (r != c) ? 1.f : 0.f;
        norm[e] = -dinv[r] * w * dinv[c];
        atomicAdd(&cnt[r], 1);
    }
}

__global__ void k_scan(const int* __restrict__ cnt, int* __restrict__ starts) {
    __shared__ int part[256];
    int t = threadIdx.x;
    int loc[8];
    int s = 0;
#pragma unroll
    for (int i = 0; i < 8; ++i) {
        int c = cnt[t * 8 + i];
        loc[i] = s;
        s += c;
    }
    part[t] = s;
    __syncthreads();
    for (int o = 1; o < 256; o <<= 1) {
        int v = (t >= o) ? part[t - o] : 0;
        __syncthreads();
        part[t] += v;
        __syncthreads();
    }
    int pbase = (t > 0) ? part[t - 1] : 0;
#pragma unroll
    for (int i = 0; i < 8; ++i) starts[t * 8 + i] = pbase + loc[i];
    if (t == 255) starts[NN] = part[255];
}

__global__ void k_scatter(const int* __restrict__ row, const int* __restrict__ starts,
                          int* __restrict__ cursor, int* __restrict__ eid) {
    int e = blockIdx.x * 256 + threadIdx.x;
    if (e < EE) {
        int r = row[e];
        int slot = atomicAdd(&cursor[r], 1);
        eid[starts[r] + slot] = e;
    }
}

// ---------------- Chebyshev ----------------

__global__ void k_tx0(const float* __restrict__ X, const float* __restrict__ diagS,
                      float* __restrict__ Tx0) {
    size_t idx = (size_t)blockIdx.x * 256 + threadIdx.x;
    Tx0[idx] = X[idx] * diagS[idx >> 9];
}

__global__ void k_prop(const float* __restrict__ x, const float* __restrict__ att,
                       const int* __restrict__ col, const int* __restrict__ starts,
                       const int* __restrict__ eid, const float* __restrict__ sub,
                       float* __restrict__ out, int mode) {
    int bn = blockIdx.x;
    int b = bn >> 11, n = bn & (NN - 1);
    int s0 = starts[n], s1 = starts[n + 1];
    float a0 = 0.f, a1 = 0.f;
    for (int j = s0; j < s1; ++j) {
        int e = eid[j];
        float a = att[(size_t)b * EE + e];
        int c = col[e];
        const float* xr = x + ((size_t)(b * NN + c)) * 512;
        a0 += a * xr[threadIdx.x];
        a1 += a * xr[threadIdx.x + 256];
    }
    size_t o = (size_t)bn * 512;
    if (mode) {
        out[o + threadIdx.x] = 2.f * a0 - sub[o + threadIdx.x];
        out[o + threadIdx.x + 256] = 2.f * a1 - sub[o + threadIdx.x + 256];
    } else {
        out[o + threadIdx.x] = a0;
        out[o + threadIdx.x + 256] = a1;
    }
}

// X_hat[b][n][c][t] = relu(sum_k sum_f Txk[bn][f][t]*cW[k][f][c] + cb[c])
// one wave per node; lane = output channel c; cW native layout is c-contiguous -> coalesced
__global__ __launch_bounds__(256) void k_cheb(const float* __restrict__ Tx0,
                                              const float* __restrict__ Tx1,
                                              const float* __restrict__ Tx2,
                                              const float* __restrict__ cW,
                                              const float* __restrict__ cb,
                                              float* __restrict__ Xh) {
    int j = threadIdx.x >> 6;          // node within block (wave id)
    int c = threadIdx.x & 63;          // lane = output channel
    int bn = (blockIdx.x << 2) + j;
    __shared__ float xs[4][3][512];    // 24 KB

    {
        const float4* s0 = (const float4*)(Tx0 + (size_t)bn * 512);
        const float4* s1 = (const float4*)(Tx1 + (size_t)bn * 512);
        const float4* s2 = (const float4*)(Tx2 + (size_t)bn * 512);
        float4* d0 = (float4*)&xs[j][0][0];
        float4* d1 = (float4*)&xs[j][1][0];
        float4* d2 = (float4*)&xs[j][2][0];
#pragma unroll
        for (int i = 0; i < 2; ++i) {
            d0[c + (i << 6)] = s0[c + (i << 6)];
            d1[c + (i << 6)] = s1[c + (i << 6)];
            d2[c + (i << 6)] = s2[c + (i << 6)];
        }
    }
    __syncthreads();

    float h[16];
    float b0 = cb[c];
#pragma unroll
    for (int t = 0; t < 16; ++t) h[t] = b0;

#pragma unroll
    for (int k = 0; k < 3; ++k) {
#pragma unroll 8
        for (int f = 0; f < 32; ++f) {
            float wv = cW[(k * 32 + f) * 64 + c];
            const float4* xrow = (const float4*)&xs[j][k][f * 16];
            float4 a = xrow[0], b4 = xrow[1], c4 = xrow[2], d4 = xrow[3];
            h[0] += a.x * wv;  h[1] += a.y * wv;  h[2] += a.z * wv;  h[3] += a.w * wv;
            h[4] += b4.x * wv; h[5] += b4.y * wv; h[6] += b4.z * wv; h[7] += b4.w * wv;
            h[8] += c4.x * wv; h[9] += c4.y * wv; h[10] += c4.z * wv; h[11] += c4.w * wv;
            h[12] += d4.x * wv; h[13] += d4.y * wv; h[14] += d4.z * wv; h[15] += d4.w * wv;
        }
    }

    float4* op = (float4*)(Xh + (size_t)bn * 1024 + (c << 4));
#pragma unroll
    for (int q = 0; q < 4; ++q)
        op[q] = make_float4(fmaxf(h[q * 4 + 0], 0.f), fmaxf(h[q * 4 + 1], 0.f),
                            fmaxf(h[q * 4 + 2], 0.f), fmaxf(h[q * 4 + 3], 0.f));
}

// ---------------- final: temporal conv + residual + LN ----------------
// one wave per node; lane = output channel o; weights pre-transposed for coalescing
__global__ __launch_bounds__(256) void k_final(const float* __restrict__ Xh,
                                               const float* __restrict__ X,
                                               const float* __restrict__ WtT,
                                               const float* __restrict__ bt,
                                               const float* __restrict__ WrT,
                                               const float* __restrict__ br,
                                               const float* __restrict__ gamma,
                                               const float* __restrict__ beta,
                                               float* __restrict__ out) {
    int j = threadIdx.x >> 6;          // node within block (also wave id)
    int o = threadIdx.x & 63;          // output channel = lane
    int bn = (blockIdx.x << 2) + j;
    __shared__ float xh[4][64][16];    // 16 KB
    __shared__ float xr[4][32][16];    // 8 KB

    // stage node data (each wave stages its own node, coalesced float4)
    {
        const float4* src = (const float4*)(Xh + (size_t)bn * 1024);
        float4* dst = (float4*)&xh[j][0][0];
#pragma unroll
        for (int i = 0; i < 4; ++i) dst[o + (i << 6)] = src[o + (i << 6)];
        const float4* src2 = (const float4*)(X + (size_t)bn * 512);
        float4* dst2 = (float4*)&xr[j][0][0];
#pragma unroll
        for (int i = 0; i < 2; ++i) dst2[o + (i << 6)] = src2[o + (i << 6)];
    }
    __syncthreads();

    float h[16];
    float hinit = bt[o] + br[o];
#pragma unroll
    for (int t = 0; t < 16; ++t) h[t] = hinit;

    // temporal conv: h[t] += sum_c xh[c][t-1..t+1] . WtT[c][0..2][o]
#pragma unroll 2
    for (int c = 0; c < 64; ++c) {
        float w0 = WtT[(c * 3 + 0) * 64 + o];
        float w1 = WtT[(c * 3 + 1) * 64 + o];
        float w2 = WtT[(c * 3 + 2) * 64 + o];
        const float4* xrow = (const float4*)&xh[j][c][0];
        float4 a = xrow[0], b4 = xrow[1], c4 = xrow[2], d4 = xrow[3];
        float xv[16] = {a.x, a.y, a.z, a.w, b4.x, b4.y, b4.z, b4.w,
                        c4.x, c4.y, c4.z, c4.w, d4.x, d4.y, d4.z, d4.w};
#pragma unroll
        for (int t = 0; t < 16; ++t) {
            float xm = (t == 0) ? 0.f : xv[t - 1];
            float xp = (t == 15) ? 0.f : xv[t + 1];
            h[t] += xm * w0 + xv[t] * w1 + xp * w2;
        }
    }

    // residual 1x1 conv: h[t] += sum_f xr[f][t] * WrT[f][o]
#pragma unroll 4
    for (int f = 0; f < 32; ++f) {
        float wr = WrT[(f << 6) + o];
        const float4* xrw = (const float4*)&xr[j][f][0];
        float4 a = xrw[0], b4 = xrw[1], c4 = xrw[2], d4 = xrw[3];
        h[0] += a.x * wr;  h[1] += a.y * wr;  h[2] += a.z * wr;  h[3] += a.w * wr;
        h[4] += b4.x * wr; h[5] += b4.y * wr; h[6] += b4.z * wr; h[7] += b4.w * wr;
        h[8] += c4.x * wr; h[9] += c4.y * wr; h[10] += c4.z * wr; h[11] += c4.w * wr;
        h[12] += d4.x * wr; h[13] += d4.y * wr; h[14] += d4.z * wr; h[15] += d4.w * wr;
    }

    // relu + LayerNorm over the 64 channels (= the 64 lanes of this wave)
#pragma unroll
    for (int t = 0; t < 16; ++t) h[t] = fmaxf(h[t], 0.f);
#pragma unroll
    for (int t = 0; t < 16; ++t) {
        float s1 = h[t], s2 = h[t] * h[t];
#pragma unroll
        for (int m = 32; m >= 1; m >>= 1) {
            s1 += __shfl_xor(s1, m);
            s2 += __shfl_xor(s2, m);
        }
        float mu = s1 * (1.f / 64.f);
        float var = s2 * (1.f / 64.f) - mu * mu;
        h[t] = (h[t] - mu) * rsqrtf(var + 1e-5f);
    }
    float g = gamma[o], bb = beta[o];
    float4* op = (float4*)(out + (size_t)bn * 1024 + (o << 4));
#pragma unroll
    for (int q = 0; q < 4; ++q)
        op[q] = make_float4(h[q * 4 + 0] * g + bb, h[q * 4 + 1] * g + bb,
                            h[q * 4 + 2] * g + bb, h[q * 4 + 3] * g + bb);
}

// ---------------- host ----------------

extern "C" void kernel_launch(void* const* d_in, const int* in_sizes, int n_in,
                              void* d_out, int out_size, void* d_ws, size_t ws_size,
                              hipStream_t stream) {
    (void)in_sizes; (void)n_in; (void)out_size; (void)ws_size;
    const float* X = (const float*)d_in[0];
    const int* ei = (const int*)d_in[1];
    const int* row = ei;
    const int* col = ei + EE;
    const float* U1 = (const float*)d_in[2];
    const float* U2 = (const float*)d_in[3];
    const float* U3 = (const float*)d_in[4];
    const float* be = (const float*)d_in[5];
    const float* Ve = (const float*)d_in[6];
    const float* W1 = (const float*)d_in[7];
    const float* W2 = (const float*)d_in[8];
    const float* W3 = (const float*)d_in[9];
    const float* bs = (const float*)d_in[10];
    const float* Vs = (const float*)d_in[11];
    const float* cW = (const float*)d_in[12];
    const float* cb = (const float*)d_in[13];
    const float* Wt = (const float*)d_in[14];
    const float* bt = (const float*)d_in[15];
    const float* Wr = (const float*)d_in[16];
    const float* br = (const float*)d_in[17];
    const float* gamma = (const float*)d_in[18];
    const float* beta = (const float*)d_in[19];
    float* out = (float*)d_out;

    char* w = (char*)d_ws;
    constexpr size_t OFF_TMP1 = 0;            // 8192
    constexpr size_t OFF_PT = 8192;           // 4096
    constexpr size_t OFF_DEG = 12288;         // 8192
    constexpr size_t OFF_CNT = 20480;         // 8192
    constexpr size_t OFF_CURSOR = 28672;      // 8192
    constexpr size_t ZEND = 36864;
    constexpr size_t OFF_EMAT = ZEND;                     // 4096
    constexpr size_t OFF_LHS = OFF_EMAT + 4096;           // 512K
    constexpr size_t OFF_RHS = OFF_LHS + 524288;          // 512K
    constexpr size_t OFF_LHSS = OFF_RHS + 524288;         // 512K
    constexpr size_t OFF_RHSS = OFF_LHSS + 524288;        // 512K
    constexpr size_t OFF_DIAG = OFF_RHSS + 524288;        // 32K
    constexpr size_t OFF_ATT = OFF_DIAG + 32768;          // 512K
    constexpr size_t OFF_DINV = OFF_ATT + 524288;         // 8K
    constexpr size_t OFF_NORM = OFF_DINV + 8192;          // 128K
    constexpr size_t OFF_STARTS = OFF_NORM + 131072;      // 8448
    constexpr size_t OFF_EID = OFF_STARTS + 8448;         // 128K
    constexpr size_t OFF_WTT = OFF_EID + 131072;          // 48K
    constexpr size_t OFF_WRT = OFF_WTT + 49152;           // 8K
    constexpr size_t OFF_VSBF = OFF_WRT + 8192;           // 8MB (reused: pm/ps/Mf/Inv)
    constexpr size_t OFF_XT = OFF_VSBF + 8388608;         // 16MB (reused: Tx0)
    constexpr size_t OFF_SIGT = OFF_XT + 16777216;        // 32MB (reused: X_hat)
    constexpr size_t OFF_S = OFF_SIGT + 33554432;         // 64MB+ (reused: Tx1, Tx2)

    float* tmp1 = (float*)(w + OFF_TMP1);
    float* Pt = (float*)(w + OFF_PT);
    float* deg = (float*)(w + OFF_DEG);
    int* cnt = (int*)(w + OFF_CNT);
    int* cursor = (int*)(w + OFF_CURSOR);
    float* Emat = (float*)(w + OFF_EMAT);
    float* lhs = (float*)(w + OFF_LHS);
    float* rhs = (float*)(w + OFF_RHS);
    float* lhs_s = (float*)(w + OFF_LHSS);
    float* rhs_s = (float*)(w + OFF_RHSS);
    float* diagS = (float*)(w + OFF_DIAG);
    float* att = (float*)(w + OFF_ATT);
    float* dinv = (float*)(w + OFF_DINV);
    float* normv = (float*)(w + OFF_NORM);
    int* starts = (int*)(w + OFF_STARTS);
    int* eid = (int*)(w + OFF_EID);
    float* WtT = (float*)(w + OFF_WTT);
    float* WrT = (float*)(w + OFF_WRT);
    unsigned short* Vsbf = (unsigned short*)(w + OFF_VSBF);
    float* pm = (float*)(w + OFF_VSBF);                   // reuse after gemm
    float* ps = (float*)(w + OFF_VSBF + 524288);
    float* Mf = (float*)(w + OFF_VSBF + 1048576);
    float* Inv = (float*)(w + OFF_VSBF + 1048576 + 32768);
    float* Xt = (float*)(w + OFF_XT);
    float* Tx0 = Xt;
    unsigned short* sigT = (unsigned short*)(w + OFF_SIGT);
    float* Xh = (float*)(w + OFF_SIGT);
    float* S = (float*)(w + OFF_S);
    float* Tx1 = S;
    float* Tx2 = (float*)(w + OFF_S + 16777216);

    hipMemsetAsync(w, 0, ZEND, stream);

    // temporal attention
    k_u1reduce<<<BB * 64, 256, 0, stream>>>(X, U1, tmp1);
    k_mkrhs<<<BB * NN * TT / 256, 256, 0, stream>>>(X, U3, rhs);
    k_mklhs<<<BB * TT * 8, 256, 0, stream>>>(tmp1, U2, lhs);
    k_ptaccum<<<BB * 8, 256, 0, stream>>>(lhs, rhs, Pt);
    k_temporalatt<<<BB, 256, 0, stream>>>(Pt, be, Ve, Emat);
    k_applyemat<<<BB * NN * FIN / 256, 256, 0, stream>>>(X, Emat, Xt);

    // spatial attention
    k_spatiallr<<<BB * (NN / 16), 256, 0, stream>>>(Xt, W1, W2, W3, lhs_s, rhs_s);
    k_f2bf<<<NN * NN / 256, 256, 0, stream>>>(Vs, Vsbf);
    k_wtprep<<<48, 256, 0, stream>>>(Wt, Wr, WtT, WrT);
    k_makesigT<<<dim3(NN / 64, NN / 64, BB), 256, 0, stream>>>(lhs_s, rhs_s, bs, sigT);
    k_gemm_bt<<<dim3(NN / 128, NN / 128, BB), 256, 0, stream>>>(Vsbf, sigT, S, NN, NN, NN);

    // softmax statistics only (full normalized S never materialized)
    k_colreduce1<<<dim3(8, NSPLIT, BB), 256, 0, stream>>>(S, pm, ps);
    k_colreduce2<<<BB * NN / 256, 256, 0, stream>>>(pm, ps, Mf, Inv);

    // graph prep
    k_deg<<<EE / 256, 256, 0, stream>>>(row, col, deg);
    k_dinv<<<NN / 256, 256, 0, stream>>>(deg, dinv);
    k_norm<<<EE / 256, 256, 0, stream>>>(row, col, dinv, normv, cnt);
    k_scan<<<1, 256, 0, stream>>>(cnt, starts);
    k_scatter<<<EE / 256, 256, 0, stream>>>(row, starts, cursor, eid);
    k_diagatt<<<BB * EE / 256, 256, 0, stream>>>(S, row, col, normv, Mf, Inv, diagS, att);

    // chebyshev
    k_tx0<<<BB * NN * 512 / 256, 256, 0, stream>>>(X, diagS, Tx0);
    k_prop<<<BB * NN, 256, 0, stream>>>(Tx0, att, col, starts, eid, nullptr, Tx1, 0);
    k_prop<<<BB * NN, 256, 0, stream>>>(Tx1, att, col, starts, eid, Tx0, Tx2, 1);
    k_cheb<<<BB * NN / 4, 256, 0, stream>>>(Tx0, Tx1, Tx2, cW, cb, Xh);

    // final
    k_final<<<BB * NN / 4, 256, 0, stream>>>(Xh, X, WtT, bt, WrT, br, gamma, beta, out);
}

// Round 5
// 398.896 us; speedup vs baseline: 2.2502x; 1.0288x over previous
//
#include <hip/hip_runtime.h>
#include <hip/hip_bf16.h>

#define BB 4
#define NN 2048
#define FIN 32
#define TT 16
#define EE 32768
#define CC 64
#define TFo 64
#define NSPLIT 16

typedef __attribute__((ext_vector_type(8))) short bf16x8;
typedef __attribute__((ext_vector_type(4))) float f32x4;

typedef __attribute__((address_space(1))) const unsigned int as1_uint;
typedef __attribute__((address_space(3))) unsigned int as3_uint;

__device__ __forceinline__ void gload_lds16(const void* g, void* l) {
    __builtin_amdgcn_global_load_lds((as1_uint*)g, (as3_uint*)l, 16, 0, 0);
}

__device__ __forceinline__ unsigned short f2bf(float v) {
    unsigned u = __builtin_bit_cast(unsigned, v);
    unsigned r = (u + 0x7fffu + ((u >> 16) & 1u)) >> 16;
    return (unsigned short)r;
}

// ---------------- Stage A: temporal attention ----------------

// tmp1[b][f][t] = sum_n X[b][n][f][t] * U1[n]   (atomic accumulate, tmp1 pre-zeroed)
__global__ void k_u1reduce(const float* __restrict__ X, const float* __restrict__ U1,
                           float* __restrict__ tmp1) {
    int b = blockIdx.x >> 6;
    int n0 = (blockIdx.x & 63) * 32;
    float a0 = 0.f, a1 = 0.f;
    for (int i = 0; i < 32; ++i) {
        int n = n0 + i;
        float u = U1[n];
        const float* row = X + ((size_t)(b * NN + n)) * 512;
        a0 += u * row[threadIdx.x];
        a1 += u * row[threadIdx.x + 256];
    }
    atomicAdd(&tmp1[b * 512 + threadIdx.x], a0);
    atomicAdd(&tmp1[b * 512 + threadIdx.x + 256], a1);
}

// lhs[b][t][n'] = sum_f tmp1[b][f][t] * U2[f][n']
__global__ void k_mklhs(const float* __restrict__ tmp1, const float* __restrict__ U2,
                        float* __restrict__ lhs) {
    int npr = ((blockIdx.x & 7) << 8) + threadIdx.x;
    int bt = blockIdx.x >> 3;           // b*16 + t
    int b = bt >> 4, t = bt & 15;
    float acc = 0.f;
#pragma unroll
    for (int f = 0; f < 32; ++f) acc += tmp1[b * 512 + f * 16 + t] * U2[f * NN + npr];
    lhs[(size_t)bt * NN + npr] = acc;
}

// rhs[b][n][t] = sum_f U3[f]*X[b][n][f][t]
__global__ void k_mkrhs(const float* __restrict__ X, const float* __restrict__ U3,
                        float* __restrict__ rhs) {
    int idx = blockIdx.x * 256 + threadIdx.x;   // B*N*T
    int t = idx & 15;
    int bn = idx >> 4;
    float acc = 0.f;
#pragma unroll
    for (int f = 0; f < 32; ++f) acc += U3[f] * X[(size_t)bn * 512 + f * 16 + t];
    rhs[idx] = acc;
}

// Pt[b][t][s] += sum over n-chunk lhs[b][t][n]*rhs[b][n][s]   (Pt pre-zeroed)
__global__ void k_ptaccum(const float* __restrict__ lhs, const float* __restrict__ rhs,
                          float* __restrict__ Pt) {
    int b = blockIdx.x >> 3;
    int n0 = (blockIdx.x & 7) * 256;
    int t = threadIdx.x >> 4, s = threadIdx.x & 15;
    const float* lr = lhs + (size_t)b * TT * NN + (size_t)t * NN;
    const float* rr = rhs + (size_t)b * NN * TT;
    float acc = 0.f;
    for (int i = 0; i < 256; ++i) {
        int n = n0 + i;
        acc += lr[n] * rr[n * 16 + s];
    }
    atomicAdd(&Pt[b * 256 + threadIdx.x], acc);
}

// Emat[b][t][s]: sigmoid(+be), Ve-multiply, softmax over t
__global__ void k_temporalatt(const float* __restrict__ Pt, const float* __restrict__ be,
                              const float* __restrict__ Ve, float* __restrict__ Emat) {
    int b = blockIdx.x;
    int t = threadIdx.x >> 4, s = threadIdx.x & 15;
    __shared__ float sg[16][17];
    __shared__ float em[16][17];
    float v = Pt[b * 256 + t * 16 + s] + be[t * 16 + s];
    sg[t][s] = 1.f / (1.f + __expf(-v));
    __syncthreads();
    float e = 0.f;
#pragma unroll
    for (int u = 0; u < 16; ++u) e += Ve[t * 16 + u] * sg[u][s];
    em[t][s] = e;
    __syncthreads();
    float mx = -1e30f;
#pragma unroll
    for (int u = 0; u < 16; ++u) mx = fmaxf(mx, em[u][s]);
    float sum = 0.f;
#pragma unroll
    for (int u = 0; u < 16; ++u) sum += __expf(em[u][s] - mx);
    Emat[b * 256 + t * 16 + s] = __expf(e - mx) / sum;
}

// ---------------- Stage B: spatial attention (applyemat fused in) ----------------

// Computes Xt for 16 nodes in-LDS from X and Emat, then lhs_s / rhs_s.
// Xt never touches global memory.
__global__ void k_spatiallr(const float* __restrict__ X, const float* __restrict__ Emat,
                            const float* __restrict__ W1, const float* __restrict__ W2,
                            const float* __restrict__ W3,
                            float* __restrict__ lhs_s, float* __restrict__ rhs_s) {
    int b = blockIdx.x >> 7;
    int n0 = (blockIdx.x & 127) * 16;
    __shared__ float em[256];
    __shared__ float xb[16 * 32 * 17];   // Xt, [(nl*32+f)*17 + s]
    __shared__ float av[16 * 32];
    em[threadIdx.x] = Emat[b * 256 + threadIdx.x];
    __syncthreads();
#pragma unroll
    for (int ii = 0; ii < 2; ++ii) {
        int p = threadIdx.x * 2 + ii;    // nl*32 + f
        int nl = p >> 5, f = p & 31;
        const float4* src = (const float4*)(X + ((size_t)(b * NN + n0 + nl)) * 512 + f * 16);
        float4 q0 = src[0], q1 = src[1], q2 = src[2], q3 = src[3];
        float xv[16] = {q0.x, q0.y, q0.z, q0.w, q1.x, q1.y, q1.z, q1.w,
                        q2.x, q2.y, q2.z, q2.w, q3.x, q3.y, q3.z, q3.w};
        float o[16];
#pragma unroll
        for (int s = 0; s < 16; ++s) o[s] = 0.f;
#pragma unroll
        for (int t = 0; t < 16; ++t) {
            float xt = xv[t];
            const float* er = &em[t * 16];
#pragma unroll
            for (int s = 0; s < 16; ++s) o[s] += xt * er[s];
        }
        float a = 0.f;
#pragma unroll
        for (int s = 0; s < 16; ++s) { xb[p * 17 + s] = o[s]; a += o[s] * W1[s]; }
        av[p] = a;
    }
    __syncthreads();
    int nl = threadIdx.x >> 4, t = threadIdx.x & 15;
    float r = 0.f;
#pragma unroll
    for (int f = 0; f < 32; ++f) r += W3[f] * xb[(nl * 32 + f) * 17 + t];
    rhs_s[(size_t)b * TT * NN + (size_t)t * NN + n0 + nl] = r;
    float l = 0.f;
#pragma unroll
    for (int f = 0; f < 32; ++f) l += av[nl * 32 + f] * W2[f * 16 + t];
    lhs_s[((size_t)(b * NN + n0 + nl)) * 16 + t] = l;
}

// Vs fp32 -> bf16
__global__ void k_f2bf(const float* __restrict__ src, unsigned short* __restrict__ dst) {
    int i = blockIdx.x * 256 + threadIdx.x;
    dst[i] = f2bf(src[i]);
}

// weight transposes for final: WtT[(c*3+tap)*64+o] = Wt[(o*64+c)*3+tap]; WrT[f*64+o] = Wr[o*32+f]
__global__ void k_wtprep(const float* __restrict__ Wt, const float* __restrict__ Wr,
                         float* __restrict__ WtT, float* __restrict__ WrT) {
    int i = blockIdx.x * 256 + threadIdx.x;
    if (i < 64 * 64 * 3) {
        int o = i & 63;
        int ct = i >> 6;
        int c = ct / 3, tap = ct - c * 3;
        WtT[i] = Wt[(o * 64 + c) * 3 + tap];
    }
    if (i < 32 * 64) {
        int o = i & 63, f = i >> 6;
        WrT[i] = Wr[o * 32 + f];
    }
}

// sigT[b][k][m] = bf16(sigmoid(dot(lhs_s[b,m,:], rhs_s[b,:,k]) + bs[m,k]))
__global__ void k_makesigT(const float* __restrict__ lhs_s, const float* __restrict__ rhs_s,
                           const float* __restrict__ bs, unsigned short* __restrict__ sigT) {
    int k0 = blockIdx.x * 64, m0 = blockIdx.y * 64, b = blockIdx.z;
    __shared__ float lh[64][17];
    __shared__ float rh[16][64];
    __shared__ float bsl[64][65];
    int tid = threadIdx.x;
#pragma unroll
    for (int i = 0; i < 4; ++i) {
        int idx = tid + i * 256;
        int mi = idx >> 4, t = idx & 15;
        lh[mi][t] = lhs_s[((size_t)(b * NN + m0 + mi)) * 16 + t];
        int tt = idx >> 6, kj = idx & 63;
        rh[tt][kj] = rhs_s[(size_t)b * TT * NN + (size_t)tt * NN + k0 + kj];
    }
#pragma unroll
    for (int i = 0; i < 16; ++i) {
        int idx = tid + i * 256;
        int mi = idx >> 6, kj = idx & 63;
        bsl[mi][kj] = bs[(size_t)(m0 + mi) * NN + k0 + kj];
    }
    __syncthreads();
    int ml = tid & 63;
    int kg = (tid >> 6) * 16;
    unsigned short* out = sigT + (size_t)b * NN * NN;
#pragma unroll 4
    for (int ki = 0; ki < 16; ++ki) {
        int kl = kg + ki;
        float acc = bsl[ml][kl];
#pragma unroll
        for (int t = 0; t < 16; ++t) acc += lh[ml][t] * rh[t][kl];
        float sgv = 1.f / (1.f + __expf(-acc));
        out[(size_t)(k0 + kl) * NN + m0 + ml] = f2bf(sgv);
    }
}

// ---------------- The big GEMM: S[b][n][k] = sum_m Vs[n][m]*sigT[b][k][m] ----------------

__global__ __launch_bounds__(256) void k_gemm_bt(const unsigned short* __restrict__ A,
                                                 const unsigned short* __restrict__ Bt,
                                                 float* __restrict__ C,
                                                 int M, int N, int K) {
    __shared__ __align__(16) unsigned short lds[2][2][128 * 32];
    const int tid = threadIdx.x;
    const int wave = tid >> 6, lane = tid & 63;
    const int bm = blockIdx.y << 7;
    const int bn = blockIdx.x << 7;
    const unsigned short* Bb = Bt + (size_t)blockIdx.z * N * K;
    float* Cb = C + (size_t)blockIdx.z * M * N;
    const int wr = wave >> 1, wc = wave & 1;
    const int srow = lane >> 2, scol = (lane & 3) << 3;

    f32x4 acc[4][4];
#pragma unroll
    for (int i = 0; i < 4; ++i)
#pragma unroll
        for (int j = 0; j < 4; ++j) acc[i][j] = (f32x4){0.f, 0.f, 0.f, 0.f};

    const size_t abase = (size_t)(bm + srow) * K + scol;
    const size_t bbase = (size_t)(bn + srow) * K + scol;

#define STAGE(buf, k0)                                                              \
    {                                                                               \
        _Pragma("unroll")                                                           \
        for (int ii = 0; ii < 2; ++ii) {                                            \
            int rb = ((ii << 2) + wave) << 4;                                       \
            gload_lds16(A + abase + (size_t)rb * K + (k0), &lds[buf][0][rb * 32]);  \
            gload_lds16(Bb + bbase + (size_t)rb * K + (k0), &lds[buf][1][rb * 32]); \
        }                                                                           \
    }

    STAGE(0, 0)
    __syncthreads();
    const int nk = K >> 5;
    const int rl = lane & 15, kg = (lane >> 4) << 3;
    for (int t = 0; t < nk; ++t) {
        int cur = t & 1;
        if (t + 1 < nk) STAGE(cur ^ 1, (t + 1) << 5)
        const unsigned short* la = &lds[cur][0][0];
        const unsigned short* lb = &lds[cur][1][0];
        bf16x8 af[4], bfr[4];
#pragma unroll
        for (int i = 0; i < 4; ++i) af[i] = *(const bf16x8*)(la + ((wr << 6) + (i << 4) + rl) * 32 + kg);
#pragma unroll
        for (int j = 0; j < 4; ++j) bfr[j] = *(const bf16x8*)(lb + ((wc << 6) + (j << 4) + rl) * 32 + kg);
#pragma unroll
        for (int i = 0; i < 4; ++i)
#pragma unroll
            for (int j = 0; j < 4; ++j)
                acc[i][j] = __builtin_amdgcn_mfma_f32_16x16x32_bf16(af[i], bfr[j], acc[i][j], 0, 0, 0);
        __syncthreads();
    }
#undef STAGE
    const int cl = lane & 15, rg = (lane >> 4) << 2;
#pragma unroll
    for (int i = 0; i < 4; ++i)
#pragma unroll
        for (int j = 0; j < 4; ++j) {
            int m0 = bm + (wr << 6) + (i << 4) + rg;
            int n0 = bn + (wc << 6) + (j << 4) + cl;
#pragma unroll
            for (int r = 0; r < 4; ++r) Cb[(size_t)(m0 + r) * N + n0] = acc[i][j][r];
        }
}

// ---------------- column softmax statistics (only stats are needed!) ----------------
__global__ void k_colreduce1(const float* __restrict__ S, float* __restrict__ pm,
                             float* __restrict__ ps) {
    int b = blockIdx.z;
    int k0 = blockIdx.x << 8;
    int nbase = blockIdx.y << 7;
    int ktl = threadIdx.x & 63;
    int g = threadIdx.x >> 6;
    const float* base = S + (size_t)b * NN * NN + k0 + (ktl << 2);
    float m0 = -1e30f, m1 = -1e30f, m2 = -1e30f, m3 = -1e30f;
    float s0 = 0.f, s1 = 0.f, s2 = 0.f, s3 = 0.f;
    for (int i = g; i < 128; i += 4) {
        float4 v = *(const float4*)(base + (size_t)(nbase + i) * NN);
        float nm;
        nm = fmaxf(m0, v.x); s0 = s0 * __expf(m0 - nm) + __expf(v.x - nm); m0 = nm;
        nm = fmaxf(m1, v.y); s1 = s1 * __expf(m1 - nm) + __expf(v.y - nm); m1 = nm;
        nm = fmaxf(m2, v.z); s2 = s2 * __expf(m2 - nm) + __expf(v.z - nm); m2 = nm;
        nm = fmaxf(m3, v.w); s3 = s3 * __expf(m3 - nm) + __expf(v.w - nm); m3 = nm;
    }
    __shared__ float sm[4][64][4], ss[4][64][4];
    sm[g][ktl][0] = m0; sm[g][ktl][1] = m1; sm[g][ktl][2] = m2; sm[g][ktl][3] = m3;
    ss[g][ktl][0] = s0; ss[g][ktl][1] = s1; ss[g][ktl][2] = s2; ss[g][ktl][3] = s3;
    __syncthreads();
    int kc = threadIdx.x;
    float M = sm[0][kc >> 2][kc & 3], Ssum = ss[0][kc >> 2][kc & 3];
#pragma unroll
    for (int gi = 1; gi < 4; ++gi) {
        float mm = sm[gi][kc >> 2][kc & 3], sv = ss[gi][kc >> 2][kc & 3];
        float nm = fmaxf(M, mm);
        Ssum = Ssum * __expf(M - nm) + sv * __expf(mm - nm);
        M = nm;
    }
    size_t o = ((size_t)(b * NSPLIT + blockIdx.y) * NN) + k0 + kc;
    pm[o] = M; ps[o] = Ssum;
}

__global__ void k_colreduce2(const float* __restrict__ pm, const float* __restrict__ ps,
                             float* __restrict__ Mf, float* __restrict__ Inv) {
    int idx = blockIdx.x * 256 + threadIdx.x;
    float M = -1e30f, Ssum = 0.f;
#pragma unroll
    for (int i = 0; i < NSPLIT; ++i) {
        size_t o = ((size_t)((idx >> 11) * NSPLIT + i) * NN) + (idx & (NN - 1));
        float mm = pm[o], sv = ps[o];
        float nm = fmaxf(M, mm);
        Ssum = Ssum * __expf(M - nm) + sv * __expf(mm - nm);
        M = nm;
    }
    Mf[idx] = M;
    Inv[idx] = 1.f / Ssum;
}

__global__ void k_diagatt(const float* __restrict__ S, const int* __restrict__ row,
                          const int* __restrict__ col, const float* __restrict__ norm,
                          const float* __restrict__ Mf, const float* __restrict__ Inv,
                          float* __restrict__ diagS, float* __restrict__ att) {
    int idx = blockIdx.x * 256 + threadIdx.x;
    if (idx < BB * EE) {
        int b = idx >> 15, e = idx & (EE - 1);
        int c = col[e];
        float v = S[(size_t)b * NN * NN + (size_t)row[e] * NN + c];
        att[idx] = norm[e] * __expf(v - Mf[b * NN + c]) * Inv[b * NN + c];
    }
    if (idx < BB * NN) {
        float v = S[(size_t)(idx >> 11) * NN * NN + (size_t)(idx & (NN - 1)) * NN + (idx & (NN - 1))];
        diagS[idx] = __expf(v - Mf[idx]) * Inv[idx];
    }
}

// ---------------- graph prep ----------------

__global__ void k_deg(const int* __restrict__ row, const int* __restrict__ col,
                      float* __restrict__ deg) {
    int e = blockIdx.x * 256 + threadIdx.x;
    if (e < EE && row[e] != col[e]) atomicAdd(&deg[row[e]], 1.0f);
}

__global__ void k_dinv(const float* __restrict__ deg, float* __restrict__ dinv) {
    int n = blockIdx.x * 256 + threadIdx.x;
    if (n < NN) {
        float d = deg[n];
        dinv[n] = d > 0.f ? rsqrtf(fmaxf(d, 1e-12f)) : 0.f;
    }
}

__global__ void k_norm(const int* __restrict__ row, const int* __restrict__ col,
                       const float* __restrict__ dinv, float* __restrict__ norm,
                       int* __restrict__ cnt) {
    int e = blockIdx.x * 256 + threadIdx.x;
    if (e < EE) {
        int r = row[e], c = col[e];
        float w = (r != c) ? 1.f : 0.f;
        norm[e] = -dinv[r] * w * dinv[c];
        atomicAdd(&cnt[r], 1);
    }
}

__global__ void k_scan(const int* __restrict__ cnt, int* __restrict__ starts) {
    __shared__ int part[256];
    int t = threadIdx.x;
    int loc[8];
    int s = 0;
#pragma unroll
    for (int i = 0; i < 8; ++i) {
        int c = cnt[t * 8 + i];
        loc[i] = s;
        s += c;
    }
    part[t] = s;
    __syncthreads();
    for (int o = 1; o < 256; o <<= 1) {
        int v = (t >= o) ? part[t - o] : 0;
        __syncthreads();
        part[t] += v;
        __syncthreads();
    }
    int pbase = (t > 0) ? part[t - 1] : 0;
#pragma unroll
    for (int i = 0; i < 8; ++i) starts[t * 8 + i] = pbase + loc[i];
    if (t == 255) starts[NN] = part[255];
}

__global__ void k_scatter(const int* __restrict__ row, const int* __restrict__ starts,
                          int* __restrict__ cursor, int* __restrict__ eid) {
    int e = blockIdx.x * 256 + threadIdx.x;
    if (e < EE) {
        int r = row[e];
        int slot = atomicAdd(&cursor[r], 1);
        eid[starts[r] + slot] = e;
    }
}

// ---------------- Chebyshev ----------------

__global__ void k_tx0(const float* __restrict__ X, const float* __restrict__ diagS,
                      float* __restrict__ Tx0) {
    size_t idx = (size_t)blockIdx.x * 256 + threadIdx.x;
    Tx0[idx] = X[idx] * diagS[idx >> 9];
}

// out[b][n][:] = (mode ? 2*gather - sub : gather); 2 nodes/block, float4 lanes, 2-edge unroll
__global__ void k_prop(const float* __restrict__ x, const float* __restrict__ att,
                       const int* __restrict__ col, const int* __restrict__ starts,
                       const int* __restrict__ eid, const float* __restrict__ sub,
                       float* __restrict__ out, int mode) {
    int g = threadIdx.x >> 7;
    int l = threadIdx.x & 127;
    int bn = (blockIdx.x << 1) + g;
    int b = bn >> 11, n = bn & (NN - 1);
    int s0 = starts[n], s1 = starts[n + 1];
    const float* xb = x + (size_t)b * NN * 512;
    const float* attb = att + (size_t)b * EE;
    float ax = 0.f, ay = 0.f, az = 0.f, aw = 0.f;
    float bx = 0.f, by = 0.f, bz = 0.f, bw = 0.f;
    int jj = s0;
    for (; jj + 2 <= s1; jj += 2) {
        int e0 = eid[jj], e1 = eid[jj + 1];
        float a0 = attb[e0], a1 = attb[e1];
        float4 v0 = *((const float4*)(xb + (size_t)col[e0] * 512) + l);
        float4 v1 = *((const float4*)(xb + (size_t)col[e1] * 512) + l);
        ax += a0 * v0.x; ay += a0 * v0.y; az += a0 * v0.z; aw += a0 * v0.w;
        bx += a1 * v1.x; by += a1 * v1.y; bz += a1 * v1.z; bw += a1 * v1.w;
    }
    if (jj < s1) {
        int e0 = eid[jj];
        float a0 = attb[e0];
        float4 v0 = *((const float4*)(xb + (size_t)col[e0] * 512) + l);
        ax += a0 * v0.x; ay += a0 * v0.y; az += a0 * v0.z; aw += a0 * v0.w;
    }
    float rx = ax + bx, ry = ay + by, rz = az + bz, rw = aw + bw;
    size_t o = (size_t)bn * 512 + (l << 2);
    if (mode) {
        float4 sv = *(const float4*)(sub + o);
        rx = 2.f * rx - sv.x; ry = 2.f * ry - sv.y;
        rz = 2.f * rz - sv.z; rw = 2.f * rw - sv.w;
    }
    *(float4*)(out + o) = make_float4(rx, ry, rz, rw);
}

// ---------------- fused cheb conv + temporal conv + residual + LN ----------------
// one wave per node; lane = channel. X_hat lives only in LDS (aliased over the Tx stage).
#define XHP 20
__global__ __launch_bounds__(256) void k_chebfinal(
    const float* __restrict__ Tx0, const float* __restrict__ Tx1,
    const float* __restrict__ Tx2, const float* __restrict__ cW,
    const float* __restrict__ cb, const float* __restrict__ X,
    const float* __restrict__ WtT, const float* __restrict__ bt,
    const float* __restrict__ WrT, const float* __restrict__ br,
    const float* __restrict__ gamma, const float* __restrict__ beta,
    float* __restrict__ out) {
    int j = threadIdx.x >> 6;          // node in block (= wave)
    int o = threadIdx.x & 63;          // lane = channel
    int bn = (blockIdx.x << 2) + j;
    __shared__ float smem[4 * 1536];   // xs [4][3][512]; later aliased as xh [4][64*XHP]
    __shared__ float xr[4][512];       // X rows [f*16+t]
    float* xsj = &smem[j * 1536];
    {
        const float4* s0 = (const float4*)(Tx0 + (size_t)bn * 512);
        const float4* s1 = (const float4*)(Tx1 + (size_t)bn * 512);
        const float4* s2 = (const float4*)(Tx2 + (size_t)bn * 512);
        const float4* sx = (const float4*)(X + (size_t)bn * 512);
        float4* d0 = (float4*)xsj;
        float4* d1 = (float4*)(xsj + 512);
        float4* d2 = (float4*)(xsj + 1024);
        float4* dx = (float4*)&xr[j][0];
#pragma unroll
        for (int i = 0; i < 2; ++i) {
            d0[o + (i << 6)] = s0[o + (i << 6)];
            d1[o + (i << 6)] = s1[o + (i << 6)];
            d2[o + (i << 6)] = s2[o + (i << 6)];
            dx[o + (i << 6)] = sx[o + (i << 6)];
        }
    }
    __syncthreads();

    // --- cheb: lane = output channel c = o ---
    float h[16];
    float b0 = cb[o];
#pragma unroll
    for (int t = 0; t < 16; ++t) h[t] = b0;
#pragma unroll
    for (int k = 0; k < 3; ++k) {
#pragma unroll 8
        for (int f = 0; f < 32; ++f) {
            float wv = cW[(k * 32 + f) * 64 + o];
            const float4* xrow = (const float4*)(xsj + k * 512 + f * 16);
            float4 a = xrow[0], b4 = xrow[1], c4 = xrow[2], d4 = xrow[3];
            h[0] += a.x * wv;  h[1] += a.y * wv;  h[2] += a.z * wv;  h[3] += a.w * wv;
            h[4] += b4.x * wv; h[5] += b4.y * wv; h[6] += b4.z * wv; h[7] += b4.w * wv;
            h[8] += c4.x * wv; h[9] += c4.y * wv; h[10] += c4.z * wv; h[11] += c4.w * wv;
            h[12] += d4.x * wv; h[13] += d4.y * wv; h[14] += d4.z * wv; h[15] += d4.w * wv;
        }
    }
#pragma unroll
    for (int t = 0; t < 16; ++t) h[t] = fmaxf(h[t], 0.f);
    __syncthreads();                 // all xs reads complete — safe to alias

    float* xhj = &smem[j * (64 * XHP)];
#pragma unroll
    for (int t = 0; t < 16; ++t) xhj[o * XHP + t] = h[t];
    __syncthreads();

    // --- final: temporal conv + residual + LN, lane = output channel o ---
    float h2[16];
    float hinit = bt[o] + br[o];
#pragma unroll
    for (int t = 0; t < 16; ++t) h2[t] = hinit;
#pragma unroll 2
    for (int c = 0; c < 64; ++c) {
        float w0 = WtT[(c * 3 + 0) * 64 + o];
        float w1 = WtT[(c * 3 + 1) * 64 + o];
        float w2 = WtT[(c * 3 + 2) * 64 + o];
        const float4* xrow = (const float4*)(xhj + c * XHP);
        float4 a = xrow[0], b4 = xrow[1], c4 = xrow[2], d4 = xrow[3];
        float xv[16] = {a.x, a.y, a.z, a.w, b4.x, b4.y, b4.z, b4.w,
                        c4.x, c4.y, c4.z, c4.w, d4.x, d4.y, d4.z, d4.w};
#pragma unroll
        for (int t = 0; t < 16; ++t) {
            float xm = (t == 0) ? 0.f : xv[t - 1];
            float xp = (t == 15) ? 0.f : xv[t + 1];
            h2[t] += xm * w0 + xv[t] * w1 + xp * w2;
        }
    }
#pragma unroll 4
    for (int f = 0; f < 32; ++f) {
        float wr = WrT[(f << 6) + o];
        const float4* xrw = (const float4*)&xr[j][f * 16];
        float4 a = xrw[0], b4 = xrw[1], c4 = xrw[2], d4 = xrw[3];
        h2[0] += a.x * wr;  h2[1] += a.y * wr;  h2[2] += a.z * wr;  h2[3] += a.w * wr;
        h2[4] += b4.x * wr; h2[5] += b4.y * wr; h2[6] += b4.z * wr; h2[7] += b4.w * wr;
        h2[8] += c4.x * wr; h2[9] += c4.y * wr; h2[10] += c4.z * wr; h2[11] += c4.w * wr;
        h2[12] += d4.x * wr; h2[13] += d4.y * wr; h2[14] += d4.z * wr; h2[15] += d4.w * wr;
    }
#pragma unroll
    for (int t = 0; t < 16; ++t) h2[t] = fmaxf(h2[t], 0.f);
#pragma unroll
    for (int t = 0; t < 16; ++t) {
        float s1 = h2[t], s2 = h2[t] * h2[t];
#pragma unroll
        for (int m = 32; m >= 1; m >>= 1) {
            s1 += __shfl_xor(s1, m);
            s2 += __shfl_xor(s2, m);
        }
        float mu = s1 * (1.f / 64.f);
        float var = s2 * (1.f / 64.f) - mu * mu;
        h2[t] = (h2[t] - mu) * rsqrtf(var + 1e-5f);
    }
    float gm = gamma[o], bb = beta[o];
    float4* op = (float4*)(out + (size_t)bn * 1024 + (o << 4));
#pragma unroll
    for (int q = 0; q < 4; ++q)
        op[q] = make_float4(h2[q * 4 + 0] * gm + bb, h2[q * 4 + 1] * gm + bb,
                            h2[q * 4 + 2] * gm + bb, h2[q * 4 + 3] * gm + bb);
}

// ---------------- host ----------------

extern "C" void kernel_launch(void* const* d_in, const int* in_sizes, int n_in,
                              void* d_out, int out_size, void* d_ws, size_t ws_size,
                              hipStream_t stream) {
    (void)in_sizes; (void)n_in; (void)out_size; (void)ws_size;
    const float* X = (const float*)d_in[0];
    const int* ei = (const int*)d_in[1];
    const int* row = ei;
    const int* col = ei + EE;
    const float* U1 = (const float*)d_in[2];
    const float* U2 = (const float*)d_in[3];
    const float* U3 = (const float*)d_in[4];
    const float* be = (const float*)d_in[5];
    const float* Ve = (const float*)d_in[6];
    const float* W1 = (const float*)d_in[7];
    const float* W2 = (const float*)d_in[8];
    const float* W3 = (const float*)d_in[9];
    const float* bs = (const float*)d_in[10];
    const float* Vs = (const float*)d_in[11];
    const float* cW = (const float*)d_in[12];
    const float* cb = (const float*)d_in[13];
    const float* Wt = (const float*)d_in[14];
    const float* bt = (const float*)d_in[15];
    const float* Wr = (const float*)d_in[16];
    const float* br = (const float*)d_in[17];
    const float* gamma = (const float*)d_in[18];
    const float* beta = (const float*)d_in[19];
    float* out = (float*)d_out;

    char* w = (char*)d_ws;
    constexpr size_t OFF_TMP1 = 0;            // 8192
    constexpr size_t OFF_PT = 8192;           // 4096
    constexpr size_t OFF_DEG = 12288;         // 8192
    constexpr size_t OFF_CNT = 20480;         // 8192
    constexpr size_t OFF_CURSOR = 28672;      // 8192
    constexpr size_t ZEND = 36864;
    constexpr size_t OFF_EMAT = ZEND;                     // 4096
    constexpr size_t OFF_LHS = OFF_EMAT + 4096;           // 512K
    constexpr size_t OFF_RHS = OFF_LHS + 524288;          // 512K
    constexpr size_t OFF_LHSS = OFF_RHS + 524288;         // 512K
    constexpr size_t OFF_RHSS = OFF_LHSS + 524288;        // 512K
    constexpr size_t OFF_DIAG = OFF_RHSS + 524288;        // 32K
    constexpr size_t OFF_ATT = OFF_DIAG + 32768;          // 512K
    constexpr size_t OFF_DINV = OFF_ATT + 524288;         // 8K
    constexpr size_t OFF_NORM = OFF_DINV + 8192;          // 128K
    constexpr size_t OFF_STARTS = OFF_NORM + 131072;      // 8448
    constexpr size_t OFF_EID = OFF_STARTS + 8448;         // 128K
    constexpr size_t OFF_WTT = OFF_EID + 131072;          // 48K
    constexpr size_t OFF_WRT = OFF_WTT + 49152;           // 8K
    constexpr size_t OFF_VSBF = OFF_WRT + 8192;           // 8MB (reused: pm/ps/Mf/Inv)
    constexpr size_t OFF_TX0 = OFF_VSBF + 8388608;        // 16MB
    constexpr size_t OFF_SIGT = OFF_TX0 + 16777216;       // 32MB
    constexpr size_t OFF_S = OFF_SIGT + 33554432;         // 64MB+ (reused: Tx1, Tx2)

    float* tmp1 = (float*)(w + OFF_TMP1);
    float* Pt = (float*)(w + OFF_PT);
    float* deg = (float*)(w + OFF_DEG);
    int* cnt = (int*)(w + OFF_CNT);
    int* cursor = (int*)(w + OFF_CURSOR);
    float* Emat = (float*)(w + OFF_EMAT);
    float* lhs = (float*)(w + OFF_LHS);
    float* rhs = (float*)(w + OFF_RHS);
    float* lhs_s = (float*)(w + OFF_LHSS);
    float* rhs_s = (float*)(w + OFF_RHSS);
    float* diagS = (float*)(w + OFF_DIAG);
    float* att = (float*)(w + OFF_ATT);
    float* dinv = (float*)(w + OFF_DINV);
    float* normv = (float*)(w + OFF_NORM);
    int* starts = (int*)(w + OFF_STARTS);
    int* eid = (int*)(w + OFF_EID);
    float* WtT = (float*)(w + OFF_WTT);
    float* WrT = (float*)(w + OFF_WRT);
    unsigned short* Vsbf = (unsigned short*)(w + OFF_VSBF);
    float* pm = (float*)(w + OFF_VSBF);                   // reuse after gemm
    float* ps = (float*)(w + OFF_VSBF + 524288);
    float* Mf = (float*)(w + OFF_VSBF + 1048576);
    float* Inv = (float*)(w + OFF_VSBF + 1048576 + 32768);
    float* Tx0 = (float*)(w + OFF_TX0);
    unsigned short* sigT = (unsigned short*)(w + OFF_SIGT);
    float* S = (float*)(w + OFF_S);
    float* Tx1 = S;                            // reuse after diag/att extracted
    float* Tx2 = (float*)(w + OFF_S + 16777216);

    hipMemsetAsync(w, 0, ZEND, stream);

    // temporal attention
    k_u1reduce<<<BB * 64, 256, 0, stream>>>(X, U1, tmp1);
    k_mkrhs<<<BB * NN * TT / 256, 256, 0, stream>>>(X, U3, rhs);
    k_mklhs<<<BB * TT * 8, 256, 0, stream>>>(tmp1, U2, lhs);
    k_ptaccum<<<BB * 8, 256, 0, stream>>>(lhs, rhs, Pt);
    k_temporalatt<<<BB, 256, 0, stream>>>(Pt, be, Ve, Emat);

    // spatial attention (Xt computed in-LDS inside k_spatiallr)
    k_spatiallr<<<BB * (NN / 16), 256, 0, stream>>>(X, Emat, W1, W2, W3, lhs_s, rhs_s);
    k_f2bf<<<NN * NN / 256, 256, 0, stream>>>(Vs, Vsbf);
    k_wtprep<<<48, 256, 0, stream>>>(Wt, Wr, WtT, WrT);
    k_makesigT<<<dim3(NN / 64, NN / 64, BB), 256, 0, stream>>>(lhs_s, rhs_s, bs, sigT);
    k_gemm_bt<<<dim3(NN / 128, NN / 128, BB), 256, 0, stream>>>(Vsbf, sigT, S, NN, NN, NN);

    // softmax statistics only (full normalized S never materialized)
    k_colreduce1<<<dim3(8, NSPLIT, BB), 256, 0, stream>>>(S, pm, ps);
    k_colreduce2<<<BB * NN / 256, 256, 0, stream>>>(pm, ps, Mf, Inv);

    // graph prep
    k_deg<<<EE / 256, 256, 0, stream>>>(row, col, deg);
    k_dinv<<<NN / 256, 256, 0, stream>>>(deg, dinv);
    k_norm<<<EE / 256, 256, 0, stream>>>(row, col, dinv, normv, cnt);
    k_scan<<<1, 256, 0, stream>>>(cnt, starts);
    k_scatter<<<EE / 256, 256, 0, stream>>>(row, starts, cursor, eid);
    k_diagatt<<<BB * EE / 256, 256, 0, stream>>>(S, row, col, normv, Mf, Inv, diagS, att);

    // chebyshev
    k_tx0<<<BB * NN * 512 / 256, 256, 0, stream>>>(X, diagS, Tx0);
    k_prop<<<BB * NN / 2, 256, 0, stream>>>(Tx0, att, col, starts, eid, nullptr, Tx1, 0);
    k_prop<<<BB * NN / 2, 256, 0, stream>>>(Tx1, att, col, starts, eid, Tx0, Tx2, 1);

    // fused cheb conv + temporal conv + residual + LN
    k_chebfinal<<<BB * NN / 4, 256, 0, stream>>>(Tx0, Tx1, Tx2, cW, cb, X,
                                                 WtT, bt, WrT, br, gamma, beta, out);
}

// Round 6
// 397.962 us; speedup vs baseline: 2.2554x; 1.0023x over previous
//
#include <hip/hip_runtime.h>
#include <hip/hip_bf16.h>

#define BB 4
#define NN 2048
#define FIN 32
#define TT 16
#define EE 32768
#define CC 64
#define TFo 64
#define NSPLIT 16

typedef __attribute__((ext_vector_type(8))) short bf16x8;
typedef __attribute__((ext_vector_type(4))) float f32x4;

typedef __attribute__((address_space(1))) const unsigned int as1_uint;
typedef __attribute__((address_space(3))) unsigned int as3_uint;

__device__ __forceinline__ void gload_lds16(const void* g, void* l) {
    __builtin_amdgcn_global_load_lds((as1_uint*)g, (as3_uint*)l, 16, 0, 0);
}

__device__ __forceinline__ unsigned short f2bf(float v) {
    unsigned u = __builtin_bit_cast(unsigned, v);
    unsigned r = (u + 0x7fffu + ((u >> 16) & 1u)) >> 16;
    return (unsigned short)r;
}

// ---------------- Stage A: temporal attention ----------------

// tmp1[b][f][t] = sum_n X[b][n][f][t] * U1[n]   (atomic accumulate, tmp1 pre-zeroed)
__global__ void k_u1reduce(const float* __restrict__ X, const float* __restrict__ U1,
                           float* __restrict__ tmp1) {
    int b = blockIdx.x >> 6;
    int n0 = (blockIdx.x & 63) * 32;
    float a0 = 0.f, a1 = 0.f;
    for (int i = 0; i < 32; ++i) {
        int n = n0 + i;
        float u = U1[n];
        const float* row = X + ((size_t)(b * NN + n)) * 512;
        a0 += u * row[threadIdx.x];
        a1 += u * row[threadIdx.x + 256];
    }
    atomicAdd(&tmp1[b * 512 + threadIdx.x], a0);
    atomicAdd(&tmp1[b * 512 + threadIdx.x + 256], a1);
}

// lhs[b][t][n'] = sum_f tmp1[b][f][t] * U2[f][n']
__global__ void k_mklhs(const float* __restrict__ tmp1, const float* __restrict__ U2,
                        float* __restrict__ lhs) {
    int npr = ((blockIdx.x & 7) << 8) + threadIdx.x;
    int bt = blockIdx.x >> 3;           // b*16 + t
    int b = bt >> 4, t = bt & 15;
    float acc = 0.f;
#pragma unroll
    for (int f = 0; f < 32; ++f) acc += tmp1[b * 512 + f * 16 + t] * U2[f * NN + npr];
    lhs[(size_t)bt * NN + npr] = acc;
}

// rhs[b][n][t] = sum_f U3[f]*X[b][n][f][t]
__global__ void k_mkrhs(const float* __restrict__ X, const float* __restrict__ U3,
                        float* __restrict__ rhs) {
    int idx = blockIdx.x * 256 + threadIdx.x;   // B*N*T
    int t = idx & 15;
    int bn = idx >> 4;
    float acc = 0.f;
#pragma unroll
    for (int f = 0; f < 32; ++f) acc += U3[f] * X[(size_t)bn * 512 + f * 16 + t];
    rhs[idx] = acc;
}

// Pt[b][t][s] += sum over n-chunk lhs[b][t][n]*rhs[b][n][s]   (Pt pre-zeroed)
__global__ void k_ptaccum(const float* __restrict__ lhs, const float* __restrict__ rhs,
                          float* __restrict__ Pt) {
    int b = blockIdx.x >> 3;
    int n0 = (blockIdx.x & 7) * 256;
    int t = threadIdx.x >> 4, s = threadIdx.x & 15;
    const float* lr = lhs + (size_t)b * TT * NN + (size_t)t * NN;
    const float* rr = rhs + (size_t)b * NN * TT;
    float acc = 0.f;
    for (int i = 0; i < 256; ++i) {
        int n = n0 + i;
        acc += lr[n] * rr[n * 16 + s];
    }
    atomicAdd(&Pt[b * 256 + threadIdx.x], acc);
}

// Emat[b][t][s]: sigmoid(+be), Ve-multiply, softmax over t
__global__ void k_temporalatt(const float* __restrict__ Pt, const float* __restrict__ be,
                              const float* __restrict__ Ve, float* __restrict__ Emat) {
    int b = blockIdx.x;
    int t = threadIdx.x >> 4, s = threadIdx.x & 15;
    __shared__ float sg[16][17];
    __shared__ float em[16][17];
    float v = Pt[b * 256 + t * 16 + s] + be[t * 16 + s];
    sg[t][s] = 1.f / (1.f + __expf(-v));
    __syncthreads();
    float e = 0.f;
#pragma unroll
    for (int u = 0; u < 16; ++u) e += Ve[t * 16 + u] * sg[u][s];
    em[t][s] = e;
    __syncthreads();
    float mx = -1e30f;
#pragma unroll
    for (int u = 0; u < 16; ++u) mx = fmaxf(mx, em[u][s]);
    float sum = 0.f;
#pragma unroll
    for (int u = 0; u < 16; ++u) sum += __expf(em[u][s] - mx);
    Emat[b * 256 + t * 16 + s] = __expf(e - mx) / sum;
}

// ---------------- Stage B: spatial attention (applyemat fused in) ----------------

__global__ void k_spatiallr(const float* __restrict__ X, const float* __restrict__ Emat,
                            const float* __restrict__ W1, const float* __restrict__ W2,
                            const float* __restrict__ W3,
                            float* __restrict__ lhs_s, float* __restrict__ rhs_s) {
    int b = blockIdx.x >> 7;
    int n0 = (blockIdx.x & 127) * 16;
    __shared__ float em[256];
    __shared__ float xb[16 * 32 * 17];   // Xt, [(nl*32+f)*17 + s]
    __shared__ float av[16 * 32];
    em[threadIdx.x] = Emat[b * 256 + threadIdx.x];
    __syncthreads();
#pragma unroll
    for (int ii = 0; ii < 2; ++ii) {
        int p = threadIdx.x * 2 + ii;    // nl*32 + f
        int nl = p >> 5, f = p & 31;
        const float4* src = (const float4*)(X + ((size_t)(b * NN + n0 + nl)) * 512 + f * 16);
        float4 q0 = src[0], q1 = src[1], q2 = src[2], q3 = src[3];
        float xv[16] = {q0.x, q0.y, q0.z, q0.w, q1.x, q1.y, q1.z, q1.w,
                        q2.x, q2.y, q2.z, q2.w, q3.x, q3.y, q3.z, q3.w};
        float o[16];
#pragma unroll
        for (int s = 0; s < 16; ++s) o[s] = 0.f;
#pragma unroll
        for (int t = 0; t < 16; ++t) {
            float xt = xv[t];
            const float* er = &em[t * 16];
#pragma unroll
            for (int s = 0; s < 16; ++s) o[s] += xt * er[s];
        }
        float a = 0.f;
#pragma unroll
        for (int s = 0; s < 16; ++s) { xb[p * 17 + s] = o[s]; a += o[s] * W1[s]; }
        av[p] = a;
    }
    __syncthreads();
    int nl = threadIdx.x >> 4, t = threadIdx.x & 15;
    float r = 0.f;
#pragma unroll
    for (int f = 0; f < 32; ++f) r += W3[f] * xb[(nl * 32 + f) * 17 + t];
    rhs_s[(size_t)b * TT * NN + (size_t)t * NN + n0 + nl] = r;
    float l = 0.f;
#pragma unroll
    for (int f = 0; f < 32; ++f) l += av[nl * 32 + f] * W2[f * 16 + t];
    lhs_s[((size_t)(b * NN + n0 + nl)) * 16 + t] = l;
}

// Vs fp32 -> bf16
__global__ void k_f2bf(const float* __restrict__ src, unsigned short* __restrict__ dst) {
    int i = blockIdx.x * 256 + threadIdx.x;
    dst[i] = f2bf(src[i]);
}

// weight transposes for final: WtT[(c*3+tap)*64+o] = Wt[(o*64+c)*3+tap]; WrT[f*64+o] = Wr[o*32+f]
__global__ void k_wtprep(const float* __restrict__ Wt, const float* __restrict__ Wr,
                         float* __restrict__ WtT, float* __restrict__ WrT) {
    int i = blockIdx.x * 256 + threadIdx.x;
    if (i < 64 * 64 * 3) {
        int o = i & 63;
        int ct = i >> 6;
        int c = ct / 3, tap = ct - c * 3;
        WtT[i] = Wt[(o * 64 + c) * 3 + tap];
    }
    if (i < 32 * 64) {
        int o = i & 63, f = i >> 6;
        WrT[i] = Wr[o * 32 + f];
    }
}

// sigT[b][k][m] = bf16(sigmoid(dot(lhs_s[b,m,:], rhs_s[b,:,k]) + bs[m,k]))
__global__ void k_makesigT(const float* __restrict__ lhs_s, const float* __restrict__ rhs_s,
                           const float* __restrict__ bs, unsigned short* __restrict__ sigT) {
    int k0 = blockIdx.x * 64, m0 = blockIdx.y * 64, b = blockIdx.z;
    __shared__ float lh[64][17];
    __shared__ float rh[16][64];
    __shared__ float bsl[64][65];
    int tid = threadIdx.x;
#pragma unroll
    for (int i = 0; i < 4; ++i) {
        int idx = tid + i * 256;
        int mi = idx >> 4, t = idx & 15;
        lh[mi][t] = lhs_s[((size_t)(b * NN + m0 + mi)) * 16 + t];
        int tt = idx >> 6, kj = idx & 63;
        rh[tt][kj] = rhs_s[(size_t)b * TT * NN + (size_t)tt * NN + k0 + kj];
    }
#pragma unroll
    for (int i = 0; i < 16; ++i) {
        int idx = tid + i * 256;
        int mi = idx >> 6, kj = idx & 63;
        bsl[mi][kj] = bs[(size_t)(m0 + mi) * NN + k0 + kj];
    }
    __syncthreads();
    int ml = tid & 63;
    int kg = (tid >> 6) * 16;
    unsigned short* out = sigT + (size_t)b * NN * NN;
#pragma unroll 4
    for (int ki = 0; ki < 16; ++ki) {
        int kl = kg + ki;
        float acc = bsl[ml][kl];
#pragma unroll
        for (int t = 0; t < 16; ++t) acc += lh[ml][t] * rh[t][kl];
        float sgv = 1.f / (1.f + __expf(-acc));
        out[(size_t)(k0 + kl) * NN + m0 + ml] = f2bf(sgv);
    }
}

// ---------------- The big GEMM: S[b][n][k] = sum_m Vs[n][m]*sigT[b][k][m] ----------------

__global__ __launch_bounds__(256) void k_gemm_bt(const unsigned short* __restrict__ A,
                                                 const unsigned short* __restrict__ Bt,
                                                 float* __restrict__ C,
                                                 int M, int N, int K) {
    __shared__ __align__(16) unsigned short lds[2][2][128 * 32];
    const int tid = threadIdx.x;
    const int wave = tid >> 6, lane = tid & 63;
    const int bm = blockIdx.y << 7;
    const int bn = blockIdx.x << 7;
    const unsigned short* Bb = Bt + (size_t)blockIdx.z * N * K;
    float* Cb = C + (size_t)blockIdx.z * M * N;
    const int wr = wave >> 1, wc = wave & 1;
    const int srow = lane >> 2, scol = (lane & 3) << 3;

    f32x4 acc[4][4];
#pragma unroll
    for (int i = 0; i < 4; ++i)
#pragma unroll
        for (int j = 0; j < 4; ++j) acc[i][j] = (f32x4){0.f, 0.f, 0.f, 0.f};

    const size_t abase = (size_t)(bm + srow) * K + scol;
    const size_t bbase = (size_t)(bn + srow) * K + scol;

#define STAGE(buf, k0)                                                              \
    {                                                                               \
        _Pragma("unroll")                                                           \
        for (int ii = 0; ii < 2; ++ii) {                                            \
            int rb = ((ii << 2) + wave) << 4;                                       \
            gload_lds16(A + abase + (size_t)rb * K + (k0), &lds[buf][0][rb * 32]);  \
            gload_lds16(Bb + bbase + (size_t)rb * K + (k0), &lds[buf][1][rb * 32]); \
        }                                                                           \
    }

    STAGE(0, 0)
    __syncthreads();
    const int nk = K >> 5;
    const int rl = lane & 15, kg = (lane >> 4) << 3;
    for (int t = 0; t < nk; ++t) {
        int cur = t & 1;
        if (t + 1 < nk) STAGE(cur ^ 1, (t + 1) << 5)
        const unsigned short* la = &lds[cur][0][0];
        const unsigned short* lb = &lds[cur][1][0];
        bf16x8 af[4], bfr[4];
#pragma unroll
        for (int i = 0; i < 4; ++i) af[i] = *(const bf16x8*)(la + ((wr << 6) + (i << 4) + rl) * 32 + kg);
#pragma unroll
        for (int j = 0; j < 4; ++j) bfr[j] = *(const bf16x8*)(lb + ((wc << 6) + (j << 4) + rl) * 32 + kg);
#pragma unroll
        for (int i = 0; i < 4; ++i)
#pragma unroll
            for (int j = 0; j < 4; ++j)
                acc[i][j] = __builtin_amdgcn_mfma_f32_16x16x32_bf16(af[i], bfr[j], acc[i][j], 0, 0, 0);
        __syncthreads();
    }
#undef STAGE
    const int cl = lane & 15, rg = (lane >> 4) << 2;
#pragma unroll
    for (int i = 0; i < 4; ++i)
#pragma unroll
        for (int j = 0; j < 4; ++j) {
            int m0 = bm + (wr << 6) + (i << 4) + rg;
            int n0 = bn + (wc << 6) + (j << 4) + cl;
#pragma unroll
            for (int r = 0; r < 4; ++r) Cb[(size_t)(m0 + r) * N + n0] = acc[i][j][r];
        }
}

// ---------------- column softmax statistics (only stats are needed!) ----------------
__global__ void k_colreduce1(const float* __restrict__ S, float* __restrict__ pm,
                             float* __restrict__ ps) {
    int b = blockIdx.z;
    int k0 = blockIdx.x << 8;
    int nbase = blockIdx.y << 7;
    int ktl = threadIdx.x & 63;
    int g = threadIdx.x >> 6;
    const float* base = S + (size_t)b * NN * NN + k0 + (ktl << 2);
    float m0 = -1e30f, m1 = -1e30f, m2 = -1e30f, m3 = -1e30f;
    float s0 = 0.f, s1 = 0.f, s2 = 0.f, s3 = 0.f;
    for (int i = g; i < 128; i += 4) {
        float4 v = *(const float4*)(base + (size_t)(nbase + i) * NN);
        float nm;
        nm = fmaxf(m0, v.x); s0 = s0 * __expf(m0 - nm) + __expf(v.x - nm); m0 = nm;
        nm = fmaxf(m1, v.y); s1 = s1 * __expf(m1 - nm) + __expf(v.y - nm); m1 = nm;
        nm = fmaxf(m2, v.z); s2 = s2 * __expf(m2 - nm) + __expf(v.z - nm); m2 = nm;
        nm = fmaxf(m3, v.w); s3 = s3 * __expf(m3 - nm) + __expf(v.w - nm); m3 = nm;
    }
    __shared__ float sm[4][64][4], ss[4][64][4];
    sm[g][ktl][0] = m0; sm[g][ktl][1] = m1; sm[g][ktl][2] = m2; sm[g][ktl][3] = m3;
    ss[g][ktl][0] = s0; ss[g][ktl][1] = s1; ss[g][ktl][2] = s2; ss[g][ktl][3] = s3;
    __syncthreads();
    int kc = threadIdx.x;
    float M = sm[0][kc >> 2][kc & 3], Ssum = ss[0][kc >> 2][kc & 3];
#pragma unroll
    for (int gi = 1; gi < 4; ++gi) {
        float mm = sm[gi][kc >> 2][kc & 3], sv = ss[gi][kc >> 2][kc & 3];
        float nm = fmaxf(M, mm);
        Ssum = Ssum * __expf(M - nm) + sv * __expf(mm - nm);
        M = nm;
    }
    size_t o = ((size_t)(b * NSPLIT + blockIdx.y) * NN) + k0 + kc;
    pm[o] = M; ps[o] = Ssum;
}

__global__ void k_colreduce2(const float* __restrict__ pm, const float* __restrict__ ps,
                             float* __restrict__ Mf, float* __restrict__ Inv) {
    int idx = blockIdx.x * 256 + threadIdx.x;
    float M = -1e30f, Ssum = 0.f;
#pragma unroll
    for (int i = 0; i < NSPLIT; ++i) {
        size_t o = ((size_t)((idx >> 11) * NSPLIT + i) * NN) + (idx & (NN - 1));
        float mm = pm[o], sv = ps[o];
        float nm = fmaxf(M, mm);
        Ssum = Ssum * __expf(M - nm) + sv * __expf(mm - nm);
        M = nm;
    }
    Mf[idx] = M;
    Inv[idx] = 1.f / Ssum;
}

__global__ void k_diagatt(const float* __restrict__ S, const int* __restrict__ row,
                          const int* __restrict__ col, const float* __restrict__ norm,
                          const float* __restrict__ Mf, const float* __restrict__ Inv,
                          float* __restrict__ diagS, float* __restrict__ att) {
    int idx = blockIdx.x * 256 + threadIdx.x;
    if (idx < BB * EE) {
        int b = idx >> 15, e = idx & (EE - 1);
        int c = col[e];
        float v = S[(size_t)b * NN * NN + (size_t)row[e] * NN + c];
        att[idx] = norm[e] * __expf(v - Mf[b * NN + c]) * Inv[b * NN + c];
    }
    if (idx < BB * NN) {
        float v = S[(size_t)(idx >> 11) * NN * NN + (size_t)(idx & (NN - 1)) * NN + (idx & (NN - 1))];
        diagS[idx] = __expf(v - Mf[idx]) * Inv[idx];
    }
}

// ---------------- graph prep ----------------

__global__ void k_deg(const int* __restrict__ row, const int* __restrict__ col,
                      float* __restrict__ deg) {
    int e = blockIdx.x * 256 + threadIdx.x;
    if (e < EE && row[e] != col[e]) atomicAdd(&deg[row[e]], 1.0f);
}

__global__ void k_dinv(const float* __restrict__ deg, float* __restrict__ dinv) {
    int n = blockIdx.x * 256 + threadIdx.x;
    if (n < NN) {
        float d = deg[n];
        dinv[n] = d > 0.f ? rsqrtf(fmaxf(d, 1e-12f)) : 0.f;
    }
}

__global__ void k_norm(const int* __restrict__ row, const int* __restrict__ col,
                       const float* __restrict__ dinv, float* __restrict__ norm,
                       int* __restrict__ cnt) {
    int e = blockIdx.x * 256 + threadIdx.x;
    if (e < EE) {
        int r = row[e], c = col[e];
        float w = (r != c) ? 1.f : 0.f;
        norm[e] = -dinv[r] * w * dinv[c];
        atomicAdd(&cnt[r], 1);
    }
}

__global__ void k_scan(const int* __restrict__ cnt, int* __restrict__ starts) {
    __shared__ int part[256];
    int t = threadIdx.x;
    int loc[8];
    int s = 0;
#pragma unroll
    for (int i = 0; i < 8; ++i) {
        int c = cnt[t * 8 + i];
        loc[i] = s;
        s += c;
    }
    part[t] = s;
    __syncthreads();
    for (int o = 1; o < 256; o <<= 1) {
        int v = (t >= o) ? part[t - o] : 0;
        __syncthreads();
        part[t] += v;
        __syncthreads();
    }
    int pbase = (t > 0) ? part[t - 1] : 0;
#pragma unroll
    for (int i = 0; i < 8; ++i) starts[t * 8 + i] = pbase + loc[i];
    if (t == 255) starts[NN] = part[255];
}

__global__ void k_scatter(const int* __restrict__ row, const int* __restrict__ starts,
                          int* __restrict__ cursor, int* __restrict__ eid) {
    int e = blockIdx.x * 256 + threadIdx.x;
    if (e < EE) {
        int r = row[e];
        int slot = atomicAdd(&cursor[r], 1);
        eid[starts[r] + slot] = e;
    }
}

// ---------------- Chebyshev ----------------

__global__ void k_tx0(const float* __restrict__ X, const float* __restrict__ diagS,
                      float* __restrict__ Tx0) {
    size_t idx = (size_t)blockIdx.x * 256 + threadIdx.x;
    Tx0[idx] = X[idx] * diagS[idx >> 9];
}

// out[b][n][:] = (mode ? 2*gather - sub : gather); 2 nodes/block, float4 lanes, 2-edge unroll
__global__ void k_prop(const float* __restrict__ x, const float* __restrict__ att,
                       const int* __restrict__ col, const int* __restrict__ starts,
                       const int* __restrict__ eid, const float* __restrict__ sub,
                       float* __restrict__ out, int mode) {
    int g = threadIdx.x >> 7;
    int l = threadIdx.x & 127;
    int bn = (blockIdx.x << 1) + g;
    int b = bn >> 11, n = bn & (NN - 1);
    int s0 = starts[n], s1 = starts[n + 1];
    const float* xb = x + (size_t)b * NN * 512;
    const float* attb = att + (size_t)b * EE;
    float ax = 0.f, ay = 0.f, az = 0.f, aw = 0.f;
    float bx = 0.f, by = 0.f, bz = 0.f, bw = 0.f;
    int jj = s0;
    for (; jj + 2 <= s1; jj += 2) {
        int e0 = eid[jj], e1 = eid[jj + 1];
        float a0 = attb[e0], a1 = attb[e1];
        float4 v0 = *((const float4*)(xb + (size_t)col[e0] * 512) + l);
        float4 v1 = *((const float4*)(xb + (size_t)col[e1] * 512) + l);
        ax += a0 * v0.x; ay += a0 * v0.y; az += a0 * v0.z; aw += a0 * v0.w;
        bx += a1 * v1.x; by += a1 * v1.y; bz += a1 * v1.z; bw += a1 * v1.w;
    }
    if (jj < s1) {
        int e0 = eid[jj];
        float a0 = attb[e0];
        float4 v0 = *((const float4*)(xb + (size_t)col[e0] * 512) + l);
        ax += a0 * v0.x; ay += a0 * v0.y; az += a0 * v0.z; aw += a0 * v0.w;
    }
    float rx = ax + bx, ry = ay + by, rz = az + bz, rw = aw + bw;
    size_t o = (size_t)bn * 512 + (l << 2);
    if (mode) {
        float4 sv = *(const float4*)(sub + o);
        rx = 2.f * rx - sv.x; ry = 2.f * ry - sv.y;
        rz = 2.f * rz - sv.z; rw = 2.f * rw - sv.w;
    }
    *(float4*)(out + o) = make_float4(rx, ry, rz, rw);
}

// ---------------- fused cheb conv + temporal conv + residual + LN ----------------
// ONE WAVE PER NODE (64-thread blocks): barriers are intra-wave (cheap), LDS 8KB
// -> ~16 blocks/CU resident instead of 2. lane = channel.
#define XHP 20
__global__ __launch_bounds__(64) void k_chebfinal(
    const float* __restrict__ Tx0, const float* __restrict__ Tx1,
    const float* __restrict__ Tx2, const float* __restrict__ cW,
    const float* __restrict__ cb, const float* __restrict__ X,
    const float* __restrict__ WtT, const float* __restrict__ bt,
    const float* __restrict__ WrT, const float* __restrict__ br,
    const float* __restrict__ gamma, const float* __restrict__ beta,
    float* __restrict__ out) {
    int o = threadIdx.x;               // lane = channel
    int bn = blockIdx.x;
    __shared__ float xs[1536];         // 6 KB: [3][512]; later aliased as xh[64*XHP]
    __shared__ float xr[512];          // 2 KB: X row [f*16+t]
    {
        const float4* s0 = (const float4*)(Tx0 + (size_t)bn * 512);
        const float4* s1 = (const float4*)(Tx1 + (size_t)bn * 512);
        const float4* s2 = (const float4*)(Tx2 + (size_t)bn * 512);
        const float4* sx = (const float4*)(X + (size_t)bn * 512);
        float4* d0 = (float4*)xs;
        float4* d1 = (float4*)(xs + 512);
        float4* d2 = (float4*)(xs + 1024);
        float4* dx = (float4*)xr;
#pragma unroll
        for (int i = 0; i < 2; ++i) {
            d0[o + (i << 6)] = s0[o + (i << 6)];
            d1[o + (i << 6)] = s1[o + (i << 6)];
            d2[o + (i << 6)] = s2[o + (i << 6)];
            dx[o + (i << 6)] = sx[o + (i << 6)];
        }
    }
    __syncthreads();

    // --- cheb: lane = output channel c = o ---
    float h[16];
    float b0 = cb[o];
#pragma unroll
    for (int t = 0; t < 16; ++t) h[t] = b0;
#pragma unroll
    for (int k = 0; k < 3; ++k) {
#pragma unroll 8
        for (int f = 0; f < 32; ++f) {
            float wv = cW[(k * 32 + f) * 64 + o];
            const float4* xrow = (const float4*)(xs + k * 512 + f * 16);
            float4 a = xrow[0], b4 = xrow[1], c4 = xrow[2], d4 = xrow[3];
            h[0] += a.x * wv;  h[1] += a.y * wv;  h[2] += a.z * wv;  h[3] += a.w * wv;
            h[4] += b4.x * wv; h[5] += b4.y * wv; h[6] += b4.z * wv; h[7] += b4.w * wv;
            h[8] += c4.x * wv; h[9] += c4.y * wv; h[10] += c4.z * wv; h[11] += c4.w * wv;
            h[12] += d4.x * wv; h[13] += d4.y * wv; h[14] += d4.z * wv; h[15] += d4.w * wv;
        }
    }
#pragma unroll
    for (int t = 0; t < 16; ++t) h[t] = fmaxf(h[t], 0.f);
    __syncthreads();                 // wave-local: all xs reads done -> safe to alias

    float* xh = xs;                  // 64*XHP = 1280 floats <= 1536
#pragma unroll
    for (int q = 0; q < 4; ++q)
        *(float4*)(xh + o * XHP + q * 4) = make_float4(h[q*4+0], h[q*4+1], h[q*4+2], h[q*4+3]);
    __syncthreads();

    // --- final: temporal conv + residual + LN, lane = output channel o ---
    float h2[16];
    float hinit = bt[o] + br[o];
#pragma unroll
    for (int t = 0; t < 16; ++t) h2[t] = hinit;
#pragma unroll 2
    for (int c = 0; c < 64; ++c) {
        float w0 = WtT[(c * 3 + 0) * 64 + o];
        float w1 = WtT[(c * 3 + 1) * 64 + o];
        float w2 = WtT[(c * 3 + 2) * 64 + o];
        const float4* xrow = (const float4*)(xh + c * XHP);
        float4 a = xrow[0], b4 = xrow[1], c4 = xrow[2], d4 = xrow[3];
        float xv[16] = {a.x, a.y, a.z, a.w, b4.x, b4.y, b4.z, b4.w,
                        c4.x, c4.y, c4.z, c4.w, d4.x, d4.y, d4.z, d4.w};
#pragma unroll
        for (int t = 0; t < 16; ++t) {
            float xm = (t == 0) ? 0.f : xv[t - 1];
            float xp = (t == 15) ? 0.f : xv[t + 1];
            h2[t] += xm * w0 + xv[t] * w1 + xp * w2;
        }
    }
#pragma unroll 4
    for (int f = 0; f < 32; ++f) {
        float wr = WrT[(f << 6) + o];
        const float4* xrw = (const float4*)(xr + f * 16);
        float4 a = xrw[0], b4 = xrw[1], c4 = xrw[2], d4 = xrw[3];
        h2[0] += a.x * wr;  h2[1] += a.y * wr;  h2[2] += a.z * wr;  h2[3] += a.w * wr;
        h2[4] += b4.x * wr; h2[5] += b4.y * wr; h2[6] += b4.z * wr; h2[7] += b4.w * wr;
        h2[8] += c4.x * wr; h2[9] += c4.y * wr; h2[10] += c4.z * wr; h2[11] += c4.w * wr;
        h2[12] += d4.x * wr; h2[13] += d4.y * wr; h2[14] += d4.z * wr; h2[15] += d4.w * wr;
    }
#pragma unroll
    for (int t = 0; t < 16; ++t) h2[t] = fmaxf(h2[t], 0.f);
#pragma unroll
    for (int t = 0; t < 16; ++t) {
        float s1 = h2[t], s2 = h2[t] * h2[t];
#pragma unroll
        for (int m = 32; m >= 1; m >>= 1) {
            s1 += __shfl_xor(s1, m);
            s2 += __shfl_xor(s2, m);
        }
        float mu = s1 * (1.f / 64.f);
        float var = s2 * (1.f / 64.f) - mu * mu;
        h2[t] = (h2[t] - mu) * rsqrtf(var + 1e-5f);
    }
    float gm = gamma[o], bb = beta[o];
    float4* op = (float4*)(out + (size_t)bn * 1024 + (o << 4));
#pragma unroll
    for (int q = 0; q < 4; ++q)
        op[q] = make_float4(h2[q * 4 + 0] * gm + bb, h2[q * 4 + 1] * gm + bb,
                            h2[q * 4 + 2] * gm + bb, h2[q * 4 + 3] * gm + bb);
}

// ---------------- host ----------------

extern "C" void kernel_launch(void* const* d_in, const int* in_sizes, int n_in,
                              void* d_out, int out_size, void* d_ws, size_t ws_size,
                              hipStream_t stream) {
    (void)in_sizes; (void)n_in; (void)out_size; (void)ws_size;
    const float* X = (const float*)d_in[0];
    const int* ei = (const int*)d_in[1];
    const int* row = ei;
    const int* col = ei + EE;
    const float* U1 = (const float*)d_in[2];
    const float* U2 = (const float*)d_in[3];
    const float* U3 = (const float*)d_in[4];
    const float* be = (const float*)d_in[5];
    const float* Ve = (const float*)d_in[6];
    const float* W1 = (const float*)d_in[7];
    const float* W2 = (const float*)d_in[8];
    const float* W3 = (const float*)d_in[9];
    const float* bs = (const float*)d_in[10];
    const float* Vs = (const float*)d_in[11];
    const float* cW = (const float*)d_in[12];
    const float* cb = (const float*)d_in[13];
    const float* Wt = (const float*)d_in[14];
    const float* bt = (const float*)d_in[15];
    const float* Wr = (const float*)d_in[16];
    const float* br = (const float*)d_in[17];
    const float* gamma = (const float*)d_in[18];
    const float* beta = (const float*)d_in[19];
    float* out = (float*)d_out;

    char* w = (char*)d_ws;
    constexpr size_t OFF_TMP1 = 0;            // 8192
    constexpr size_t OFF_PT = 8192;           // 4096
    constexpr size_t OFF_DEG = 12288;         // 8192
    constexpr size_t OFF_CNT = 20480;         // 8192
    constexpr size_t OFF_CURSOR = 28672;      // 8192
    constexpr size_t ZEND = 36864;
    constexpr size_t OFF_EMAT = ZEND;                     // 4096
    constexpr size_t OFF_LHS = OFF_EMAT + 4096;           // 512K
    constexpr size_t OFF_RHS = OFF_LHS + 524288;          // 512K
    constexpr size_t OFF_LHSS = OFF_RHS + 524288;         // 512K
    constexpr size_t OFF_RHSS = OFF_LHSS + 524288;        // 512K
    constexpr size_t OFF_DIAG = OFF_RHSS + 524288;        // 32K
    constexpr size_t OFF_ATT = OFF_DIAG + 32768;          // 512K
    constexpr size_t OFF_DINV = OFF_ATT + 524288;         // 8K
    constexpr size_t OFF_NORM = OFF_DINV + 8192;          // 128K
    constexpr size_t OFF_STARTS = OFF_NORM + 131072;      // 8448
    constexpr size_t OFF_EID = OFF_STARTS + 8448;         // 128K
    constexpr size_t OFF_WTT = OFF_EID + 131072;          // 48K
    constexpr size_t OFF_WRT = OFF_WTT + 49152;           // 8K
    constexpr size_t OFF_VSBF = OFF_WRT + 8192;           // 8MB (reused: pm/ps/Mf/Inv)
    constexpr size_t OFF_TX0 = OFF_VSBF + 8388608;        // 16MB
    constexpr size_t OFF_SIGT = OFF_TX0 + 16777216;       // 32MB
    constexpr size_t OFF_S = OFF_SIGT + 33554432;         // 64MB+ (reused: Tx1, Tx2)

    float* tmp1 = (float*)(w + OFF_TMP1);
    float* Pt = (float*)(w + OFF_PT);
    float* deg = (float*)(w + OFF_DEG);
    int* cnt = (int*)(w + OFF_CNT);
    int* cursor = (int*)(w + OFF_CURSOR);
    float* Emat = (float*)(w + OFF_EMAT);
    float* lhs = (float*)(w + OFF_LHS);
    float* rhs = (float*)(w + OFF_RHS);
    float* lhs_s = (float*)(w + OFF_LHSS);
    float* rhs_s = (float*)(w + OFF_RHSS);
    float* diagS = (float*)(w + OFF_DIAG);
    float* att = (float*)(w + OFF_ATT);
    float* dinv = (float*)(w + OFF_DINV);
    float* normv = (float*)(w + OFF_NORM);
    int* starts = (int*)(w + OFF_STARTS);
    int* eid = (int*)(w + OFF_EID);
    float* WtT = (float*)(w + OFF_WTT);
    float* WrT = (float*)(w + OFF_WRT);
    unsigned short* Vsbf = (unsigned short*)(w + OFF_VSBF);
    float* pm = (float*)(w + OFF_VSBF);                   // reuse after gemm
    float* ps = (float*)(w + OFF_VSBF + 524288);
    float* Mf = (float*)(w + OFF_VSBF + 1048576);
    float* Inv = (float*)(w + OFF_VSBF + 1048576 + 32768);
    float* Tx0 = (float*)(w + OFF_TX0);
    unsigned short* sigT = (unsigned short*)(w + OFF_SIGT);
    float* S = (float*)(w + OFF_S);
    float* Tx1 = S;                            // reuse after diag/att extracted
    float* Tx2 = (float*)(w + OFF_S + 16777216);

    hipMemsetAsync(w, 0, ZEND, stream);

    // temporal attention
    k_u1reduce<<<BB * 64, 256, 0, stream>>>(X, U1, tmp1);
    k_mkrhs<<<BB * NN * TT / 256, 256, 0, stream>>>(X, U3, rhs);
    k_mklhs<<<BB * TT * 8, 256, 0, stream>>>(tmp1, U2, lhs);
    k_ptaccum<<<BB * 8, 256, 0, stream>>>(lhs, rhs, Pt);
    k_temporalatt<<<BB, 256, 0, stream>>>(Pt, be, Ve, Emat);

    // spatial attention (Xt computed in-LDS inside k_spatiallr)
    k_spatiallr<<<BB * (NN / 16), 256, 0, stream>>>(X, Emat, W1, W2, W3, lhs_s, rhs_s);
    k_f2bf<<<NN * NN / 256, 256, 0, stream>>>(Vs, Vsbf);
    k_wtprep<<<48, 256, 0, stream>>>(Wt, Wr, WtT, WrT);
    k_makesigT<<<dim3(NN / 64, NN / 64, BB), 256, 0, stream>>>(lhs_s, rhs_s, bs, sigT);
    k_gemm_bt<<<dim3(NN / 128, NN / 128, BB), 256, 0, stream>>>(Vsbf, sigT, S, NN, NN, NN);

    // softmax statistics only (full normalized S never materialized)
    k_colreduce1<<<dim3(8, NSPLIT, BB), 256, 0, stream>>>(S, pm, ps);
    k_colreduce2<<<BB * NN / 256, 256, 0, stream>>>(pm, ps, Mf, Inv);

    // graph prep
    k_deg<<<EE / 256, 256, 0, stream>>>(row, col, deg);
    k_dinv<<<NN / 256, 256, 0, stream>>>(deg, dinv);
    k_norm<<<EE / 256, 256, 0, stream>>>(row, col, dinv, normv, cnt);
    k_scan<<<1, 256, 0, stream>>>(cnt, starts);
    k_scatter<<<EE / 256, 256, 0, stream>>>(row, starts, cursor, eid);
    k_diagatt<<<BB * EE / 256, 256, 0, stream>>>(S, row, col, normv, Mf, Inv, diagS, att);

    // chebyshev
    k_tx0<<<BB * NN * 512 / 256, 256, 0, stream>>>(X, diagS, Tx0);
    k_prop<<<BB * NN / 2, 256, 0, stream>>>(Tx0, att, col, starts, eid, nullptr, Tx1, 0);
    k_prop<<<BB * NN / 2, 256, 0, stream>>>(Tx1, att, col, starts, eid, Tx0, Tx2, 1);

    // fused cheb conv + temporal conv + residual + LN (1 wave / node)
    k_chebfinal<<<BB * NN, 64, 0, stream>>>(Tx0, Tx1, Tx2, cW, cb, X,
                                            WtT, bt, WrT, br, gamma, beta, out);
}

// Round 7
// 318.944 us; speedup vs baseline: 2.8142x; 1.2477x over previous
//
#include <hip/hip_runtime.h>
#include <hip/hip_bf16.h>

#define BB 4
#define NN 2048
#define FIN 32
#define TT 16
#define EE 32768
#define CC 64
#define TFo 64
#define NSPLIT 16

typedef __attribute__((ext_vector_type(8))) short bf16x8;
typedef __attribute__((ext_vector_type(4))) float f32x4;

typedef __attribute__((address_space(1))) const unsigned int as1_uint;
typedef __attribute__((address_space(3))) unsigned int as3_uint;

__device__ __forceinline__ void gload_lds16(const void* g, void* l) {
    __builtin_amdgcn_global_load_lds((as1_uint*)g, (as3_uint*)l, 16, 0, 0);
}

__device__ __forceinline__ unsigned short f2bf(float v) {
    unsigned u = __builtin_bit_cast(unsigned, v);
    unsigned r = (u + 0x7fffu + ((u >> 16) & 1u)) >> 16;
    return (unsigned short)r;
}

// ---------------- Stage A: temporal attention ----------------

__global__ void k_u1reduce(const float* __restrict__ X, const float* __restrict__ U1,
                           float* __restrict__ tmp1) {
    int b = blockIdx.x >> 6;
    int n0 = (blockIdx.x & 63) * 32;
    float a0 = 0.f, a1 = 0.f;
    for (int i = 0; i < 32; ++i) {
        int n = n0 + i;
        float u = U1[n];
        const float* row = X + ((size_t)(b * NN + n)) * 512;
        a0 += u * row[threadIdx.x];
        a1 += u * row[threadIdx.x + 256];
    }
    atomicAdd(&tmp1[b * 512 + threadIdx.x], a0);
    atomicAdd(&tmp1[b * 512 + threadIdx.x + 256], a1);
}

__global__ void k_mklhs(const float* __restrict__ tmp1, const float* __restrict__ U2,
                        float* __restrict__ lhs) {
    int npr = ((blockIdx.x & 7) << 8) + threadIdx.x;
    int bt = blockIdx.x >> 3;           // b*16 + t
    int b = bt >> 4, t = bt & 15;
    float acc = 0.f;
#pragma unroll
    for (int f = 0; f < 32; ++f) acc += tmp1[b * 512 + f * 16 + t] * U2[f * NN + npr];
    lhs[(size_t)bt * NN + npr] = acc;
}

__global__ void k_mkrhs(const float* __restrict__ X, const float* __restrict__ U3,
                        float* __restrict__ rhs) {
    int idx = blockIdx.x * 256 + threadIdx.x;   // B*N*T
    int t = idx & 15;
    int bn = idx >> 4;
    float acc = 0.f;
#pragma unroll
    for (int f = 0; f < 32; ++f) acc += U3[f] * X[(size_t)bn * 512 + f * 16 + t];
    rhs[idx] = acc;
}

__global__ void k_ptaccum(const float* __restrict__ lhs, const float* __restrict__ rhs,
                          float* __restrict__ Pt) {
    int b = blockIdx.x >> 3;
    int n0 = (blockIdx.x & 7) * 256;
    int t = threadIdx.x >> 4, s = threadIdx.x & 15;
    const float* lr = lhs + (size_t)b * TT * NN + (size_t)t * NN;
    const float* rr = rhs + (size_t)b * NN * TT;
    float acc = 0.f;
    for (int i = 0; i < 256; ++i) {
        int n = n0 + i;
        acc += lr[n] * rr[n * 16 + s];
    }
    atomicAdd(&Pt[b * 256 + threadIdx.x], acc);
}

__global__ void k_temporalatt(const float* __restrict__ Pt, const float* __restrict__ be,
                              const float* __restrict__ Ve, float* __restrict__ Emat) {
    int b = blockIdx.x;
    int t = threadIdx.x >> 4, s = threadIdx.x & 15;
    __shared__ float sg[16][17];
    __shared__ float em[16][17];
    float v = Pt[b * 256 + t * 16 + s] + be[t * 16 + s];
    sg[t][s] = 1.f / (1.f + __expf(-v));
    __syncthreads();
    float e = 0.f;
#pragma unroll
    for (int u = 0; u < 16; ++u) e += Ve[t * 16 + u] * sg[u][s];
    em[t][s] = e;
    __syncthreads();
    float mx = -1e30f;
#pragma unroll
    for (int u = 0; u < 16; ++u) mx = fmaxf(mx, em[u][s]);
    float sum = 0.f;
#pragma unroll
    for (int u = 0; u < 16; ++u) sum += __expf(em[u][s] - mx);
    Emat[b * 256 + t * 16 + s] = __expf(e - mx) / sum;
}

// ---------------- Stage B: spatial attention (applyemat fused in) ----------------

__global__ void k_spatiallr(const float* __restrict__ X, const float* __restrict__ Emat,
                            const float* __restrict__ W1, const float* __restrict__ W2,
                            const float* __restrict__ W3,
                            float* __restrict__ lhs_s, float* __restrict__ rhs_s) {
    int b = blockIdx.x >> 7;
    int n0 = (blockIdx.x & 127) * 16;
    __shared__ float em[256];
    __shared__ float xb[16 * 32 * 17];   // Xt, [(nl*32+f)*17 + s]
    __shared__ float av[16 * 32];
    em[threadIdx.x] = Emat[b * 256 + threadIdx.x];
    __syncthreads();
#pragma unroll
    for (int ii = 0; ii < 2; ++ii) {
        int p = threadIdx.x * 2 + ii;    // nl*32 + f
        int nl = p >> 5, f = p & 31;
        const float4* src = (const float4*)(X + ((size_t)(b * NN + n0 + nl)) * 512 + f * 16);
        float4 q0 = src[0], q1 = src[1], q2 = src[2], q3 = src[3];
        float xv[16] = {q0.x, q0.y, q0.z, q0.w, q1.x, q1.y, q1.z, q1.w,
                        q2.x, q2.y, q2.z, q2.w, q3.x, q3.y, q3.z, q3.w};
        float o[16];
#pragma unroll
        for (int s = 0; s < 16; ++s) o[s] = 0.f;
#pragma unroll
        for (int t = 0; t < 16; ++t) {
            float xt = xv[t];
            const float* er = &em[t * 16];
#pragma unroll
            for (int s = 0; s < 16; ++s) o[s] += xt * er[s];
        }
        float a = 0.f;
#pragma unroll
        for (int s = 0; s < 16; ++s) { xb[p * 17 + s] = o[s]; a += o[s] * W1[s]; }
        av[p] = a;
    }
    __syncthreads();
    int nl = threadIdx.x >> 4, t = threadIdx.x & 15;
    float r = 0.f;
#pragma unroll
    for (int f = 0; f < 32; ++f) r += W3[f] * xb[(nl * 32 + f) * 17 + t];
    rhs_s[(size_t)b * TT * NN + (size_t)t * NN + n0 + nl] = r;
    float l = 0.f;
#pragma unroll
    for (int f = 0; f < 32; ++f) l += av[nl * 32 + f] * W2[f * 16 + t];
    lhs_s[((size_t)(b * NN + n0 + nl)) * 16 + t] = l;
}

// Vs fp32 -> bf16
__global__ void k_f2bf(const float* __restrict__ src, unsigned short* __restrict__ dst) {
    int i = blockIdx.x * 256 + threadIdx.x;
    dst[i] = f2bf(src[i]);
}

// ---------------- weight prep: exact per-lane MFMA A-fragments (bf16) ----------------
// WAcheb[ks][i][l][j]: A[row=c][kidx=k*32+f] from cW[k][f][c]       (3 ksteps)
// WAtc  [ks][i][l][j]: A[row=o][kidx=tap*64+c] from Wt[o][c][tap]   (6 ksteps)
// WAres [ i][l][j]   : A[row=o][k=f] from Wr[o][f]                  (1 kstep)
// btr[o] = bt[o]+br[o]
__global__ void k_wtprep(const float* __restrict__ cW, const float* __restrict__ Wt,
                         const float* __restrict__ Wr, const float* __restrict__ bt,
                         const float* __restrict__ br,
                         unsigned short* __restrict__ WAcheb,
                         unsigned short* __restrict__ WAtc,
                         unsigned short* __restrict__ WAres,
                         float* __restrict__ btr) {
    int idx = blockIdx.x * 256 + threadIdx.x;
    if (idx < 6144) {                      // cheb
        int j = idx & 7, l = (idx >> 3) & 63, fi = idx >> 9;   // fi = ks*4+i
        int row = ((fi & 3) << 4) + (l & 15);
        int kidx = ((fi >> 2) << 5) + ((l >> 4) << 3) + j;
        int k = kidx >> 5, f = kidx & 31;
        WAcheb[idx] = f2bf(cW[k * 2048 + f * 64 + row]);
    } else if (idx < 18432) {              // temporal conv
        int e = idx - 6144;
        int j = e & 7, l = (e >> 3) & 63, fi = e >> 9;         // fi = ks*4+i, ks<6
        int row = ((fi & 3) << 4) + (l & 15);
        int kidx = ((fi >> 2) << 5) + ((l >> 4) << 3) + j;
        int tap = kidx >> 6, c = kidx & 63;
        WAtc[e] = f2bf(Wt[row * 192 + c * 3 + tap]);
    } else if (idx < 20480) {              // residual
        int e = idx - 18432;
        int j = e & 7, l = (e >> 3) & 63, i = e >> 9;
        int row = (i << 4) + (l & 15);
        int f = ((l >> 4) << 3) + j;
        WAres[e] = f2bf(Wr[row * 32 + f]);
    } else if (idx < 20544) {
        int o = idx - 20480;
        btr[o] = bt[o] + br[o];
    }
}

// sigT[b][k][m] = bf16(sigmoid(dot(lhs_s[b,m,:], rhs_s[b,:,k]) + bs[m,k]))
__global__ void k_makesigT(const float* __restrict__ lhs_s, const float* __restrict__ rhs_s,
                           const float* __restrict__ bs, unsigned short* __restrict__ sigT) {
    int k0 = blockIdx.x * 64, m0 = blockIdx.y * 64, b = blockIdx.z;
    __shared__ float lh[64][17];
    __shared__ float rh[16][64];
    __shared__ float bsl[64][65];
    int tid = threadIdx.x;
#pragma unroll
    for (int i = 0; i < 4; ++i) {
        int idx = tid + i * 256;
        int mi = idx >> 4, t = idx & 15;
        lh[mi][t] = lhs_s[((size_t)(b * NN + m0 + mi)) * 16 + t];
        int tt = idx >> 6, kj = idx & 63;
        rh[tt][kj] = rhs_s[(size_t)b * TT * NN + (size_t)tt * NN + k0 + kj];
    }
#pragma unroll
    for (int i = 0; i < 16; ++i) {
        int idx = tid + i * 256;
        int mi = idx >> 6, kj = idx & 63;
        bsl[mi][kj] = bs[(size_t)(m0 + mi) * NN + k0 + kj];
    }
    __syncthreads();
    int ml = tid & 63;
    int kg = (tid >> 6) * 16;
    unsigned short* out = sigT + (size_t)b * NN * NN;
#pragma unroll 4
    for (int ki = 0; ki < 16; ++ki) {
        int kl = kg + ki;
        float acc = bsl[ml][kl];
#pragma unroll
        for (int t = 0; t < 16; ++t) acc += lh[ml][t] * rh[t][kl];
        float sgv = 1.f / (1.f + __expf(-acc));
        out[(size_t)(k0 + kl) * NN + m0 + ml] = f2bf(sgv);
    }
}

// ---------------- The big GEMM: S[b][n][k] = sum_m Vs[n][m]*sigT[b][k][m] ----------------

__global__ __launch_bounds__(256) void k_gemm_bt(const unsigned short* __restrict__ A,
                                                 const unsigned short* __restrict__ Bt,
                                                 float* __restrict__ C,
                                                 int M, int N, int K) {
    __shared__ __align__(16) unsigned short lds[2][2][128 * 32];
    const int tid = threadIdx.x;
    const int wave = tid >> 6, lane = tid & 63;
    const int bm = blockIdx.y << 7;
    const int bn = blockIdx.x << 7;
    const unsigned short* Bb = Bt + (size_t)blockIdx.z * N * K;
    float* Cb = C + (size_t)blockIdx.z * M * N;
    const int wr = wave >> 1, wc = wave & 1;
    const int srow = lane >> 2, scol = (lane & 3) << 3;

    f32x4 acc[4][4];
#pragma unroll
    for (int i = 0; i < 4; ++i)
#pragma unroll
        for (int j = 0; j < 4; ++j) acc[i][j] = (f32x4){0.f, 0.f, 0.f, 0.f};

    const size_t abase = (size_t)(bm + srow) * K + scol;
    const size_t bbase = (size_t)(bn + srow) * K + scol;

#define STAGE(buf, k0)                                                              \
    {                                                                               \
        _Pragma("unroll")                                                           \
        for (int ii = 0; ii < 2; ++ii) {                                            \
            int rb = ((ii << 2) + wave) << 4;                                       \
            gload_lds16(A + abase + (size_t)rb * K + (k0), &lds[buf][0][rb * 32]);  \
            gload_lds16(Bb + bbase + (size_t)rb * K + (k0), &lds[buf][1][rb * 32]); \
        }                                                                           \
    }

    STAGE(0, 0)
    __syncthreads();
    const int nk = K >> 5;
    const int rl = lane & 15, kg = (lane >> 4) << 3;
    for (int t = 0; t < nk; ++t) {
        int cur = t & 1;
        if (t + 1 < nk) STAGE(cur ^ 1, (t + 1) << 5)
        const unsigned short* la = &lds[cur][0][0];
        const unsigned short* lb = &lds[cur][1][0];
        bf16x8 af[4], bfr[4];
#pragma unroll
        for (int i = 0; i < 4; ++i) af[i] = *(const bf16x8*)(la + ((wr << 6) + (i << 4) + rl) * 32 + kg);
#pragma unroll
        for (int j = 0; j < 4; ++j) bfr[j] = *(const bf16x8*)(lb + ((wc << 6) + (j << 4) + rl) * 32 + kg);
#pragma unroll
        for (int i = 0; i < 4; ++i)
#pragma unroll
            for (int j = 0; j < 4; ++j)
                acc[i][j] = __builtin_amdgcn_mfma_f32_16x16x32_bf16(af[i], bfr[j], acc[i][j], 0, 0, 0);
        __syncthreads();
    }
#undef STAGE
    const int cl = lane & 15, rg = (lane >> 4) << 2;
#pragma unroll
    for (int i = 0; i < 4; ++i)
#pragma unroll
        for (int j = 0; j < 4; ++j) {
            int m0 = bm + (wr << 6) + (i << 4) + rg;
            int n0 = bn + (wc << 6) + (j << 4) + cl;
#pragma unroll
            for (int r = 0; r < 4; ++r) Cb[(size_t)(m0 + r) * N + n0] = acc[i][j][r];
        }
}

// ---------------- column softmax statistics (only stats are needed!) ----------------
__global__ void k_colreduce1(const float* __restrict__ S, float* __restrict__ pm,
                             float* __restrict__ ps) {
    int b = blockIdx.z;
    int k0 = blockIdx.x << 8;
    int nbase = blockIdx.y << 7;
    int ktl = threadIdx.x & 63;
    int g = threadIdx.x >> 6;
    const float* base = S + (size_t)b * NN * NN + k0 + (ktl << 2);
    float m0 = -1e30f, m1 = -1e30f, m2 = -1e30f, m3 = -1e30f;
    float s0 = 0.f, s1 = 0.f, s2 = 0.f, s3 = 0.f;
    for (int i = g; i < 128; i += 4) {
        float4 v = *(const float4*)(base + (size_t)(nbase + i) * NN);
        float nm;
        nm = fmaxf(m0, v.x); s0 = s0 * __expf(m0 - nm) + __expf(v.x - nm); m0 = nm;
        nm = fmaxf(m1, v.y); s1 = s1 * __expf(m1 - nm) + __expf(v.y - nm); m1 = nm;
        nm = fmaxf(m2, v.z); s2 = s2 * __expf(m2 - nm) + __expf(v.z - nm); m2 = nm;
        nm = fmaxf(m3, v.w); s3 = s3 * __expf(m3 - nm) + __expf(v.w - nm); m3 = nm;
    }
    __shared__ float sm[4][64][4], ss[4][64][4];
    sm[g][ktl][0] = m0; sm[g][ktl][1] = m1; sm[g][ktl][2] = m2; sm[g][ktl][3] = m3;
    ss[g][ktl][0] = s0; ss[g][ktl][1] = s1; ss[g][ktl][2] = s2; ss[g][ktl][3] = s3;
    __syncthreads();
    int kc = threadIdx.x;
    float M = sm[0][kc >> 2][kc & 3], Ssum = ss[0][kc >> 2][kc & 3];
#pragma unroll
    for (int gi = 1; gi < 4; ++gi) {
        float mm = sm[gi][kc >> 2][kc & 3], sv = ss[gi][kc >> 2][kc & 3];
        float nm = fmaxf(M, mm);
        Ssum = Ssum * __expf(M - nm) + sv * __expf(mm - nm);
        M = nm;
    }
    size_t o = ((size_t)(b * NSPLIT + blockIdx.y) * NN) + k0 + kc;
    pm[o] = M; ps[o] = Ssum;
}

__global__ void k_colreduce2(const float* __restrict__ pm, const float* __restrict__ ps,
                             float* __restrict__ Mf, float* __restrict__ Inv) {
    int idx = blockIdx.x * 256 + threadIdx.x;
    float M = -1e30f, Ssum = 0.f;
#pragma unroll
    for (int i = 0; i < NSPLIT; ++i) {
        size_t o = ((size_t)((idx >> 11) * NSPLIT + i) * NN) + (idx & (NN - 1));
        float mm = pm[o], sv = ps[o];
        float nm = fmaxf(M, mm);
        Ssum = Ssum * __expf(M - nm) + sv * __expf(mm - nm);
        M = nm;
    }
    Mf[idx] = M;
    Inv[idx] = 1.f / Ssum;
}

__global__ void k_diagatt(const float* __restrict__ S, const int* __restrict__ row,
                          const int* __restrict__ col, const float* __restrict__ norm,
                          const float* __restrict__ Mf, const float* __restrict__ Inv,
                          float* __restrict__ diagS, float* __restrict__ att) {
    int idx = blockIdx.x * 256 + threadIdx.x;
    if (idx < BB * EE) {
        int b = idx >> 15, e = idx & (EE - 1);
        int c = col[e];
        float v = S[(size_t)b * NN * NN + (size_t)row[e] * NN + c];
        att[idx] = norm[e] * __expf(v - Mf[b * NN + c]) * Inv[b * NN + c];
    }
    if (idx < BB * NN) {
        float v = S[(size_t)(idx >> 11) * NN * NN + (size_t)(idx & (NN - 1)) * NN + (idx & (NN - 1))];
        diagS[idx] = __expf(v - Mf[idx]) * Inv[idx];
    }
}

// ---------------- graph prep ----------------

__global__ void k_deg(const int* __restrict__ row, const int* __restrict__ col,
                      float* __restrict__ deg) {
    int e = blockIdx.x * 256 + threadIdx.x;
    if (e < EE && row[e] != col[e]) atomicAdd(&deg[row[e]], 1.0f);
}

__global__ void k_dinv(const float* __restrict__ deg, float* __restrict__ dinv) {
    int n = blockIdx.x * 256 + threadIdx.x;
    if (n < NN) {
        float d = deg[n];
        dinv[n] = d > 0.f ? rsqrtf(fmaxf(d, 1e-12f)) : 0.f;
    }
}

__global__ void k_norm(const int* __restrict__ row, const int* __restrict__ col,
                       const float* __restrict__ dinv, float* __restrict__ norm,
                       int* __restrict__ cnt) {
    int e = blockIdx.x * 256 + threadIdx.x;
    if (e < EE) {
        int r = row[e], c = col[e];
        float w = (r != c) ? 1.f : 0.f;
        norm[e] = -dinv[r] * w * dinv[c];
        atomicAdd(&cnt[r], 1);
    }
}

__global__ void k_scan(const int* __restrict__ cnt, int* __restrict__ starts) {
    __shared__ int part[256];
    int t = threadIdx.x;
    int loc[8];
    int s = 0;
#pragma unroll
    for (int i = 0; i < 8; ++i) {
        int c = cnt[t * 8 + i];
        loc[i] = s;
        s += c;
    }
    part[t] = s;
    __syncthreads();
    for (int o = 1; o < 256; o <<= 1) {
        int v = (t >= o) ? part[t - o] : 0;
        __syncthreads();
        part[t] += v;
        __syncthreads();
    }
    int pbase = (t > 0) ? part[t - 1] : 0;
#pragma unroll
    for (int i = 0; i < 8; ++i) starts[t * 8 + i] = pbase + loc[i];
    if (t == 255) starts[NN] = part[255];
}

__global__ void k_scatter(const int* __restrict__ row, const int* __restrict__ starts,
                          int* __restrict__ cursor, int* __restrict__ eid) {
    int e = blockIdx.x * 256 + threadIdx.x;
    if (e < EE) {
        int r = row[e];
        int slot = atomicAdd(&cursor[r], 1);
        eid[starts[r] + slot] = e;
    }
}

// ---------------- Chebyshev ----------------

__global__ void k_tx0(const float* __restrict__ X, const float* __restrict__ diagS,
                      float* __restrict__ Tx0) {
    size_t idx = (size_t)blockIdx.x * 256 + threadIdx.x;
    Tx0[idx] = X[idx] * diagS[idx >> 9];
}

__global__ void k_prop(const float* __restrict__ x, const float* __restrict__ att,
                       const int* __restrict__ col, const int* __restrict__ starts,
                       const int* __restrict__ eid, const float* __restrict__ sub,
                       float* __restrict__ out, int mode) {
    int g = threadIdx.x >> 7;
    int l = threadIdx.x & 127;
    int bn = (blockIdx.x << 1) + g;
    int b = bn >> 11, n = bn & (NN - 1);
    int s0 = starts[n], s1 = starts[n + 1];
    const float* xb = x + (size_t)b * NN * 512;
    const float* attb = att + (size_t)b * EE;
    float ax = 0.f, ay = 0.f, az = 0.f, aw = 0.f;
    float bx = 0.f, by = 0.f, bz = 0.f, bw = 0.f;
    int jj = s0;
    for (; jj + 2 <= s1; jj += 2) {
        int e0 = eid[jj], e1 = eid[jj + 1];
        float a0 = attb[e0], a1 = attb[e1];
        float4 v0 = *((const float4*)(xb + (size_t)col[e0] * 512) + l);
        float4 v1 = *((const float4*)(xb + (size_t)col[e1] * 512) + l);
        ax += a0 * v0.x; ay += a0 * v0.y; az += a0 * v0.z; aw += a0 * v0.w;
        bx += a1 * v1.x; by += a1 * v1.y; bz += a1 * v1.z; bw += a1 * v1.w;
    }
    if (jj < s1) {
        int e0 = eid[jj];
        float a0 = attb[e0];
        float4 v0 = *((const float4*)(xb + (size_t)col[e0] * 512) + l);
        ax += a0 * v0.x; ay += a0 * v0.y; az += a0 * v0.z; aw += a0 * v0.w;
    }
    float rx = ax + bx, ry = ay + by, rz = az + bz, rw = aw + bw;
    size_t o = (size_t)bn * 512 + (l << 2);
    if (mode) {
        float4 sv = *(const float4*)(sub + o);
        rx = 2.f * rx - sv.x; ry = 2.f * ry - sv.y;
        rz = 2.f * rz - sv.z; rw = 2.f * rw - sv.w;
    }
    *(float4*)(out + o) = make_float4(rx, ry, rz, rw);
}

// ---------------- fused cheb + temporal conv + residual + LN via MFMA ----------------
// 1 wave / node. Per-node matmuls: cheb 64x16xK96, tconv 64x16xK192, res 64x16xK32.
// B operands staged transposed-bf16 in LDS (per-lane-distinct reads, no broadcast).
// A operands = precomputed per-lane fragments in global (L2). D layout: col=lane&15(=t),
// row=(lane>>4)*4+r — same convention as the verified k_gemm_bt.
#define XSP 104   // xsT row stride (shorts): 16 rows x [kidx 0..95]
#define XHP2 72   // xhT row stride (shorts): 18 rows x [c 0..63] (rows 0,17 = zero pad)
#define XTP 40    // XT row stride (shorts): 16 rows x [f 0..31]
__global__ __launch_bounds__(64) void k_chebfinal(
    const float* __restrict__ Tx0, const float* __restrict__ Tx1,
    const float* __restrict__ Tx2, const float* __restrict__ X,
    const unsigned short* __restrict__ WAcheb,
    const unsigned short* __restrict__ WAtc,
    const unsigned short* __restrict__ WAres,
    const float* __restrict__ cb, const float* __restrict__ btr,
    const float* __restrict__ gamma, const float* __restrict__ beta,
    float* __restrict__ out) {
    int l = threadIdx.x;
    int bn = blockIdx.x;
    int tl = l & 15, fg = l >> 4;
    __shared__ unsigned short xsT[16 * XSP];
    __shared__ unsigned short xhT[18 * XHP2];
    __shared__ unsigned short XT[16 * XTP];
    xhT[l] = 0;
    xhT[17 * XHP2 + l] = 0;
    size_t nb = (size_t)bn * 512;
    {
        bf16x8 v;
#pragma unroll
        for (int j = 0; j < 8; ++j) v[j] = (short)f2bf(Tx0[nb + (fg * 8 + j) * 16 + tl]);
        *(bf16x8*)&xsT[tl * XSP + fg * 8] = v;
#pragma unroll
        for (int j = 0; j < 8; ++j) v[j] = (short)f2bf(Tx1[nb + (fg * 8 + j) * 16 + tl]);
        *(bf16x8*)&xsT[tl * XSP + 32 + fg * 8] = v;
#pragma unroll
        for (int j = 0; j < 8; ++j) v[j] = (short)f2bf(Tx2[nb + (fg * 8 + j) * 16 + tl]);
        *(bf16x8*)&xsT[tl * XSP + 64 + fg * 8] = v;
#pragma unroll
        for (int j = 0; j < 8; ++j) v[j] = (short)f2bf(X[nb + (fg * 8 + j) * 16 + tl]);
        *(bf16x8*)&XT[tl * XTP + fg * 8] = v;
    }
    __syncthreads();

    // --- cheb: D[c][t] = sum_kidx cW'[c][kidx] * xsT[t][kidx] ---
    f32x4 acc[4];
#pragma unroll
    for (int i = 0; i < 4; ++i) acc[i] = (f32x4){0.f, 0.f, 0.f, 0.f};
#pragma unroll
    for (int ks = 0; ks < 3; ++ks) {
        bf16x8 bfrag = *(const bf16x8*)&xsT[tl * XSP + ks * 32 + fg * 8];
#pragma unroll
        for (int i = 0; i < 4; ++i)
            acc[i] = __builtin_amdgcn_mfma_f32_16x16x32_bf16(
                *(const bf16x8*)&WAcheb[((ks * 4 + i) * 64 + l) * 8], bfrag, acc[i], 0, 0, 0);
    }
    // + cb, relu, write transposed-bf16 xh
#pragma unroll
    for (int i = 0; i < 4; ++i) {
        int cbase = i * 16 + fg * 4;
        float4 cv = *(const float4*)&cb[cbase];
        float h0 = fmaxf(acc[i][0] + cv.x, 0.f);
        float h1 = fmaxf(acc[i][1] + cv.y, 0.f);
        float h2v = fmaxf(acc[i][2] + cv.z, 0.f);
        float h3 = fmaxf(acc[i][3] + cv.w, 0.f);
        unsigned lo = (unsigned)f2bf(h0) | ((unsigned)f2bf(h1) << 16);
        unsigned hi = (unsigned)f2bf(h2v) | ((unsigned)f2bf(h3) << 16);
        *(uint2*)&xhT[(tl + 1) * XHP2 + cbase] = make_uint2(lo, hi);
    }
    __syncthreads();

    // --- temporal conv (K=192, kidx=tap*64+c) + residual (K=32) ---
    f32x4 a2[4];
#pragma unroll
    for (int i = 0; i < 4; ++i) a2[i] = (f32x4){0.f, 0.f, 0.f, 0.f};
#pragma unroll
    for (int ks = 0; ks < 6; ++ks) {
        int kb = ks * 32 + fg * 8;
        bf16x8 bfrag = *(const bf16x8*)&xhT[(tl + (kb >> 6)) * XHP2 + (kb & 63)];
#pragma unroll
        for (int i = 0; i < 4; ++i)
            a2[i] = __builtin_amdgcn_mfma_f32_16x16x32_bf16(
                *(const bf16x8*)&WAtc[((ks * 4 + i) * 64 + l) * 8], bfrag, a2[i], 0, 0, 0);
    }
    {
        bf16x8 bfrag = *(const bf16x8*)&XT[tl * XTP + fg * 8];
#pragma unroll
        for (int i = 0; i < 4; ++i)
            a2[i] = __builtin_amdgcn_mfma_f32_16x16x32_bf16(
                *(const bf16x8*)&WAres[(i * 64 + l) * 8], bfrag, a2[i], 0, 0, 0);
    }
    // + (bt+br), relu, LayerNorm over 64 channels, scale, write
    float h2[16];
#pragma unroll
    for (int i = 0; i < 4; ++i) {
        float4 bv = *(const float4*)&btr[i * 16 + fg * 4];
        h2[i * 4 + 0] = fmaxf(a2[i][0] + bv.x, 0.f);
        h2[i * 4 + 1] = fmaxf(a2[i][1] + bv.y, 0.f);
        h2[i * 4 + 2] = fmaxf(a2[i][2] + bv.z, 0.f);
        h2[i * 4 + 3] = fmaxf(a2[i][3] + bv.w, 0.f);
    }
    float s1 = 0.f, s2 = 0.f;
#pragma unroll
    for (int q = 0; q < 16; ++q) { s1 += h2[q]; s2 += h2[q] * h2[q]; }
    s1 += __shfl_xor(s1, 16); s2 += __shfl_xor(s2, 16);
    s1 += __shfl_xor(s1, 32); s2 += __shfl_xor(s2, 32);
    float mu = s1 * (1.f / 64.f);
    float rs = rsqrtf(s2 * (1.f / 64.f) - mu * mu + 1e-5f);
    float* ob = out + (size_t)bn * 1024 + tl;
#pragma unroll
    for (int i = 0; i < 4; ++i) {
        int cbase = i * 16 + fg * 4;
        float4 gv = *(const float4*)&gamma[cbase];
        float4 bv = *(const float4*)&beta[cbase];
        ob[(cbase + 0) * 16] = (h2[i * 4 + 0] - mu) * rs * gv.x + bv.x;
        ob[(cbase + 1) * 16] = (h2[i * 4 + 1] - mu) * rs * gv.y + bv.y;
        ob[(cbase + 2) * 16] = (h2[i * 4 + 2] - mu) * rs * gv.z + bv.z;
        ob[(cbase + 3) * 16] = (h2[i * 4 + 3] - mu) * rs * gv.w + bv.w;
    }
}

// ---------------- host ----------------

extern "C" void kernel_launch(void* const* d_in, const int* in_sizes, int n_in,
                              void* d_out, int out_size, void* d_ws, size_t ws_size,
                              hipStream_t stream) {
    (void)in_sizes; (void)n_in; (void)out_size; (void)ws_size;
    const float* X = (const float*)d_in[0];
    const int* ei = (const int*)d_in[1];
    const int* row = ei;
    const int* col = ei + EE;
    const float* U1 = (const float*)d_in[2];
    const float* U2 = (const float*)d_in[3];
    const float* U3 = (const float*)d_in[4];
    const float* be = (const float*)d_in[5];
    const float* Ve = (const float*)d_in[6];
    const float* W1 = (const float*)d_in[7];
    const float* W2 = (const float*)d_in[8];
    const float* W3 = (const float*)d_in[9];
    const float* bs = (const float*)d_in[10];
    const float* Vs = (const float*)d_in[11];
    const float* cW = (const float*)d_in[12];
    const float* cb = (const float*)d_in[13];
    const float* Wt = (const float*)d_in[14];
    const float* bt = (const float*)d_in[15];
    const float* Wr = (const float*)d_in[16];
    const float* br = (const float*)d_in[17];
    const float* gamma = (const float*)d_in[18];
    const float* beta = (const float*)d_in[19];
    float* out = (float*)d_out;

    char* w = (char*)d_ws;
    constexpr size_t OFF_TMP1 = 0;            // 8192
    constexpr size_t OFF_PT = 8192;           // 4096
    constexpr size_t OFF_DEG = 12288;         // 8192
    constexpr size_t OFF_CNT = 20480;         // 8192
    constexpr size_t OFF_CURSOR = 28672;      // 8192
    constexpr size_t ZEND = 36864;
    constexpr size_t OFF_EMAT = ZEND;                     // 4096
    constexpr size_t OFF_LHS = OFF_EMAT + 4096;           // 512K
    constexpr size_t OFF_RHS = OFF_LHS + 524288;          // 512K
    constexpr size_t OFF_LHSS = OFF_RHS + 524288;         // 512K
    constexpr size_t OFF_RHSS = OFF_LHSS + 524288;        // 512K
    constexpr size_t OFF_DIAG = OFF_RHSS + 524288;        // 32K
    constexpr size_t OFF_ATT = OFF_DIAG + 32768;          // 512K
    constexpr size_t OFF_DINV = OFF_ATT + 524288;         // 8K
    constexpr size_t OFF_NORM = OFF_DINV + 8192;          // 128K
    constexpr size_t OFF_STARTS = OFF_NORM + 131072;      // 8448
    constexpr size_t OFF_EID = OFF_STARTS + 8448;         // 128K
    constexpr size_t OFF_WA = OFF_EID + 131072;           // 56K region for frags
    constexpr size_t OFF_WACHEB = OFF_WA;                 // 12288
    constexpr size_t OFF_WATC = OFF_WA + 12288;           // 24576
    constexpr size_t OFF_WARES = OFF_WA + 36864;          // 4096
    constexpr size_t OFF_BTR = OFF_WA + 40960;            // 256
    constexpr size_t OFF_VSBF = OFF_WA + 57344;           // 8MB (reused: pm/ps/Mf/Inv)
    constexpr size_t OFF_TX0 = OFF_VSBF + 8388608;        // 16MB
    constexpr size_t OFF_SIGT = OFF_TX0 + 16777216;       // 32MB
    constexpr size_t OFF_S = OFF_SIGT + 33554432;         // 64MB+ (reused: Tx1, Tx2)

    float* tmp1 = (float*)(w + OFF_TMP1);
    float* Pt = (float*)(w + OFF_PT);
    float* deg = (float*)(w + OFF_DEG);
    int* cnt = (int*)(w + OFF_CNT);
    int* cursor = (int*)(w + OFF_CURSOR);
    float* Emat = (float*)(w + OFF_EMAT);
    float* lhs = (float*)(w + OFF_LHS);
    float* rhs = (float*)(w + OFF_RHS);
    float* lhs_s = (float*)(w + OFF_LHSS);
    float* rhs_s = (float*)(w + OFF_RHSS);
    float* diagS = (float*)(w + OFF_DIAG);
    float* att = (float*)(w + OFF_ATT);
    float* dinv = (float*)(w + OFF_DINV);
    float* normv = (float*)(w + OFF_NORM);
    int* starts = (int*)(w + OFF_STARTS);
    int* eid = (int*)(w + OFF_EID);
    unsigned short* WAcheb = (unsigned short*)(w + OFF_WACHEB);
    unsigned short* WAtc = (unsigned short*)(w + OFF_WATC);
    unsigned short* WAres = (unsigned short*)(w + OFF_WARES);
    float* btr = (float*)(w + OFF_BTR);
    unsigned short* Vsbf = (unsigned short*)(w + OFF_VSBF);
    float* pm = (float*)(w + OFF_VSBF);                   // reuse after gemm
    float* ps = (float*)(w + OFF_VSBF + 524288);
    float* Mf = (float*)(w + OFF_VSBF + 1048576);
    float* Inv = (float*)(w + OFF_VSBF + 1048576 + 32768);
    float* Tx0 = (float*)(w + OFF_TX0);
    unsigned short* sigT = (unsigned short*)(w + OFF_SIGT);
    float* S = (float*)(w + OFF_S);
    float* Tx1 = S;                            // reuse after diag/att extracted
    float* Tx2 = (float*)(w + OFF_S + 16777216);

    hipMemsetAsync(w, 0, ZEND, stream);

    // temporal attention
    k_u1reduce<<<BB * 64, 256, 0, stream>>>(X, U1, tmp1);
    k_mkrhs<<<BB * NN * TT / 256, 256, 0, stream>>>(X, U3, rhs);
    k_mklhs<<<BB * TT * 8, 256, 0, stream>>>(tmp1, U2, lhs);
    k_ptaccum<<<BB * 8, 256, 0, stream>>>(lhs, rhs, Pt);
    k_temporalatt<<<BB, 256, 0, stream>>>(Pt, be, Ve, Emat);

    // spatial attention (Xt computed in-LDS inside k_spatiallr)
    k_spatiallr<<<BB * (NN / 16), 256, 0, stream>>>(X, Emat, W1, W2, W3, lhs_s, rhs_s);
    k_f2bf<<<NN * NN / 256, 256, 0, stream>>>(Vs, Vsbf);
    k_wtprep<<<81, 256, 0, stream>>>(cW, Wt, Wr, bt, br, WAcheb, WAtc, WAres, btr);
    k_makesigT<<<dim3(NN / 64, NN / 64, BB), 256, 0, stream>>>(lhs_s, rhs_s, bs, sigT);
    k_gemm_bt<<<dim3(NN / 128, NN / 128, BB), 256, 0, stream>>>(Vsbf, sigT, S, NN, NN, NN);

    // softmax statistics only (full normalized S never materialized)
    k_colreduce1<<<dim3(8, NSPLIT, BB), 256, 0, stream>>>(S, pm, ps);
    k_colreduce2<<<BB * NN / 256, 256, 0, stream>>>(pm, ps, Mf, Inv);

    // graph prep
    k_deg<<<EE / 256, 256, 0, stream>>>(row, col, deg);
    k_dinv<<<NN / 256, 256, 0, stream>>>(deg, dinv);
    k_norm<<<EE / 256, 256, 0, stream>>>(row, col, dinv, normv, cnt);
    k_scan<<<1, 256, 0, stream>>>(cnt, starts);
    k_scatter<<<EE / 256, 256, 0, stream>>>(row, starts, cursor, eid);
    k_diagatt<<<BB * EE / 256, 256, 0, stream>>>(S, row, col, normv, Mf, Inv, diagS, att);

    // chebyshev
    k_tx0<<<BB * NN * 512 / 256, 256, 0, stream>>>(X, diagS, Tx0);
    k_prop<<<BB * NN / 2, 256, 0, stream>>>(Tx0, att, col, starts, eid, nullptr, Tx1, 0);
    k_prop<<<BB * NN / 2, 256, 0, stream>>>(Tx1, att, col, starts, eid, Tx0, Tx2, 1);

    // fused cheb + temporal conv + residual + LN (MFMA, 1 wave / node)
    k_chebfinal<<<BB * NN, 64, 0, stream>>>(Tx0, Tx1, Tx2, X,
                                            WAcheb, WAtc, WAres,
                                            cb, btr, gamma, beta, out);
}

// Round 8
// 303.418 us; speedup vs baseline: 2.9582x; 1.0512x over previous
//
#include <hip/hip_runtime.h>
#include <hip/hip_bf16.h>

#define BB 4
#define NN 2048
#define FIN 32
#define TT 16
#define EE 32768
#define CC 64
#define TFo 64
#define NSPLIT 16

typedef __attribute__((ext_vector_type(8))) short bf16x8;
typedef __attribute__((ext_vector_type(4))) float f32x4;

typedef __attribute__((address_space(1))) const unsigned int as1_uint;
typedef __attribute__((address_space(3))) unsigned int as3_uint;

__device__ __forceinline__ void gload_lds16(const void* g, void* l) {
    __builtin_amdgcn_global_load_lds((as1_uint*)g, (as3_uint*)l, 16, 0, 0);
}

__device__ __forceinline__ unsigned short f2bf(float v) {
    unsigned u = __builtin_bit_cast(unsigned, v);
    unsigned r = (u + 0x7fffu + ((u >> 16) & 1u)) >> 16;
    return (unsigned short)r;
}

__device__ __forceinline__ float bf2f(unsigned short v) {
    return __builtin_bit_cast(float, (unsigned)v << 16);
}

// ---------------- Stage A: temporal attention ----------------

__global__ void k_u1reduce(const float* __restrict__ X, const float* __restrict__ U1,
                           float* __restrict__ tmp1) {
    int b = blockIdx.x >> 6;
    int n0 = (blockIdx.x & 63) * 32;
    float a0 = 0.f, a1 = 0.f;
    for (int i = 0; i < 32; ++i) {
        int n = n0 + i;
        float u = U1[n];
        const float* row = X + ((size_t)(b * NN + n)) * 512;
        a0 += u * row[threadIdx.x];
        a1 += u * row[threadIdx.x + 256];
    }
    atomicAdd(&tmp1[b * 512 + threadIdx.x], a0);
    atomicAdd(&tmp1[b * 512 + threadIdx.x + 256], a1);
}

__global__ void k_mklhs(const float* __restrict__ tmp1, const float* __restrict__ U2,
                        float* __restrict__ lhs) {
    int npr = ((blockIdx.x & 7) << 8) + threadIdx.x;
    int bt = blockIdx.x >> 3;           // b*16 + t
    int b = bt >> 4, t = bt & 15;
    float acc = 0.f;
#pragma unroll
    for (int f = 0; f < 32; ++f) acc += tmp1[b * 512 + f * 16 + t] * U2[f * NN + npr];
    lhs[(size_t)bt * NN + npr] = acc;
}

__global__ void k_mkrhs(const float* __restrict__ X, const float* __restrict__ U3,
                        float* __restrict__ rhs) {
    int idx = blockIdx.x * 256 + threadIdx.x;   // B*N*T
    int t = idx & 15;
    int bn = idx >> 4;
    float acc = 0.f;
#pragma unroll
    for (int f = 0; f < 32; ++f) acc += U3[f] * X[(size_t)bn * 512 + f * 16 + t];
    rhs[idx] = acc;
}

__global__ void k_ptaccum(const float* __restrict__ lhs, const float* __restrict__ rhs,
                          float* __restrict__ Pt) {
    int b = blockIdx.x >> 3;
    int n0 = (blockIdx.x & 7) * 256;
    int t = threadIdx.x >> 4, s = threadIdx.x & 15;
    const float* lr = lhs + (size_t)b * TT * NN + (size_t)t * NN;
    const float* rr = rhs + (size_t)b * NN * TT;
    float acc = 0.f;
    for (int i = 0; i < 256; ++i) {
        int n = n0 + i;
        acc += lr[n] * rr[n * 16 + s];
    }
    atomicAdd(&Pt[b * 256 + threadIdx.x], acc);
}

__global__ void k_temporalatt(const float* __restrict__ Pt, const float* __restrict__ be,
                              const float* __restrict__ Ve, float* __restrict__ Emat) {
    int b = blockIdx.x;
    int t = threadIdx.x >> 4, s = threadIdx.x & 15;
    __shared__ float sg[16][17];
    __shared__ float em[16][17];
    float v = Pt[b * 256 + t * 16 + s] + be[t * 16 + s];
    sg[t][s] = 1.f / (1.f + __expf(-v));
    __syncthreads();
    float e = 0.f;
#pragma unroll
    for (int u = 0; u < 16; ++u) e += Ve[t * 16 + u] * sg[u][s];
    em[t][s] = e;
    __syncthreads();
    float mx = -1e30f;
#pragma unroll
    for (int u = 0; u < 16; ++u) mx = fmaxf(mx, em[u][s]);
    float sum = 0.f;
#pragma unroll
    for (int u = 0; u < 16; ++u) sum += __expf(em[u][s] - mx);
    Emat[b * 256 + t * 16 + s] = __expf(e - mx) / sum;
}

// ---------------- Stage B: spatial attention (applyemat fused in) ----------------

__global__ void k_spatiallr(const float* __restrict__ X, const float* __restrict__ Emat,
                            const float* __restrict__ W1, const float* __restrict__ W2,
                            const float* __restrict__ W3,
                            float* __restrict__ lhs_s, float* __restrict__ rhs_s) {
    int b = blockIdx.x >> 7;
    int n0 = (blockIdx.x & 127) * 16;
    __shared__ float em[256];
    __shared__ float xb[16 * 32 * 17];   // Xt, [(nl*32+f)*17 + s]
    __shared__ float av[16 * 32];
    em[threadIdx.x] = Emat[b * 256 + threadIdx.x];
    __syncthreads();
#pragma unroll
    for (int ii = 0; ii < 2; ++ii) {
        int p = threadIdx.x * 2 + ii;    // nl*32 + f
        int nl = p >> 5, f = p & 31;
        const float4* src = (const float4*)(X + ((size_t)(b * NN + n0 + nl)) * 512 + f * 16);
        float4 q0 = src[0], q1 = src[1], q2 = src[2], q3 = src[3];
        float xv[16] = {q0.x, q0.y, q0.z, q0.w, q1.x, q1.y, q1.z, q1.w,
                        q2.x, q2.y, q2.z, q2.w, q3.x, q3.y, q3.z, q3.w};
        float o[16];
#pragma unroll
        for (int s = 0; s < 16; ++s) o[s] = 0.f;
#pragma unroll
        for (int t = 0; t < 16; ++t) {
            float xt = xv[t];
            const float* er = &em[t * 16];
#pragma unroll
            for (int s = 0; s < 16; ++s) o[s] += xt * er[s];
        }
        float a = 0.f;
#pragma unroll
        for (int s = 0; s < 16; ++s) { xb[p * 17 + s] = o[s]; a += o[s] * W1[s]; }
        av[p] = a;
    }
    __syncthreads();
    int nl = threadIdx.x >> 4, t = threadIdx.x & 15;
    float r = 0.f;
#pragma unroll
    for (int f = 0; f < 32; ++f) r += W3[f] * xb[(nl * 32 + f) * 17 + t];
    rhs_s[(size_t)b * TT * NN + (size_t)t * NN + n0 + nl] = r;
    float l = 0.f;
#pragma unroll
    for (int f = 0; f < 32; ++f) l += av[nl * 32 + f] * W2[f * 16 + t];
    lhs_s[((size_t)(b * NN + n0 + nl)) * 16 + t] = l;
}

// Vs fp32 -> bf16
__global__ void k_f2bf(const float* __restrict__ src, unsigned short* __restrict__ dst) {
    int i = blockIdx.x * 256 + threadIdx.x;
    dst[i] = f2bf(src[i]);
}

// ---------------- weight prep: exact per-lane MFMA A-fragments (bf16) ----------------
__global__ void k_wtprep(const float* __restrict__ cW, const float* __restrict__ Wt,
                         const float* __restrict__ Wr, const float* __restrict__ bt,
                         const float* __restrict__ br,
                         unsigned short* __restrict__ WAcheb,
                         unsigned short* __restrict__ WAtc,
                         unsigned short* __restrict__ WAres,
                         float* __restrict__ btr) {
    int idx = blockIdx.x * 256 + threadIdx.x;
    if (idx < 6144) {                      // cheb
        int j = idx & 7, l = (idx >> 3) & 63, fi = idx >> 9;   // fi = ks*4+i
        int row = ((fi & 3) << 4) + (l & 15);
        int kidx = ((fi >> 2) << 5) + ((l >> 4) << 3) + j;
        int k = kidx >> 5, f = kidx & 31;
        WAcheb[idx] = f2bf(cW[k * 2048 + f * 64 + row]);
    } else if (idx < 18432) {              // temporal conv
        int e = idx - 6144;
        int j = e & 7, l = (e >> 3) & 63, fi = e >> 9;         // fi = ks*4+i, ks<6
        int row = ((fi & 3) << 4) + (l & 15);
        int kidx = ((fi >> 2) << 5) + ((l >> 4) << 3) + j;
        int tap = kidx >> 6, c = kidx & 63;
        WAtc[e] = f2bf(Wt[row * 192 + c * 3 + tap]);
    } else if (idx < 20480) {              // residual
        int e = idx - 18432;
        int j = e & 7, l = (e >> 3) & 63, i = e >> 9;
        int row = (i << 4) + (l & 15);
        int f = ((l >> 4) << 3) + j;
        WAres[e] = f2bf(Wr[row * 32 + f]);
    } else if (idx < 20544) {
        int o = idx - 20480;
        btr[o] = bt[o] + br[o];
    }
}

// sigT[b][k][m] = bf16(sigmoid(dot(lhs_s[b,m,:], rhs_s[b,:,k]) + bs[m,k]))
// bs tile staged ONCE, reused for all 4 batches
__global__ void k_makesigT(const float* __restrict__ lhs_s, const float* __restrict__ rhs_s,
                           const float* __restrict__ bs, unsigned short* __restrict__ sigT) {
    int k0 = blockIdx.x * 64, m0 = blockIdx.y * 64;
    __shared__ float lh[64][17];
    __shared__ float rh[16][64];
    __shared__ float bsl[64][65];
    int tid = threadIdx.x;
#pragma unroll
    for (int i = 0; i < 16; ++i) {
        int idx = tid + i * 256;
        int mi = idx >> 6, kj = idx & 63;
        bsl[mi][kj] = bs[(size_t)(m0 + mi) * NN + k0 + kj];
    }
    int ml = tid & 63;
    int kg = (tid >> 6) * 16;
    for (int b = 0; b < BB; ++b) {
        __syncthreads();
#pragma unroll
        for (int i = 0; i < 4; ++i) {
            int idx = tid + i * 256;
            int mi = idx >> 4, t = idx & 15;
            lh[mi][t] = lhs_s[((size_t)(b * NN + m0 + mi)) * 16 + t];
            int tt = idx >> 6, kj = idx & 63;
            rh[tt][kj] = rhs_s[(size_t)b * TT * NN + (size_t)tt * NN + k0 + kj];
        }
        __syncthreads();
        unsigned short* out = sigT + (size_t)b * NN * NN;
#pragma unroll 4
        for (int ki = 0; ki < 16; ++ki) {
            int kl = kg + ki;
            float acc = bsl[ml][kl];
#pragma unroll
            for (int t = 0; t < 16; ++t) acc += lh[ml][t] * rh[t][kl];
            float sgv = 1.f / (1.f + __expf(-acc));
            out[(size_t)(k0 + kl) * NN + m0 + ml] = f2bf(sgv);
        }
    }
}

// ---------------- The big GEMM: S[b][n][k] = sum_m Vs[n][m]*sigT[b][k][m] ----------------

__global__ __launch_bounds__(256) void k_gemm_bt(const unsigned short* __restrict__ A,
                                                 const unsigned short* __restrict__ Bt,
                                                 float* __restrict__ C,
                                                 int M, int N, int K) {
    __shared__ __align__(16) unsigned short lds[2][2][128 * 32];
    const int tid = threadIdx.x;
    const int wave = tid >> 6, lane = tid & 63;
    const int bm = blockIdx.y << 7;
    const int bn = blockIdx.x << 7;
    const unsigned short* Bb = Bt + (size_t)blockIdx.z * N * K;
    float* Cb = C + (size_t)blockIdx.z * M * N;
    const int wr = wave >> 1, wc = wave & 1;
    const int srow = lane >> 2, scol = (lane & 3) << 3;

    f32x4 acc[4][4];
#pragma unroll
    for (int i = 0; i < 4; ++i)
#pragma unroll
        for (int j = 0; j < 4; ++j) acc[i][j] = (f32x4){0.f, 0.f, 0.f, 0.f};

    const size_t abase = (size_t)(bm + srow) * K + scol;
    const size_t bbase = (size_t)(bn + srow) * K + scol;

#define STAGE(buf, k0)                                                              \
    {                                                                               \
        _Pragma("unroll")                                                           \
        for (int ii = 0; ii < 2; ++ii) {                                            \
            int rb = ((ii << 2) + wave) << 4;                                       \
            gload_lds16(A + abase + (size_t)rb * K + (k0), &lds[buf][0][rb * 32]);  \
            gload_lds16(Bb + bbase + (size_t)rb * K + (k0), &lds[buf][1][rb * 32]); \
        }                                                                           \
    }

    STAGE(0, 0)
    __syncthreads();
    const int nk = K >> 5;
    const int rl = lane & 15, kg = (lane >> 4) << 3;
    for (int t = 0; t < nk; ++t) {
        int cur = t & 1;
        if (t + 1 < nk) STAGE(cur ^ 1, (t + 1) << 5)
        const unsigned short* la = &lds[cur][0][0];
        const unsigned short* lb = &lds[cur][1][0];
        bf16x8 af[4], bfr[4];
#pragma unroll
        for (int i = 0; i < 4; ++i) af[i] = *(const bf16x8*)(la + ((wr << 6) + (i << 4) + rl) * 32 + kg);
#pragma unroll
        for (int j = 0; j < 4; ++j) bfr[j] = *(const bf16x8*)(lb + ((wc << 6) + (j << 4) + rl) * 32 + kg);
#pragma unroll
        for (int i = 0; i < 4; ++i)
#pragma unroll
            for (int j = 0; j < 4; ++j)
                acc[i][j] = __builtin_amdgcn_mfma_f32_16x16x32_bf16(af[i], bfr[j], acc[i][j], 0, 0, 0);
        __syncthreads();
    }
#undef STAGE
    const int cl = lane & 15, rg = (lane >> 4) << 2;
#pragma unroll
    for (int i = 0; i < 4; ++i)
#pragma unroll
        for (int j = 0; j < 4; ++j) {
            int m0 = bm + (wr << 6) + (i << 4) + rg;
            int n0 = bn + (wc << 6) + (j << 4) + cl;
#pragma unroll
            for (int r = 0; r < 4; ++r) Cb[(size_t)(m0 + r) * N + n0] = acc[i][j][r];
        }
}

// ---------------- column softmax statistics (only stats are needed!) ----------------
__global__ void k_colreduce1(const float* __restrict__ S, float* __restrict__ pm,
                             float* __restrict__ ps) {
    int b = blockIdx.z;
    int k0 = blockIdx.x << 8;
    int nbase = blockIdx.y << 7;
    int ktl = threadIdx.x & 63;
    int g = threadIdx.x >> 6;
    const float* base = S + (size_t)b * NN * NN + k0 + (ktl << 2);
    float m0 = -1e30f, m1 = -1e30f, m2 = -1e30f, m3 = -1e30f;
    float s0 = 0.f, s1 = 0.f, s2 = 0.f, s3 = 0.f;
    for (int i = g; i < 128; i += 4) {
        float4 v = *(const float4*)(base + (size_t)(nbase + i) * NN);
        float nm;
        nm = fmaxf(m0, v.x); s0 = s0 * __expf(m0 - nm) + __expf(v.x - nm); m0 = nm;
        nm = fmaxf(m1, v.y); s1 = s1 * __expf(m1 - nm) + __expf(v.y - nm); m1 = nm;
        nm = fmaxf(m2, v.z); s2 = s2 * __expf(m2 - nm) + __expf(v.z - nm); m2 = nm;
        nm = fmaxf(m3, v.w); s3 = s3 * __expf(m3 - nm) + __expf(v.w - nm); m3 = nm;
    }
    __shared__ float sm[4][64][4], ss[4][64][4];
    sm[g][ktl][0] = m0; sm[g][ktl][1] = m1; sm[g][ktl][2] = m2; sm[g][ktl][3] = m3;
    ss[g][ktl][0] = s0; ss[g][ktl][1] = s1; ss[g][ktl][2] = s2; ss[g][ktl][3] = s3;
    __syncthreads();
    int kc = threadIdx.x;
    float M = sm[0][kc >> 2][kc & 3], Ssum = ss[0][kc >> 2][kc & 3];
#pragma unroll
    for (int gi = 1; gi < 4; ++gi) {
        float mm = sm[gi][kc >> 2][kc & 3], sv = ss[gi][kc >> 2][kc & 3];
        float nm = fmaxf(M, mm);
        Ssum = Ssum * __expf(M - nm) + sv * __expf(mm - nm);
        M = nm;
    }
    size_t o = ((size_t)(b * NSPLIT + blockIdx.y) * NN) + k0 + kc;
    pm[o] = M; ps[o] = Ssum;
}

__global__ void k_colreduce2(const float* __restrict__ pm, const float* __restrict__ ps,
                             float* __restrict__ Mf, float* __restrict__ Inv) {
    int idx = blockIdx.x * 256 + threadIdx.x;
    float M = -1e30f, Ssum = 0.f;
#pragma unroll
    for (int i = 0; i < NSPLIT; ++i) {
        size_t o = ((size_t)((idx >> 11) * NSPLIT + i) * NN) + (idx & (NN - 1));
        float mm = pm[o], sv = ps[o];
        float nm = fmaxf(M, mm);
        Ssum = Ssum * __expf(M - nm) + sv * __expf(mm - nm);
        M = nm;
    }
    Mf[idx] = M;
    Inv[idx] = 1.f / Ssum;
}

__global__ void k_diagatt(const float* __restrict__ S, const int* __restrict__ row,
                          const int* __restrict__ col, const float* __restrict__ norm,
                          const float* __restrict__ Mf, const float* __restrict__ Inv,
                          float* __restrict__ diagS, float* __restrict__ att) {
    int idx = blockIdx.x * 256 + threadIdx.x;
    if (idx < BB * EE) {
        int b = idx >> 15, e = idx & (EE - 1);
        int c = col[e];
        float v = S[(size_t)b * NN * NN + (size_t)row[e] * NN + c];
        att[idx] = norm[e] * __expf(v - Mf[b * NN + c]) * Inv[b * NN + c];
    }
    if (idx < BB * NN) {
        float v = S[(size_t)(idx >> 11) * NN * NN + (size_t)(idx & (NN - 1)) * NN + (idx & (NN - 1))];
        diagS[idx] = __expf(v - Mf[idx]) * Inv[idx];
    }
}

// ---------------- graph prep ----------------

__global__ void k_deg(const int* __restrict__ row, const int* __restrict__ col,
                      float* __restrict__ deg) {
    int e = blockIdx.x * 256 + threadIdx.x;
    if (e < EE && row[e] != col[e]) atomicAdd(&deg[row[e]], 1.0f);
}

__global__ void k_dinv(const float* __restrict__ deg, float* __restrict__ dinv) {
    int n = blockIdx.x * 256 + threadIdx.x;
    if (n < NN) {
        float d = deg[n];
        dinv[n] = d > 0.f ? rsqrtf(fmaxf(d, 1e-12f)) : 0.f;
    }
}

__global__ void k_norm(const int* __restrict__ row, const int* __restrict__ col,
                       const float* __restrict__ dinv, float* __restrict__ norm,
                       int* __restrict__ cnt) {
    int e = blockIdx.x * 256 + threadIdx.x;
    if (e < EE) {
        int r = row[e], c = col[e];
        float w = (r != c) ? 1.f : 0.f;
        norm[e] = -dinv[r] * w * dinv[c];
        atomicAdd(&cnt[r], 1);
    }
}

__global__ void k_scan(const int* __restrict__ cnt, int* __restrict__ starts) {
    __shared__ int part[256];
    int t = threadIdx.x;
    int loc[8];
    int s = 0;
#pragma unroll
    for (int i = 0; i < 8; ++i) {
        int c = cnt[t * 8 + i];
        loc[i] = s;
        s += c;
    }
    part[t] = s;
    __syncthreads();
    for (int o = 1; o < 256; o <<= 1) {
        int v = (t >= o) ? part[t - o] : 0;
        __syncthreads();
        part[t] += v;
        __syncthreads();
    }
    int pbase = (t > 0) ? part[t - 1] : 0;
#pragma unroll
    for (int i = 0; i < 8; ++i) starts[t * 8 + i] = pbase + loc[i];
    if (t == 255) starts[NN] = part[255];
}

__global__ void k_scatter(const int* __restrict__ row, const int* __restrict__ starts,
                          int* __restrict__ cursor, int* __restrict__ eid) {
    int e = blockIdx.x * 256 + threadIdx.x;
    if (e < EE) {
        int r = row[e];
        int slot = atomicAdd(&cursor[r], 1);
        eid[starts[r] + slot] = e;
    }
}

// ---------------- Chebyshev (bf16 Tx pipeline) ----------------

// Tx0 = X * diagS, stored bf16. 2 elements/thread.
__global__ void k_tx0(const float* __restrict__ X, const float* __restrict__ diagS,
                      unsigned short* __restrict__ Tx0) {
    size_t idx = ((size_t)blockIdx.x * 256 + threadIdx.x) * 2;
    float2 v = *(const float2*)(X + idx);
    float d = diagS[idx >> 9];
    unsigned pack = (unsigned)f2bf(v.x * d) | ((unsigned)f2bf(v.y * d) << 16);
    *(unsigned*)(Tx0 + idx) = pack;
}

// bf16 gather: out = (mode ? 2*gather - sub : gather); gathers 1KB bf16 rows
__global__ void k_prop(const unsigned short* __restrict__ x, const float* __restrict__ att,
                       const int* __restrict__ col, const int* __restrict__ starts,
                       const int* __restrict__ eid, const unsigned short* __restrict__ sub,
                       unsigned short* __restrict__ out, int mode) {
    int g = threadIdx.x >> 7;
    int l = threadIdx.x & 127;
    int bn = (blockIdx.x << 1) + g;
    int b = bn >> 11, n = bn & (NN - 1);
    int s0 = starts[n], s1 = starts[n + 1];
    const unsigned short* xb = x + (size_t)b * NN * 512;
    const float* attb = att + (size_t)b * EE;
    float ax = 0.f, ay = 0.f, az = 0.f, aw = 0.f;
    float bx = 0.f, by = 0.f, bz = 0.f, bw = 0.f;
    int jj = s0;
    for (; jj + 2 <= s1; jj += 2) {
        int e0 = eid[jj], e1 = eid[jj + 1];
        float a0 = attb[e0], a1 = attb[e1];
        ushort4 v0 = *((const ushort4*)(xb + (size_t)col[e0] * 512) + l);
        ushort4 v1 = *((const ushort4*)(xb + (size_t)col[e1] * 512) + l);
        ax += a0 * bf2f(v0.x); ay += a0 * bf2f(v0.y); az += a0 * bf2f(v0.z); aw += a0 * bf2f(v0.w);
        bx += a1 * bf2f(v1.x); by += a1 * bf2f(v1.y); bz += a1 * bf2f(v1.z); bw += a1 * bf2f(v1.w);
    }
    if (jj < s1) {
        int e0 = eid[jj];
        float a0 = attb[e0];
        ushort4 v0 = *((const ushort4*)(xb + (size_t)col[e0] * 512) + l);
        ax += a0 * bf2f(v0.x); ay += a0 * bf2f(v0.y); az += a0 * bf2f(v0.z); aw += a0 * bf2f(v0.w);
    }
    float rx = ax + bx, ry = ay + by, rz = az + bz, rw = aw + bw;
    size_t o = (size_t)bn * 512 + (l << 2);
    if (mode) {
        ushort4 sv = *(const ushort4*)(sub + o);
        rx = 2.f * rx - bf2f(sv.x); ry = 2.f * ry - bf2f(sv.y);
        rz = 2.f * rz - bf2f(sv.z); rw = 2.f * rw - bf2f(sv.w);
    }
    ushort4 ov;
    ov.x = f2bf(rx); ov.y = f2bf(ry); ov.z = f2bf(rz); ov.w = f2bf(rw);
    *(ushort4*)(out + o) = ov;
}

// ---------------- fused cheb + temporal conv + residual + LN via MFMA ----------------
#define XSP 104   // xsT row stride (shorts)
#define XHP2 72   // xhT row stride (shorts)
#define XTP 40    // XT row stride (shorts)
__global__ __launch_bounds__(64) void k_chebfinal(
    const unsigned short* __restrict__ Tx0, const unsigned short* __restrict__ Tx1,
    const unsigned short* __restrict__ Tx2, const float* __restrict__ X,
    const unsigned short* __restrict__ WAcheb,
    const unsigned short* __restrict__ WAtc,
    const unsigned short* __restrict__ WAres,
    const float* __restrict__ cb, const float* __restrict__ btr,
    const float* __restrict__ gamma, const float* __restrict__ beta,
    float* __restrict__ out) {
    int l = threadIdx.x;
    int bn = blockIdx.x;
    int tl = l & 15, fg = l >> 4;
    __shared__ unsigned short xsT[16 * XSP];
    __shared__ unsigned short xhT[18 * XHP2];
    __shared__ unsigned short XT[16 * XTP];
    xhT[l] = 0;
    xhT[17 * XHP2 + l] = 0;
    size_t nb = (size_t)bn * 512;
    {
        bf16x8 v;
#pragma unroll
        for (int j = 0; j < 8; ++j) v[j] = (short)Tx0[nb + (fg * 8 + j) * 16 + tl];
        *(bf16x8*)&xsT[tl * XSP + fg * 8] = v;
#pragma unroll
        for (int j = 0; j < 8; ++j) v[j] = (short)Tx1[nb + (fg * 8 + j) * 16 + tl];
        *(bf16x8*)&xsT[tl * XSP + 32 + fg * 8] = v;
#pragma unroll
        for (int j = 0; j < 8; ++j) v[j] = (short)Tx2[nb + (fg * 8 + j) * 16 + tl];
        *(bf16x8*)&xsT[tl * XSP + 64 + fg * 8] = v;
#pragma unroll
        for (int j = 0; j < 8; ++j) v[j] = (short)f2bf(X[nb + (fg * 8 + j) * 16 + tl]);
        *(bf16x8*)&XT[tl * XTP + fg * 8] = v;
    }
    __syncthreads();

    // --- cheb ---
    f32x4 acc[4];
#pragma unroll
    for (int i = 0; i < 4; ++i) acc[i] = (f32x4){0.f, 0.f, 0.f, 0.f};
#pragma unroll
    for (int ks = 0; ks < 3; ++ks) {
        bf16x8 bfrag = *(const bf16x8*)&xsT[tl * XSP + ks * 32 + fg * 8];
#pragma unroll
        for (int i = 0; i < 4; ++i)
            acc[i] = __builtin_amdgcn_mfma_f32_16x16x32_bf16(
                *(const bf16x8*)&WAcheb[((ks * 4 + i) * 64 + l) * 8], bfrag, acc[i], 0, 0, 0);
    }
#pragma unroll
    for (int i = 0; i < 4; ++i) {
        int cbase = i * 16 + fg * 4;
        float4 cv = *(const float4*)&cb[cbase];
        float h0 = fmaxf(acc[i][0] + cv.x, 0.f);
        float h1 = fmaxf(acc[i][1] + cv.y, 0.f);
        float h2v = fmaxf(acc[i][2] + cv.z, 0.f);
        float h3 = fmaxf(acc[i][3] + cv.w, 0.f);
        unsigned lo = (unsigned)f2bf(h0) | ((unsigned)f2bf(h1) << 16);
        unsigned hi = (unsigned)f2bf(h2v) | ((unsigned)f2bf(h3) << 16);
        *(uint2*)&xhT[(tl + 1) * XHP2 + cbase] = make_uint2(lo, hi);
    }
    __syncthreads();

    // --- temporal conv + residual ---
    f32x4 a2[4];
#pragma unroll
    for (int i = 0; i < 4; ++i) a2[i] = (f32x4){0.f, 0.f, 0.f, 0.f};
#pragma unroll
    for (int ks = 0; ks < 6; ++ks) {
        int kb = ks * 32 + fg * 8;
        bf16x8 bfrag = *(const bf16x8*)&xhT[(tl + (kb >> 6)) * XHP2 + (kb & 63)];
#pragma unroll
        for (int i = 0; i < 4; ++i)
            a2[i] = __builtin_amdgcn_mfma_f32_16x16x32_bf16(
                *(const bf16x8*)&WAtc[((ks * 4 + i) * 64 + l) * 8], bfrag, a2[i], 0, 0, 0);
    }
    {
        bf16x8 bfrag = *(const bf16x8*)&XT[tl * XTP + fg * 8];
#pragma unroll
        for (int i = 0; i < 4; ++i)
            a2[i] = __builtin_amdgcn_mfma_f32_16x16x32_bf16(
                *(const bf16x8*)&WAres[(i * 64 + l) * 8], bfrag, a2[i], 0, 0, 0);
    }
    float h2[16];
#pragma unroll
    for (int i = 0; i < 4; ++i) {
        float4 bv = *(const float4*)&btr[i * 16 + fg * 4];
        h2[i * 4 + 0] = fmaxf(a2[i][0] + bv.x, 0.f);
        h2[i * 4 + 1] = fmaxf(a2[i][1] + bv.y, 0.f);
        h2[i * 4 + 2] = fmaxf(a2[i][2] + bv.z, 0.f);
        h2[i * 4 + 3] = fmaxf(a2[i][3] + bv.w, 0.f);
    }
    float s1 = 0.f, s2 = 0.f;
#pragma unroll
    for (int q = 0; q < 16; ++q) { s1 += h2[q]; s2 += h2[q] * h2[q]; }
    s1 += __shfl_xor(s1, 16); s2 += __shfl_xor(s2, 16);
    s1 += __shfl_xor(s1, 32); s2 += __shfl_xor(s2, 32);
    float mu = s1 * (1.f / 64.f);
    float rs = rsqrtf(s2 * (1.f / 64.f) - mu * mu + 1e-5f);
    float* ob = out + (size_t)bn * 1024 + tl;
#pragma unroll
    for (int i = 0; i < 4; ++i) {
        int cbase = i * 16 + fg * 4;
        float4 gv = *(const float4*)&gamma[cbase];
        float4 bv = *(const float4*)&beta[cbase];
        ob[(cbase + 0) * 16] = (h2[i * 4 + 0] - mu) * rs * gv.x + bv.x;
        ob[(cbase + 1) * 16] = (h2[i * 4 + 1] - mu) * rs * gv.y + bv.y;
        ob[(cbase + 2) * 16] = (h2[i * 4 + 2] - mu) * rs * gv.z + bv.z;
        ob[(cbase + 3) * 16] = (h2[i * 4 + 3] - mu) * rs * gv.w + bv.w;
    }
}

// ---------------- host ----------------

extern "C" void kernel_launch(void* const* d_in, const int* in_sizes, int n_in,
                              void* d_out, int out_size, void* d_ws, size_t ws_size,
                              hipStream_t stream) {
    (void)in_sizes; (void)n_in; (void)out_size; (void)ws_size;
    const float* X = (const float*)d_in[0];
    const int* ei = (const int*)d_in[1];
    const int* row = ei;
    const int* col = ei + EE;
    const float* U1 = (const float*)d_in[2];
    const float* U2 = (const float*)d_in[3];
    const float* U3 = (const float*)d_in[4];
    const float* be = (const float*)d_in[5];
    const float* Ve = (const float*)d_in[6];
    const float* W1 = (const float*)d_in[7];
    const float* W2 = (const float*)d_in[8];
    const float* W3 = (const float*)d_in[9];
    const float* bs = (const float*)d_in[10];
    const float* Vs = (const float*)d_in[11];
    const float* cW = (const float*)d_in[12];
    const float* cb = (const float*)d_in[13];
    const float* Wt = (const float*)d_in[14];
    const float* bt = (const float*)d_in[15];
    const float* Wr = (const float*)d_in[16];
    const float* br = (const float*)d_in[17];
    const float* gamma = (const float*)d_in[18];
    const float* beta = (const float*)d_in[19];
    float* out = (float*)d_out;

    char* w = (char*)d_ws;
    constexpr size_t OFF_TMP1 = 0;            // 8192
    constexpr size_t OFF_PT = 8192;           // 4096
    constexpr size_t OFF_DEG = 12288;         // 8192
    constexpr size_t OFF_CNT = 20480;         // 8192
    constexpr size_t OFF_CURSOR = 28672;      // 8192
    constexpr size_t ZEND = 36864;
    constexpr size_t OFF_EMAT = ZEND;                     // 4096
    constexpr size_t OFF_LHS = OFF_EMAT + 4096;           // 512K
    constexpr size_t OFF_RHS = OFF_LHS + 524288;          // 512K
    constexpr size_t OFF_LHSS = OFF_RHS + 524288;         // 512K
    constexpr size_t OFF_RHSS = OFF_LHSS + 524288;        // 512K
    constexpr size_t OFF_DIAG = OFF_RHSS + 524288;        // 32K
    constexpr size_t OFF_ATT = OFF_DIAG + 32768;          // 512K
    constexpr size_t OFF_DINV = OFF_ATT + 524288;         // 8K
    constexpr size_t OFF_NORM = OFF_DINV + 8192;          // 128K
    constexpr size_t OFF_STARTS = OFF_NORM + 131072;      // 8448
    constexpr size_t OFF_EID = OFF_STARTS + 8448;         // 128K
    constexpr size_t OFF_WA = OFF_EID + 131072;           // 56K region for frags
    constexpr size_t OFF_WACHEB = OFF_WA;                 // 12288
    constexpr size_t OFF_WATC = OFF_WA + 12288;           // 24576
    constexpr size_t OFF_WARES = OFF_WA + 36864;          // 4096
    constexpr size_t OFF_BTR = OFF_WA + 40960;            // 256
    constexpr size_t OFF_VSBF = OFF_WA + 57344;           // 8MB (reused: pm/ps/Mf/Inv)
    constexpr size_t OFF_TX0 = OFF_VSBF + 8388608;        // 16MB region (Tx0 bf16 uses 8.4MB)
    constexpr size_t OFF_SIGT = OFF_TX0 + 16777216;       // 32MB
    constexpr size_t OFF_S = OFF_SIGT + 33554432;         // 64MB+ (reused: Tx1, Tx2 bf16)

    float* tmp1 = (float*)(w + OFF_TMP1);
    float* Pt = (float*)(w + OFF_PT);
    float* deg = (float*)(w + OFF_DEG);
    int* cnt = (int*)(w + OFF_CNT);
    int* cursor = (int*)(w + OFF_CURSOR);
    float* Emat = (float*)(w + OFF_EMAT);
    float* lhs = (float*)(w + OFF_LHS);
    float* rhs = (float*)(w + OFF_RHS);
    float* lhs_s = (float*)(w + OFF_LHSS);
    float* rhs_s = (float*)(w + OFF_RHSS);
    float* diagS = (float*)(w + OFF_DIAG);
    float* att = (float*)(w + OFF_ATT);
    float* dinv = (float*)(w + OFF_DINV);
    float* normv = (float*)(w + OFF_NORM);
    int* starts = (int*)(w + OFF_STARTS);
    int* eid = (int*)(w + OFF_EID);
    unsigned short* WAcheb = (unsigned short*)(w + OFF_WACHEB);
    unsigned short* WAtc = (unsigned short*)(w + OFF_WATC);
    unsigned short* WAres = (unsigned short*)(w + OFF_WARES);
    float* btr = (float*)(w + OFF_BTR);
    unsigned short* Vsbf = (unsigned short*)(w + OFF_VSBF);
    float* pm = (float*)(w + OFF_VSBF);                   // reuse after gemm
    float* ps = (float*)(w + OFF_VSBF + 524288);
    float* Mf = (float*)(w + OFF_VSBF + 1048576);
    float* Inv = (float*)(w + OFF_VSBF + 1048576 + 32768);
    unsigned short* Tx0 = (unsigned short*)(w + OFF_TX0);
    unsigned short* sigT = (unsigned short*)(w + OFF_SIGT);
    float* S = (float*)(w + OFF_S);
    unsigned short* Tx1 = (unsigned short*)(w + OFF_S);   // reuse after diag/att extracted
    unsigned short* Tx2 = (unsigned short*)(w + OFF_S + 16777216);

    hipMemsetAsync(w, 0, ZEND, stream);

    // temporal attention
    k_u1reduce<<<BB * 64, 256, 0, stream>>>(X, U1, tmp1);
    k_mkrhs<<<BB * NN * TT / 256, 256, 0, stream>>>(X, U3, rhs);
    k_mklhs<<<BB * TT * 8, 256, 0, stream>>>(tmp1, U2, lhs);
    k_ptaccum<<<BB * 8, 256, 0, stream>>>(lhs, rhs, Pt);
    k_temporalatt<<<BB, 256, 0, stream>>>(Pt, be, Ve, Emat);

    // spatial attention (Xt computed in-LDS inside k_spatiallr)
    k_spatiallr<<<BB * (NN / 16), 256, 0, stream>>>(X, Emat, W1, W2, W3, lhs_s, rhs_s);
    k_f2bf<<<NN * NN / 256, 256, 0, stream>>>(Vs, Vsbf);
    k_wtprep<<<81, 256, 0, stream>>>(cW, Wt, Wr, bt, br, WAcheb, WAtc, WAres, btr);
    k_makesigT<<<dim3(NN / 64, NN / 64), 256, 0, stream>>>(lhs_s, rhs_s, bs, sigT);
    k_gemm_bt<<<dim3(NN / 128, NN / 128, BB), 256, 0, stream>>>(Vsbf, sigT, S, NN, NN, NN);

    // softmax statistics only (full normalized S never materialized)
    k_colreduce1<<<dim3(8, NSPLIT, BB), 256, 0, stream>>>(S, pm, ps);
    k_colreduce2<<<BB * NN / 256, 256, 0, stream>>>(pm, ps, Mf, Inv);

    // graph prep
    k_deg<<<EE / 256, 256, 0, stream>>>(row, col, deg);
    k_dinv<<<NN / 256, 256, 0, stream>>>(deg, dinv);
    k_norm<<<EE / 256, 256, 0, stream>>>(row, col, dinv, normv, cnt);
    k_scan<<<1, 256, 0, stream>>>(cnt, starts);
    k_scatter<<<EE / 256, 256, 0, stream>>>(row, starts, cursor, eid);
    k_diagatt<<<BB * EE / 256, 256, 0, stream>>>(S, row, col, normv, Mf, Inv, diagS, att);

    // chebyshev (bf16 pipeline)
    k_tx0<<<BB * NN * 512 / 512, 256, 0, stream>>>(X, diagS, Tx0);
    k_prop<<<BB * NN / 2, 256, 0, stream>>>(Tx0, att, col, starts, eid, nullptr, Tx1, 0);
    k_prop<<<BB * NN / 2, 256, 0, stream>>>(Tx1, att, col, starts, eid, Tx0, Tx2, 1);

    // fused cheb + temporal conv + residual + LN (MFMA, 1 wave / node)
    k_chebfinal<<<BB * NN, 64, 0, stream>>>(Tx0, Tx1, Tx2, X,
                                            WAcheb, WAtc, WAres,
                                            cb, btr, gamma, beta, out);
}

// Round 9
// 269.441 us; speedup vs baseline: 3.3313x; 1.1261x over previous
//
#include <hip/hip_runtime.h>
#include <hip/hip_bf16.h>

#define BB 4
#define NN 2048
#define FIN 32
#define TT 16
#define EE 32768
#define CC 64
#define TFo 64
#define NSPLIT 8

typedef __attribute__((ext_vector_type(8))) short bf16x8;
typedef __attribute__((ext_vector_type(4))) float f32x4;

typedef __attribute__((address_space(1))) const unsigned int as1_uint;
typedef __attribute__((address_space(3))) unsigned int as3_uint;

__device__ __forceinline__ void gload_lds16(const void* g, void* l) {
    __builtin_amdgcn_global_load_lds((as1_uint*)g, (as3_uint*)l, 16, 0, 0);
}

__device__ __forceinline__ unsigned short f2bf(float v) {
    unsigned u = __builtin_bit_cast(unsigned, v);
    unsigned r = (u + 0x7fffu + ((u >> 16) & 1u)) >> 16;
    return (unsigned short)r;
}

__device__ __forceinline__ float bf2f(unsigned short v) {
    return __builtin_bit_cast(float, (unsigned)v << 16);
}

// ---------------- Stage A: temporal attention ----------------

__global__ void k_u1reduce(const float* __restrict__ X, const float* __restrict__ U1,
                           float* __restrict__ tmp1) {
    int b = blockIdx.x >> 6;
    int n0 = (blockIdx.x & 63) * 32;
    float a0 = 0.f, a1 = 0.f;
    for (int i = 0; i < 32; ++i) {
        int n = n0 + i;
        float u = U1[n];
        const float* row = X + ((size_t)(b * NN + n)) * 512;
        a0 += u * row[threadIdx.x];
        a1 += u * row[threadIdx.x + 256];
    }
    atomicAdd(&tmp1[b * 512 + threadIdx.x], a0);
    atomicAdd(&tmp1[b * 512 + threadIdx.x + 256], a1);
}

__global__ void k_mklhs(const float* __restrict__ tmp1, const float* __restrict__ U2,
                        float* __restrict__ lhs) {
    int npr = ((blockIdx.x & 7) << 8) + threadIdx.x;
    int bt = blockIdx.x >> 3;           // b*16 + t
    int b = bt >> 4, t = bt & 15;
    float acc = 0.f;
#pragma unroll
    for (int f = 0; f < 32; ++f) acc += tmp1[b * 512 + f * 16 + t] * U2[f * NN + npr];
    lhs[(size_t)bt * NN + npr] = acc;
}

__global__ void k_mkrhs(const float* __restrict__ X, const float* __restrict__ U3,
                        float* __restrict__ rhs) {
    int idx = blockIdx.x * 256 + threadIdx.x;   // B*N*T
    int t = idx & 15;
    int bn = idx >> 4;
    float acc = 0.f;
#pragma unroll
    for (int f = 0; f < 32; ++f) acc += U3[f] * X[(size_t)bn * 512 + f * 16 + t];
    rhs[idx] = acc;
}

__global__ void k_ptaccum(const float* __restrict__ lhs, const float* __restrict__ rhs,
                          float* __restrict__ Pt) {
    int b = blockIdx.x >> 3;
    int n0 = (blockIdx.x & 7) * 256;
    int t = threadIdx.x >> 4, s = threadIdx.x & 15;
    const float* lr = lhs + (size_t)b * TT * NN + (size_t)t * NN;
    const float* rr = rhs + (size_t)b * NN * TT;
    float acc = 0.f;
    for (int i = 0; i < 256; ++i) {
        int n = n0 + i;
        acc += lr[n] * rr[n * 16 + s];
    }
    atomicAdd(&Pt[b * 256 + threadIdx.x], acc);
}

__global__ void k_temporalatt(const float* __restrict__ Pt, const float* __restrict__ be,
                              const float* __restrict__ Ve, float* __restrict__ Emat) {
    int b = blockIdx.x;
    int t = threadIdx.x >> 4, s = threadIdx.x & 15;
    __shared__ float sg[16][17];
    __shared__ float em[16][17];
    float v = Pt[b * 256 + t * 16 + s] + be[t * 16 + s];
    sg[t][s] = 1.f / (1.f + __expf(-v));
    __syncthreads();
    float e = 0.f;
#pragma unroll
    for (int u = 0; u < 16; ++u) e += Ve[t * 16 + u] * sg[u][s];
    em[t][s] = e;
    __syncthreads();
    float mx = -1e30f;
#pragma unroll
    for (int u = 0; u < 16; ++u) mx = fmaxf(mx, em[u][s]);
    float sum = 0.f;
#pragma unroll
    for (int u = 0; u < 16; ++u) sum += __expf(em[u][s] - mx);
    Emat[b * 256 + t * 16 + s] = __expf(e - mx) / sum;
}

// ---------------- Stage B: spatial attention (applyemat fused in) ----------------

__global__ void k_spatiallr(const float* __restrict__ X, const float* __restrict__ Emat,
                            const float* __restrict__ W1, const float* __restrict__ W2,
                            const float* __restrict__ W3,
                            float* __restrict__ lhs_s, float* __restrict__ rhs_s) {
    int b = blockIdx.x >> 7;
    int n0 = (blockIdx.x & 127) * 16;
    __shared__ float em[256];
    __shared__ float xb[16 * 32 * 17];   // Xt, [(nl*32+f)*17 + s]
    __shared__ float av[16 * 32];
    em[threadIdx.x] = Emat[b * 256 + threadIdx.x];
    __syncthreads();
#pragma unroll
    for (int ii = 0; ii < 2; ++ii) {
        int p = threadIdx.x * 2 + ii;    // nl*32 + f
        int nl = p >> 5, f = p & 31;
        const float4* src = (const float4*)(X + ((size_t)(b * NN + n0 + nl)) * 512 + f * 16);
        float4 q0 = src[0], q1 = src[1], q2 = src[2], q3 = src[3];
        float xv[16] = {q0.x, q0.y, q0.z, q0.w, q1.x, q1.y, q1.z, q1.w,
                        q2.x, q2.y, q2.z, q2.w, q3.x, q3.y, q3.z, q3.w};
        float o[16];
#pragma unroll
        for (int s = 0; s < 16; ++s) o[s] = 0.f;
#pragma unroll
        for (int t = 0; t < 16; ++t) {
            float xt = xv[t];
            const float* er = &em[t * 16];
#pragma unroll
            for (int s = 0; s < 16; ++s) o[s] += xt * er[s];
        }
        float a = 0.f;
#pragma unroll
        for (int s = 0; s < 16; ++s) { xb[p * 17 + s] = o[s]; a += o[s] * W1[s]; }
        av[p] = a;
    }
    __syncthreads();
    int nl = threadIdx.x >> 4, t = threadIdx.x & 15;
    float r = 0.f;
#pragma unroll
    for (int f = 0; f < 32; ++f) r += W3[f] * xb[(nl * 32 + f) * 17 + t];
    rhs_s[(size_t)b * TT * NN + (size_t)t * NN + n0 + nl] = r;
    float l = 0.f;
#pragma unroll
    for (int f = 0; f < 32; ++f) l += av[nl * 32 + f] * W2[f * 16 + t];
    lhs_s[((size_t)(b * NN + n0 + nl)) * 16 + t] = l;
}

// Vs fp32 -> bf16
__global__ void k_f2bf(const float* __restrict__ src, unsigned short* __restrict__ dst) {
    int i = blockIdx.x * 256 + threadIdx.x;
    dst[i] = f2bf(src[i]);
}

// ---------------- weight prep: exact per-lane MFMA A-fragments (bf16) ----------------
__global__ void k_wtprep(const float* __restrict__ cW, const float* __restrict__ Wt,
                         const float* __restrict__ Wr, const float* __restrict__ bt,
                         const float* __restrict__ br,
                         unsigned short* __restrict__ WAcheb,
                         unsigned short* __restrict__ WAtc,
                         unsigned short* __restrict__ WAres,
                         float* __restrict__ btr) {
    int idx = blockIdx.x * 256 + threadIdx.x;
    if (idx < 6144) {                      // cheb
        int j = idx & 7, l = (idx >> 3) & 63, fi = idx >> 9;   // fi = ks*4+i
        int row = ((fi & 3) << 4) + (l & 15);
        int kidx = ((fi >> 2) << 5) + ((l >> 4) << 3) + j;
        int k = kidx >> 5, f = kidx & 31;
        WAcheb[idx] = f2bf(cW[k * 2048 + f * 64 + row]);
    } else if (idx < 18432) {              // temporal conv
        int e = idx - 6144;
        int j = e & 7, l = (e >> 3) & 63, fi = e >> 9;         // fi = ks*4+i, ks<6
        int row = ((fi & 3) << 4) + (l & 15);
        int kidx = ((fi >> 2) << 5) + ((l >> 4) << 3) + j;
        int tap = kidx >> 6, c = kidx & 63;
        WAtc[e] = f2bf(Wt[row * 192 + c * 3 + tap]);
    } else if (idx < 20480) {              // residual
        int e = idx - 18432;
        int j = e & 7, l = (e >> 3) & 63, i = e >> 9;
        int row = (i << 4) + (l & 15);
        int f = ((l >> 4) << 3) + j;
        WAres[e] = f2bf(Wr[row * 32 + f]);
    } else if (idx < 20544) {
        int o = idx - 20480;
        btr[o] = bt[o] + br[o];
    }
}

// sigT[b][k][m] = bf16(sigmoid(dot(lhs_s[b,m,:], rhs_s[b,:,k]) + bs[m,k]))
// bs tile staged ONCE, reused for all 4 batches
__global__ void k_makesigT(const float* __restrict__ lhs_s, const float* __restrict__ rhs_s,
                           const float* __restrict__ bs, unsigned short* __restrict__ sigT) {
    int k0 = blockIdx.x * 64, m0 = blockIdx.y * 64;
    __shared__ float lh[64][17];
    __shared__ float rh[16][64];
    __shared__ float bsl[64][65];
    int tid = threadIdx.x;
#pragma unroll
    for (int i = 0; i < 16; ++i) {
        int idx = tid + i * 256;
        int mi = idx >> 6, kj = idx & 63;
        bsl[mi][kj] = bs[(size_t)(m0 + mi) * NN + k0 + kj];
    }
    int ml = tid & 63;
    int kg = (tid >> 6) * 16;
    for (int b = 0; b < BB; ++b) {
        __syncthreads();
#pragma unroll
        for (int i = 0; i < 4; ++i) {
            int idx = tid + i * 256;
            int mi = idx >> 4, t = idx & 15;
            lh[mi][t] = lhs_s[((size_t)(b * NN + m0 + mi)) * 16 + t];
            int tt = idx >> 6, kj = idx & 63;
            rh[tt][kj] = rhs_s[(size_t)b * TT * NN + (size_t)tt * NN + k0 + kj];
        }
        __syncthreads();
        unsigned short* out = sigT + (size_t)b * NN * NN;
#pragma unroll 4
        for (int ki = 0; ki < 16; ++ki) {
            int kl = kg + ki;
            float acc = bsl[ml][kl];
#pragma unroll
            for (int t = 0; t < 16; ++t) acc += lh[ml][t] * rh[t][kl];
            float sgv = 1.f / (1.f + __expf(-acc));
            out[(size_t)(k0 + kl) * NN + m0 + ml] = f2bf(sgv);
        }
    }
}

// ---------------- big GEMM: 256x256 tile, BK=64, 8 waves, counted-vmcnt pipeline ----------
// S[b][n][k] = sum_m Vs[n][m]*sigT[b][k][m]; epilogue also emits per-256-row-slice
// column softmax partials (max, sumexp) -> pm/ps   (NSPLIT = 2048/256 = 8)
// LDS swizzle: kbyte ^= (row&7)<<4 ; staged via linear-LDS-dest + pre-swizzled global src.
__global__ __launch_bounds__(512, 2) void k_gemm256(const unsigned short* __restrict__ A,
                                                    const unsigned short* __restrict__ Bt,
                                                    float* __restrict__ C,
                                                    float* __restrict__ pm,
                                                    float* __restrict__ ps) {
    __shared__ __align__(16) unsigned short lds[2][2][256 * 64];   // 128 KB
    const int tid = threadIdx.x;
    const int wid = tid >> 6, lane = tid & 63;
    const int wrM = (wid >> 2) << 7;     // 0 / 128
    const int wcN = (wid & 3) << 6;      // 0..192
    const int rl = lane & 15;
    const int kg = (lane >> 4) << 3;     // shorts
    const int sw = (rl & 7) << 3;        // read-side XOR (shorts)
    const int bm = blockIdx.y << 8;
    const int bn = blockIdx.x << 8;
    const int b = blockIdx.z;
    const unsigned short* Bb = Bt + (size_t)b * NN * NN;
    float* Cb = C + (size_t)b * NN * NN;

    const int srow = (wid << 3) + (lane >> 3);                       // row in 64-row group
    const int skel = (((lane & 7) << 3) ^ ((lane >> 3) << 3));       // pre-swizzled k-elem

    f32x4 acc[8][4];
#pragma unroll
    for (int i = 0; i < 8; ++i)
#pragma unroll
        for (int j = 0; j < 4; ++j) acc[i][j] = (f32x4){0.f, 0.f, 0.f, 0.f};

#define STAGE256(buf, kt)                                                          \
    {                                                                              \
        _Pragma("unroll")                                                          \
        for (int q = 0; q < 4; ++q) {                                              \
            int rowA = (q << 6) + srow;                                            \
            gload_lds16(A + (size_t)(bm + rowA) * NN + ((kt) << 6) + skel,         \
                        &lds[buf][0][(q << 12) + (wid << 9)]);                     \
            gload_lds16(Bb + (size_t)(bn + rowA) * NN + ((kt) << 6) + skel,        \
                        &lds[buf][1][(q << 12) + (wid << 9)]);                     \
        }                                                                          \
    }

#define COMPUTE256(buf)                                                            \
    {                                                                              \
        const unsigned short* la = &lds[buf][0][0];                                \
        const unsigned short* lb = &lds[buf][1][0];                                \
        _Pragma("unroll")                                                          \
        for (int ks = 0; ks < 2; ++ks) {                                           \
            bf16x8 af[8], bfr[4];                                                  \
            _Pragma("unroll")                                                      \
            for (int i = 0; i < 8; ++i) {                                          \
                int r = wrM + (i << 4) + rl;                                       \
                af[i] = *(const bf16x8*)(la + (r << 6) + (((ks << 5) + kg) ^ sw)); \
            }                                                                      \
            _Pragma("unroll")                                                      \
            for (int j = 0; j < 4; ++j) {                                          \
                int r = wcN + (j << 4) + rl;                                       \
                bfr[j] = *(const bf16x8*)(lb + (r << 6) + (((ks << 5) + kg) ^ sw)); \
            }                                                                      \
            _Pragma("unroll")                                                      \
            for (int i = 0; i < 8; ++i)                                            \
                _Pragma("unroll")                                                  \
                for (int j = 0; j < 4; ++j)                                        \
                    acc[i][j] = __builtin_amdgcn_mfma_f32_16x16x32_bf16(af[i], bfr[j], acc[i][j], 0, 0, 0); \
        }                                                                          \
    }

    const int NKT = NN >> 6;   // 32
    STAGE256(0, 0)
    STAGE256(1, 1)
    asm volatile("s_waitcnt vmcnt(8)" ::: "memory");
    asm volatile("s_barrier" ::: "memory");
    for (int t = 0; t < NKT; ++t) {
        int cur = t & 1;
        COMPUTE256(cur)
        asm volatile("s_barrier" ::: "memory");   // all reads of buf[cur] done
        if (t + 2 < NKT) {
            STAGE256(cur, t + 2)
            asm volatile("s_waitcnt vmcnt(8)" ::: "memory");  // buf[cur^1] ready
            asm volatile("s_barrier" ::: "memory");
        } else if (t + 1 < NKT) {
            asm volatile("s_waitcnt vmcnt(0)" ::: "memory");
            asm volatile("s_barrier" ::: "memory");
        }
    }
#undef STAGE256
#undef COMPUTE256

    // ---- C write ----
    const int cl = lane & 15, rg = (lane >> 4) << 2;
#pragma unroll
    for (int i = 0; i < 8; ++i)
#pragma unroll
        for (int j = 0; j < 4; ++j) {
            int m0 = bm + wrM + (i << 4) + rg;
            int n0 = bn + wcN + (j << 4) + cl;
#pragma unroll
            for (int r = 0; r < 4; ++r) Cb[(size_t)(m0 + r) * NN + n0] = acc[i][j][r];
        }

    // ---- fused column-softmax partials over this block's 256 rows ----
    float* smax = (float*)&lds[0][0][0];
    float* ssum = smax + 512;
#pragma unroll
    for (int j = 0; j < 4; ++j) {
        float mx = -1e30f;
#pragma unroll
        for (int i = 0; i < 8; ++i)
#pragma unroll
            for (int r = 0; r < 4; ++r) mx = fmaxf(mx, acc[i][j][r]);
        float se = 0.f;
#pragma unroll
        for (int i = 0; i < 8; ++i)
#pragma unroll
            for (int r = 0; r < 4; ++r) se += __expf(acc[i][j][r] - mx);
#pragma unroll
        for (int m = 16; m <= 32; m <<= 1) {
            float omx = __shfl_xor(mx, m);
            float ose = __shfl_xor(se, m);
            float nm = fmaxf(mx, omx);
            se = se * __expf(mx - nm) + ose * __expf(omx - nm);
            mx = nm;
        }
        if (lane < 16) {
            int idx = wcN + (j << 4) + lane;
            smax[((wid >> 2) << 8) + idx] = mx;
            ssum[((wid >> 2) << 8) + idx] = se;
        }
    }
    __syncthreads();
    if (tid < 256) {
        float m0 = smax[tid], m1 = smax[256 + tid];
        float s0 = ssum[tid], s1 = ssum[256 + tid];
        float nm = fmaxf(m0, m1);
        float s = s0 * __expf(m0 - nm) + s1 * __expf(m1 - nm);
        size_t o = ((size_t)(b * NSPLIT + blockIdx.y) * NN) + bn + tid;
        pm[o] = nm;
        ps[o] = s;
    }
}

// combine NSPLIT partials -> Mf[b][k], Inv[b][k]
__global__ void k_colreduce2(const float* __restrict__ pm, const float* __restrict__ ps,
                             float* __restrict__ Mf, float* __restrict__ Inv) {
    int idx = blockIdx.x * 256 + threadIdx.x;
    float M = -1e30f, Ssum = 0.f;
#pragma unroll
    for (int i = 0; i < NSPLIT; ++i) {
        size_t o = ((size_t)((idx >> 11) * NSPLIT + i) * NN) + (idx & (NN - 1));
        float mm = pm[o], sv = ps[o];
        float nm = fmaxf(M, mm);
        Ssum = Ssum * __expf(M - nm) + sv * __expf(mm - nm);
        M = nm;
    }
    Mf[idx] = M;
    Inv[idx] = 1.f / Ssum;
}

__global__ void k_diagatt(const float* __restrict__ S, const int* __restrict__ row,
                          const int* __restrict__ col, const float* __restrict__ norm,
                          const float* __restrict__ Mf, const float* __restrict__ Inv,
                          float* __restrict__ diagS, float* __restrict__ att) {
    int idx = blockIdx.x * 256 + threadIdx.x;
    if (idx < BB * EE) {
        int b = idx >> 15, e = idx & (EE - 1);
        int c = col[e];
        float v = S[(size_t)b * NN * NN + (size_t)row[e] * NN + c];
        att[idx] = norm[e] * __expf(v - Mf[b * NN + c]) * Inv[b * NN + c];
    }
    if (idx < BB * NN) {
        float v = S[(size_t)(idx >> 11) * NN * NN + (size_t)(idx & (NN - 1)) * NN + (idx & (NN - 1))];
        diagS[idx] = __expf(v - Mf[idx]) * Inv[idx];
    }
}

// ---------------- graph prep ----------------

__global__ void k_deg(const int* __restrict__ row, const int* __restrict__ col,
                      float* __restrict__ deg) {
    int e = blockIdx.x * 256 + threadIdx.x;
    if (e < EE && row[e] != col[e]) atomicAdd(&deg[row[e]], 1.0f);
}

__global__ void k_dinv(const float* __restrict__ deg, float* __restrict__ dinv) {
    int n = blockIdx.x * 256 + threadIdx.x;
    if (n < NN) {
        float d = deg[n];
        dinv[n] = d > 0.f ? rsqrtf(fmaxf(d, 1e-12f)) : 0.f;
    }
}

__global__ void k_norm(const int* __restrict__ row, const int* __restrict__ col,
                       const float* __restrict__ dinv, float* __restrict__ norm,
                       int* __restrict__ cnt) {
    int e = blockIdx.x * 256 + threadIdx.x;
    if (e < EE) {
        int r = row[e], c = col[e];
        float w = (r != c) ? 1.f : 0.f;
        norm[e] = -dinv[r] * w * dinv[c];
        atomicAdd(&cnt[r], 1);
    }
}

__global__ void k_scan(const int* __restrict__ cnt, int* __restrict__ starts) {
    __shared__ int part[256];
    int t = threadIdx.x;
    int loc[8];
    int s = 0;
#pragma unroll
    for (int i = 0; i < 8; ++i) {
        int c = cnt[t * 8 + i];
        loc[i] = s;
        s += c;
    }
    part[t] = s;
    __syncthreads();
    for (int o = 1; o < 256; o <<= 1) {
        int v = (t >= o) ? part[t - o] : 0;
        __syncthreads();
        part[t] += v;
        __syncthreads();
    }
    int pbase = (t > 0) ? part[t - 1] : 0;
#pragma unroll
    for (int i = 0; i < 8; ++i) starts[t * 8 + i] = pbase + loc[i];
    if (t == 255) starts[NN] = part[255];
}

__global__ void k_scatter(const int* __restrict__ row, const int* __restrict__ starts,
                          int* __restrict__ cursor, int* __restrict__ eid) {
    int e = blockIdx.x * 256 + threadIdx.x;
    if (e < EE) {
        int r = row[e];
        int slot = atomicAdd(&cursor[r], 1);
        eid[starts[r] + slot] = e;
    }
}

// ---------------- Chebyshev (bf16 Tx pipeline) ----------------

__global__ void k_tx0(const float* __restrict__ X, const float* __restrict__ diagS,
                      unsigned short* __restrict__ Tx0) {
    size_t idx = ((size_t)blockIdx.x * 256 + threadIdx.x) * 2;
    float2 v = *(const float2*)(X + idx);
    float d = diagS[idx >> 9];
    unsigned pack = (unsigned)f2bf(v.x * d) | ((unsigned)f2bf(v.y * d) << 16);
    *(unsigned*)(Tx0 + idx) = pack;
}

__global__ void k_prop(const unsigned short* __restrict__ x, const float* __restrict__ att,
                       const int* __restrict__ col, const int* __restrict__ starts,
                       const int* __restrict__ eid, const unsigned short* __restrict__ sub,
                       unsigned short* __restrict__ out, int mode) {
    int g = threadIdx.x >> 7;
    int l = threadIdx.x & 127;
    int bn = (blockIdx.x << 1) + g;
    int b = bn >> 11, n = bn & (NN - 1);
    int s0 = starts[n], s1 = starts[n + 1];
    const unsigned short* xb = x + (size_t)b * NN * 512;
    const float* attb = att + (size_t)b * EE;
    float ax = 0.f, ay = 0.f, az = 0.f, aw = 0.f;
    float bx = 0.f, by = 0.f, bz = 0.f, bw = 0.f;
    int jj = s0;
    for (; jj + 2 <= s1; jj += 2) {
        int e0 = eid[jj], e1 = eid[jj + 1];
        float a0 = attb[e0], a1 = attb[e1];
        ushort4 v0 = *((const ushort4*)(xb + (size_t)col[e0] * 512) + l);
        ushort4 v1 = *((const ushort4*)(xb + (size_t)col[e1] * 512) + l);
        ax += a0 * bf2f(v0.x); ay += a0 * bf2f(v0.y); az += a0 * bf2f(v0.z); aw += a0 * bf2f(v0.w);
        bx += a1 * bf2f(v1.x); by += a1 * bf2f(v1.y); bz += a1 * bf2f(v1.z); bw += a1 * bf2f(v1.w);
    }
    if (jj < s1) {
        int e0 = eid[jj];
        float a0 = attb[e0];
        ushort4 v0 = *((const ushort4*)(xb + (size_t)col[e0] * 512) + l);
        ax += a0 * bf2f(v0.x); ay += a0 * bf2f(v0.y); az += a0 * bf2f(v0.z); aw += a0 * bf2f(v0.w);
    }
    float rx = ax + bx, ry = ay + by, rz = az + bz, rw = aw + bw;
    size_t o = (size_t)bn * 512 + (l << 2);
    if (mode) {
        ushort4 sv = *(const ushort4*)(sub + o);
        rx = 2.f * rx - bf2f(sv.x); ry = 2.f * ry - bf2f(sv.y);
        rz = 2.f * rz - bf2f(sv.z); rw = 2.f * rw - bf2f(sv.w);
    }
    ushort4 ov;
    ov.x = f2bf(rx); ov.y = f2bf(ry); ov.z = f2bf(rz); ov.w = f2bf(rw);
    *(ushort4*)(out + o) = ov;
}

// ---------------- fused cheb + temporal conv + residual + LN via MFMA ----------------
#define XSP 104
#define XHP2 72
#define XTP 40
__global__ __launch_bounds__(64) void k_chebfinal(
    const unsigned short* __restrict__ Tx0, const unsigned short* __restrict__ Tx1,
    const unsigned short* __restrict__ Tx2, const float* __restrict__ X,
    const unsigned short* __restrict__ WAcheb,
    const unsigned short* __restrict__ WAtc,
    const unsigned short* __restrict__ WAres,
    const float* __restrict__ cb, const float* __restrict__ btr,
    const float* __restrict__ gamma, const float* __restrict__ beta,
    float* __restrict__ out) {
    int l = threadIdx.x;
    int bn = blockIdx.x;
    int tl = l & 15, fg = l >> 4;
    __shared__ unsigned short xsT[16 * XSP];
    __shared__ unsigned short xhT[18 * XHP2];
    __shared__ unsigned short XT[16 * XTP];
    xhT[l] = 0;
    xhT[17 * XHP2 + l] = 0;
    size_t nb = (size_t)bn * 512;
    {
        bf16x8 v;
#pragma unroll
        for (int j = 0; j < 8; ++j) v[j] = (short)Tx0[nb + (fg * 8 + j) * 16 + tl];
        *(bf16x8*)&xsT[tl * XSP + fg * 8] = v;
#pragma unroll
        for (int j = 0; j < 8; ++j) v[j] = (short)Tx1[nb + (fg * 8 + j) * 16 + tl];
        *(bf16x8*)&xsT[tl * XSP + 32 + fg * 8] = v;
#pragma unroll
        for (int j = 0; j < 8; ++j) v[j] = (short)Tx2[nb + (fg * 8 + j) * 16 + tl];
        *(bf16x8*)&xsT[tl * XSP + 64 + fg * 8] = v;
#pragma unroll
        for (int j = 0; j < 8; ++j) v[j] = (short)f2bf(X[nb + (fg * 8 + j) * 16 + tl]);
        *(bf16x8*)&XT[tl * XTP + fg * 8] = v;
    }
    __syncthreads();

    f32x4 acc[4];
#pragma unroll
    for (int i = 0; i < 4; ++i) acc[i] = (f32x4){0.f, 0.f, 0.f, 0.f};
#pragma unroll
    for (int ks = 0; ks < 3; ++ks) {
        bf16x8 bfrag = *(const bf16x8*)&xsT[tl * XSP + ks * 32 + fg * 8];
#pragma unroll
        for (int i = 0; i < 4; ++i)
            acc[i] = __builtin_amdgcn_mfma_f32_16x16x32_bf16(
                *(const bf16x8*)&WAcheb[((ks * 4 + i) * 64 + l) * 8], bfrag, acc[i], 0, 0, 0);
    }
#pragma unroll
    for (int i = 0; i < 4; ++i) {
        int cbase = i * 16 + fg * 4;
        float4 cv = *(const float4*)&cb[cbase];
        float h0 = fmaxf(acc[i][0] + cv.x, 0.f);
        float h1 = fmaxf(acc[i][1] + cv.y, 0.f);
        float h2v = fmaxf(acc[i][2] + cv.z, 0.f);
        float h3 = fmaxf(acc[i][3] + cv.w, 0.f);
        unsigned lo = (unsigned)f2bf(h0) | ((unsigned)f2bf(h1) << 16);
        unsigned hi = (unsigned)f2bf(h2v) | ((unsigned)f2bf(h3) << 16);
        *(uint2*)&xhT[(tl + 1) * XHP2 + cbase] = make_uint2(lo, hi);
    }
    __syncthreads();

    f32x4 a2[4];
#pragma unroll
    for (int i = 0; i < 4; ++i) a2[i] = (f32x4){0.f, 0.f, 0.f, 0.f};
#pragma unroll
    for (int ks = 0; ks < 6; ++ks) {
        int kb = ks * 32 + fg * 8;
        bf16x8 bfrag = *(const bf16x8*)&xhT[(tl + (kb >> 6)) * XHP2 + (kb & 63)];
#pragma unroll
        for (int i = 0; i < 4; ++i)
            a2[i] = __builtin_amdgcn_mfma_f32_16x16x32_bf16(
                *(const bf16x8*)&WAtc[((ks * 4 + i) * 64 + l) * 8], bfrag, a2[i], 0, 0, 0);
    }
    {
        bf16x8 bfrag = *(const bf16x8*)&XT[tl * XTP + fg * 8];
#pragma unroll
        for (int i = 0; i < 4; ++i)
            a2[i] = __builtin_amdgcn_mfma_f32_16x16x32_bf16(
                *(const bf16x8*)&WAres[(i * 64 + l) * 8], bfrag, a2[i], 0, 0, 0);
    }
    float h2[16];
#pragma unroll
    for (int i = 0; i < 4; ++i) {
        float4 bv = *(const float4*)&btr[i * 16 + fg * 4];
        h2[i * 4 + 0] = fmaxf(a2[i][0] + bv.x, 0.f);
        h2[i * 4 + 1] = fmaxf(a2[i][1] + bv.y, 0.f);
        h2[i * 4 + 2] = fmaxf(a2[i][2] + bv.z, 0.f);
        h2[i * 4 + 3] = fmaxf(a2[i][3] + bv.w, 0.f);
    }
    float s1 = 0.f, s2 = 0.f;
#pragma unroll
    for (int q = 0; q < 16; ++q) { s1 += h2[q]; s2 += h2[q] * h2[q]; }
    s1 += __shfl_xor(s1, 16); s2 += __shfl_xor(s2, 16);
    s1 += __shfl_xor(s1, 32); s2 += __shfl_xor(s2, 32);
    float mu = s1 * (1.f / 64.f);
    float rs = rsqrtf(s2 * (1.f / 64.f) - mu * mu + 1e-5f);
    float* ob = out + (size_t)bn * 1024 + tl;
#pragma unroll
    for (int i = 0; i < 4; ++i) {
        int cbase = i * 16 + fg * 4;
        float4 gv = *(const float4*)&gamma[cbase];
        float4 bv = *(const float4*)&beta[cbase];
        ob[(cbase + 0) * 16] = (h2[i * 4 + 0] - mu) * rs * gv.x + bv.x;
        ob[(cbase + 1) * 16] = (h2[i * 4 + 1] - mu) * rs * gv.y + bv.y;
        ob[(cbase + 2) * 16] = (h2[i * 4 + 2] - mu) * rs * gv.z + bv.z;
        ob[(cbase + 3) * 16] = (h2[i * 4 + 3] - mu) * rs * gv.w + bv.w;
    }
}

// ---------------- host ----------------

extern "C" void kernel_launch(void* const* d_in, const int* in_sizes, int n_in,
                              void* d_out, int out_size, void* d_ws, size_t ws_size,
                              hipStream_t stream) {
    (void)in_sizes; (void)n_in; (void)out_size; (void)ws_size;
    const float* X = (const float*)d_in[0];
    const int* ei = (const int*)d_in[1];
    const int* row = ei;
    const int* col = ei + EE;
    const float* U1 = (const float*)d_in[2];
    const float* U2 = (const float*)d_in[3];
    const float* U3 = (const float*)d_in[4];
    const float* be = (const float*)d_in[5];
    const float* Ve = (const float*)d_in[6];
    const float* W1 = (const float*)d_in[7];
    const float* W2 = (const float*)d_in[8];
    const float* W3 = (const float*)d_in[9];
    const float* bs = (const float*)d_in[10];
    const float* Vs = (const float*)d_in[11];
    const float* cW = (const float*)d_in[12];
    const float* cb = (const float*)d_in[13];
    const float* Wt = (const float*)d_in[14];
    const float* bt = (const float*)d_in[15];
    const float* Wr = (const float*)d_in[16];
    const float* br = (const float*)d_in[17];
    const float* gamma = (const float*)d_in[18];
    const float* beta = (const float*)d_in[19];
    float* out = (float*)d_out;

    char* w = (char*)d_ws;
    constexpr size_t OFF_TMP1 = 0;            // 8192
    constexpr size_t OFF_PT = 8192;           // 4096
    constexpr size_t OFF_DEG = 12288;         // 8192
    constexpr size_t OFF_CNT = 20480;         // 8192
    constexpr size_t OFF_CURSOR = 28672;      // 8192
    constexpr size_t ZEND = 36864;
    constexpr size_t OFF_EMAT = ZEND;                     // 4096
    constexpr size_t OFF_LHS = OFF_EMAT + 4096;           // 512K
    constexpr size_t OFF_RHS = OFF_LHS + 524288;          // 512K
    constexpr size_t OFF_LHSS = OFF_RHS + 524288;         // 512K (reused: pm)
    constexpr size_t OFF_RHSS = OFF_LHSS + 524288;        // 512K (reused: ps)
    constexpr size_t OFF_DIAG = OFF_RHSS + 524288;        // 32K
    constexpr size_t OFF_ATT = OFF_DIAG + 32768;          // 512K
    constexpr size_t OFF_DINV = OFF_ATT + 524288;         // 8K
    constexpr size_t OFF_NORM = OFF_DINV + 8192;          // 128K
    constexpr size_t OFF_STARTS = OFF_NORM + 131072;      // 8448
    constexpr size_t OFF_EID = OFF_STARTS + 8448;         // 128K
    constexpr size_t OFF_WA = OFF_EID + 131072;           // 56K region for frags
    constexpr size_t OFF_WACHEB = OFF_WA;                 // 12288
    constexpr size_t OFF_WATC = OFF_WA + 12288;           // 24576
    constexpr size_t OFF_WARES = OFF_WA + 36864;          // 4096
    constexpr size_t OFF_BTR = OFF_WA + 40960;            // 256
    constexpr size_t OFF_VSBF = OFF_WA + 57344;           // 8MB (reused: Mf/Inv)
    constexpr size_t OFF_TX0 = OFF_VSBF + 8388608;        // 16MB region (Tx0 bf16)
    constexpr size_t OFF_SIGT = OFF_TX0 + 16777216;       // 32MB
    constexpr size_t OFF_S = OFF_SIGT + 33554432;         // 64MB (reused: Tx1, Tx2 bf16)

    float* tmp1 = (float*)(w + OFF_TMP1);
    float* Pt = (float*)(w + OFF_PT);
    float* deg = (float*)(w + OFF_DEG);
    int* cnt = (int*)(w + OFF_CNT);
    int* cursor = (int*)(w + OFF_CURSOR);
    float* Emat = (float*)(w + OFF_EMAT);
    float* lhs = (float*)(w + OFF_LHS);
    float* rhs = (float*)(w + OFF_RHS);
    float* lhs_s = (float*)(w + OFF_LHSS);
    float* rhs_s = (float*)(w + OFF_RHSS);
    float* diagS = (float*)(w + OFF_DIAG);
    float* att = (float*)(w + OFF_ATT);
    float* dinv = (float*)(w + OFF_DINV);
    float* normv = (float*)(w + OFF_NORM);
    int* starts = (int*)(w + OFF_STARTS);
    int* eid = (int*)(w + OFF_EID);
    unsigned short* WAcheb = (unsigned short*)(w + OFF_WACHEB);
    unsigned short* WAtc = (unsigned short*)(w + OFF_WATC);
    unsigned short* WAres = (unsigned short*)(w + OFF_WARES);
    float* btr = (float*)(w + OFF_BTR);
    unsigned short* Vsbf = (unsigned short*)(w + OFF_VSBF);
    // pm/ps live in the dead lhs_s/rhs_s regions during+after the GEMM (256 KB each)
    float* pm = (float*)(w + OFF_LHSS);
    float* ps = (float*)(w + OFF_RHSS);
    float* Mf = (float*)(w + OFF_VSBF + 1048576);         // Vsbf dead after GEMM
    float* Inv = (float*)(w + OFF_VSBF + 1048576 + 32768);
    unsigned short* Tx0 = (unsigned short*)(w + OFF_TX0);
    unsigned short* sigT = (unsigned short*)(w + OFF_SIGT);
    float* S = (float*)(w + OFF_S);
    unsigned short* Tx1 = (unsigned short*)(w + OFF_S);   // reuse after diag/att extracted
    unsigned short* Tx2 = (unsigned short*)(w + OFF_S + 16777216);

    hipMemsetAsync(w, 0, ZEND, stream);

    // temporal attention
    k_u1reduce<<<BB * 64, 256, 0, stream>>>(X, U1, tmp1);
    k_mkrhs<<<BB * NN * TT / 256, 256, 0, stream>>>(X, U3, rhs);
    k_mklhs<<<BB * TT * 8, 256, 0, stream>>>(tmp1, U2, lhs);
    k_ptaccum<<<BB * 8, 256, 0, stream>>>(lhs, rhs, Pt);
    k_temporalatt<<<BB, 256, 0, stream>>>(Pt, be, Ve, Emat);

    // spatial attention (Xt computed in-LDS inside k_spatiallr)
    k_spatiallr<<<BB * (NN / 16), 256, 0, stream>>>(X, Emat, W1, W2, W3, lhs_s, rhs_s);
    k_f2bf<<<NN * NN / 256, 256, 0, stream>>>(Vs, Vsbf);
    k_wtprep<<<81, 256, 0, stream>>>(cW, Wt, Wr, bt, br, WAcheb, WAtc, WAres, btr);
    k_makesigT<<<dim3(NN / 64, NN / 64), 256, 0, stream>>>(lhs_s, rhs_s, bs, sigT);

    // big GEMM (256² tile, counted-vmcnt pipeline) + fused column-stat partials
    k_gemm256<<<dim3(NN / 256, NN / 256, BB), 512, 0, stream>>>(Vsbf, sigT, S, pm, ps);
    k_colreduce2<<<BB * NN / 256, 256, 0, stream>>>(pm, ps, Mf, Inv);

    // graph prep
    k_deg<<<EE / 256, 256, 0, stream>>>(row, col, deg);
    k_dinv<<<NN / 256, 256, 0, stream>>>(deg, dinv);
    k_norm<<<EE / 256, 256, 0, stream>>>(row, col, dinv, normv, cnt);
    k_scan<<<1, 256, 0, stream>>>(cnt, starts);
    k_scatter<<<EE / 256, 256, 0, stream>>>(row, starts, cursor, eid);
    k_diagatt<<<BB * EE / 256, 256, 0, stream>>>(S, row, col, normv, Mf, Inv, diagS, att);

    // chebyshev (bf16 pipeline)
    k_tx0<<<BB * NN * 512 / 512, 256, 0, stream>>>(X, diagS, Tx0);
    k_prop<<<BB * NN / 2, 256, 0, stream>>>(Tx0, att, col, starts, eid, nullptr, Tx1, 0);
    k_prop<<<BB * NN / 2, 256, 0, stream>>>(Tx1, att, col, starts, eid, Tx0, Tx2, 1);

    // fused cheb + temporal conv + residual + LN (MFMA, 1 wave / node)
    k_chebfinal<<<BB * NN, 64, 0, stream>>>(Tx0, Tx1, Tx2, X,
                                            WAcheb, WAtc, WAres,
                                            cb, btr, gamma, beta, out);
}